// Round 5
// baseline (1544.021 us; speedup 1.0000x reference)
//
#include <hip/hip_runtime.h>
#include <math.h>

#define NFFT  512
#define WINL  320
#define HOP   160
#define FPAD  256
#define NF    257
#define TT    601
#define LSEQ  96000
#define XPLEN 96512
#define NCH   8
#define NB    8
#define NSEQ  64
#define NROWS 38464   // NSEQ*TT
#define DD    514
#define HH    128
#define G4    512
#define KPAD  544     // 17*32, zero-padded K for split-B arrays
#define NCOMB 1026    // 514 (S cols) + 512 (XW cols)

typedef _Float16 h2v __attribute__((ext_vector_type(2)));
typedef short bf16x8 __attribute__((ext_vector_type(8)));
typedef float f32x4 __attribute__((ext_vector_type(4)));

// ---------------- init helpers ----------------
__device__ __forceinline__ float winval(int k) {
  if (k < 96 || k >= 416) return 0.f;
  return 0.5f - 0.5f * cosf((float)(2.0 * M_PI / 320.0) * (float)(k - 96));
}

__device__ __forceinline__ void split_bf16(float v, unsigned short* h, unsigned short* l) {
  unsigned int hb = __float_as_uint(v) >> 16;
  float r = v - __uint_as_float(hb << 16);
  *h = (unsigned short)hb;
  *l = (unsigned short)(__float_as_uint(r) >> 16);
}

__global__ void k_wsq(float* __restrict__ wsq) {
  int p = blockIdx.x * 256 + threadIdx.x;
  if (p >= XPLEN) return;
  int t0 = (p <= 511) ? 0 : (p - 352) / 160;
  int t1 = p / 160; if (t1 > 600) t1 = 600;
  float s = 0.f;
  for (int t = t0; t <= t1; t++) { float w = winval(p - t * HOP); s += w * w; }
  wsq[p] = s;
}

// fp32 forward-DFT matrix BFf[k][d] (512 x 514), for the BW precompute GEMM
__global__ void k_bff(float* __restrict__ BFf) {
  int idx = blockIdx.x * 256 + threadIdx.x;
  if (idx >= NFFT * DD) return;
  int k = idx / DD, d = idx - k * DD;
  float w = winval(k);
  int f = (d < NF) ? d : d - NF;
  int m = (k * f) & 511;
  float th = (float)(M_PI / 256.0) * (float)m;
  BFf[idx] = ((d < NF) ? cosf(th) : -sinf(th)) * w;
}

// WT split: Bt[n][k] = Wih[n][k]  (used by the BW precompute)
__global__ void k_wtsplit(const float* __restrict__ Wih, unsigned short* __restrict__ H,
                          unsigned short* __restrict__ L) {
  int idx = blockIdx.x * 256 + threadIdx.x;
  if (idx >= G4 * KPAD) return;
  int n = idx / KPAD, k = idx - n * KPAD;
  float v = (k < DD) ? Wih[n * DD + k] : 0.f;
  split_bf16(v, &H[idx], &L[idx]);
}

// Combined split B for the fused STFT+xW GEMM: BC[n][k], n in [0,1152)
__global__ void k_bcomb(const float* __restrict__ BWf, unsigned short* __restrict__ H,
                        unsigned short* __restrict__ L) {
  int idx = blockIdx.x * 256 + threadIdx.x;
  if (idx >= 1152 * KPAD) return;
  int n = idx / KPAD, k = idx - n * KPAD;
  float v = 0.f;
  if (k < NFFT) {
    if (n < DD) {
      float w = winval(k);
      int f = (n < NF) ? n : n - NF;
      int m = (k * f) & 511;
      float th = (float)(M_PI / 256.0) * (float)m;
      v = ((n < NF) ? cosf(th) : -sinf(th)) * w;
    } else if (n < NCOMB) {
      v = BWf[k * G4 + (n - 514)];
    }
  }
  split_bf16(v, &H[idx], &L[idx]);
}

// BI split: Bt[n][kk] = BI[kk][n]
__global__ void k_bisplit(unsigned short* __restrict__ H, unsigned short* __restrict__ L) {
  int idx = blockIdx.x * 256 + threadIdx.x;
  if (idx >= NFFT * KPAD) return;
  int n = idx / KPAD, kk = idx - n * KPAD;
  float v = 0.f;
  if (kk < DD) {
    float w = winval(n);
    int f = (kk < NF) ? kk : kk - NF;
    int edge = (f == 0 || f == 256);
    float alpha = edge ? 1.f : 2.f;
    int m = (n * f) & 511;
    float th = (float)(M_PI / 256.0) * (float)m;
    float c;
    if (kk < NF) c = alpha * cosf(th);
    else         c = edge ? 0.f : -alpha * sinf(th);
    v = c * w * (1.f / 512.f);
  }
  split_bf16(v, &H[idx], &L[idx]);
}

__global__ void k_bsum(const float* __restrict__ bih, const float* __restrict__ bhh,
                       float* __restrict__ BSUM) {
  int idx = blockIdx.x * 256 + threadIdx.x;
  if (idx < G4) BSUM[idx] = bih[idx] + bhh[idx];
}

// W1/W2 mask-weight split: Ws[n'][k], n' = ri*320 + f
__global__ void k_wmsplit(const float* __restrict__ W1, const float* __restrict__ W2,
                          unsigned short* __restrict__ W1h, unsigned short* __restrict__ W1l,
                          unsigned short* __restrict__ W2h, unsigned short* __restrict__ W2l) {
  int idx = blockIdx.x * 256 + threadIdx.x;
  if (idx >= 2 * 640 * HH) return;
  int m = idx / (640 * HH);
  int rem = idx - m * 640 * HH;
  int np = rem / HH, k = rem - np * HH;
  int ri = np / 320, f = np - ri * 320;
  float v = 0.f;
  if (f < NF) {
    int fcol = (ri == 0) ? f : NF + f;
    v = (m == 0) ? W1[fcol * HH + k] : W2[fcol * HH + k];
  }
  unsigned short h, l;
  split_bf16(v, &h, &l);
  if (m == 0) { W1h[rem] = h; W1l[rem] = l; }
  else        { W2h[rem] = h; W2l[rem] = l; }
}

// pack Whh into f16 pairs, uint4-transposed (v8 layout, indexed by gate row)
__global__ void k_wpack(const float* __restrict__ Whh, unsigned int* __restrict__ WhhP4) {
  int idx = blockIdx.x * 256 + threadIdx.x;
  if (idx >= G4 * 64) return;
  int j = idx >> 6, k2 = idx & 63;
  _Float16 lo = (_Float16)Whh[j * HH + 2 * k2];
  _Float16 hi = (_Float16)Whh[j * HH + 2 * k2 + 1];
  unsigned int u = ((unsigned int)__builtin_bit_cast(unsigned short, hi) << 16)
                 |  (unsigned int)__builtin_bit_cast(unsigned short, lo);
  WhhP4[(k2 >> 2) * (G4 * 4) + j * 4 + (k2 & 3)] = u;
}

// reflect-padded multichannel extraction, pre-split to bf16 hi/lo: XPh/XPl[n][i]
__global__ void k_xp(const float* __restrict__ x, unsigned short* __restrict__ XPh,
                     unsigned short* __restrict__ XPl) {
  int idx = blockIdx.x * 256 + threadIdx.x;
  if (idx >= NSEQ * XPLEN) return;
  int n = idx / XPLEN, i = idx - n * XPLEN;
  int j = i - FPAD;
  if (j < 0) j = -j;
  else if (j >= LSEQ) j = 2 * LSEQ - 2 - j;
  int b = n >> 3, c = n & 7;
  float v = x[((long)b * LSEQ + j) * NCH + c];
  split_bf16(v, &XPh[idx], &XPl[idx]);
}

// ---------------- split-bf16 MFMA GEMM (fp32 A): C[M,N] = A[M,K] * Bt^T (+bias) ----------------
template <int GATHER>
__launch_bounds__(256)
__global__ void k_gemm3(const float* __restrict__ A,
                        const unsigned short* __restrict__ Bth,
                        const unsigned short* __restrict__ Btl,
                        const float* __restrict__ bias, float* __restrict__ C,
                        int M, int N, int K, int lda, int ldc) {
  __shared__ __align__(16) unsigned short sAh[128 * 40];
  __shared__ __align__(16) unsigned short sAl[128 * 40];
  __shared__ __align__(16) unsigned short sBh[128 * 40];
  __shared__ __align__(16) unsigned short sBl[128 * 40];
  const int tid = threadIdx.x;
  const int row0 = blockIdx.y * 128, col0 = blockIdx.x * 128;
  const int sar = tid >> 1, sak = (tid & 1) * 16;
  const int arow = row0 + sar;
  long abase = (long)arow * lda;
  const bool arok = (arow < M);
  const int lane = tid & 63, w = tid >> 6;
  const int wm = (w >> 1) * 64, wn = (w & 1) * 64;
  const int l15 = lane & 15, quad = lane >> 4;
  f32x4 acc[4][4] = {};
  unsigned int* aH = (unsigned int*)sAh;
  unsigned int* aL = (unsigned int*)sAl;
  uint4* bH = (uint4*)sBh;
  uint4* bL = (uint4*)sBl;
  for (int k0 = 0; k0 < K; k0 += 32) {
#pragma unroll
    for (int i = 0; i < 8; i++) {
      int kk = k0 + sak + 2 * i;
      float v0 = 0.f, v1 = 0.f;
      if (arok) {
        if (kk + 1 < K) { float2 t2 = *(const float2*)(A + abase + kk); v0 = t2.x; v1 = t2.y; }
        else if (kk < K) { v0 = A[abase + kk]; }
      }
      unsigned int h0 = __float_as_uint(v0) >> 16, h1 = __float_as_uint(v1) >> 16;
      float r0 = v0 - __uint_as_float(h0 << 16), r1 = v1 - __uint_as_float(h1 << 16);
      unsigned int l0 = __float_as_uint(r0) >> 16, l1 = __float_as_uint(r1) >> 16;
      aH[sar * 20 + (sak >> 1) + i] = h0 | (h1 << 16);
      aL[sar * 20 + (sak >> 1) + i] = l0 | (l1 << 16);
    }
#pragma unroll
    for (int h = 0; h < 2; h++) {
      int idx = tid + h * 256;
      int r = idx >> 2, c = idx & 3;
      long go = (long)(col0 + r) * KPAD + k0 + c * 8;
      bH[r * 5 + c] = *(const uint4*)(Bth + go);
      bL[r * 5 + c] = *(const uint4*)(Btl + go);
    }
    __syncthreads();
    bf16x8 ah[4], al[4], bh[4], bl[4];
#pragma unroll
    for (int i = 0; i < 4; i++) {
      int off = (wm + i * 16 + l15) * 40 + quad * 8;
      ah[i] = *(const bf16x8*)(sAh + off);
      al[i] = *(const bf16x8*)(sAl + off);
      int boff = (wn + i * 16 + l15) * 40 + quad * 8;
      bh[i] = *(const bf16x8*)(sBh + boff);
      bl[i] = *(const bf16x8*)(sBl + boff);
    }
#pragma unroll
    for (int i = 0; i < 4; i++)
#pragma unroll
      for (int j = 0; j < 4; j++) {
        acc[i][j] = __builtin_amdgcn_mfma_f32_16x16x32_bf16(al[i], bh[j], acc[i][j], 0, 0, 0);
        acc[i][j] = __builtin_amdgcn_mfma_f32_16x16x32_bf16(ah[i], bl[j], acc[i][j], 0, 0, 0);
        acc[i][j] = __builtin_amdgcn_mfma_f32_16x16x32_bf16(ah[i], bh[j], acc[i][j], 0, 0, 0);
      }
    __syncthreads();
  }
#pragma unroll
  for (int i = 0; i < 4; i++)
#pragma unroll
    for (int j = 0; j < 4; j++) {
      int cc = col0 + wn + j * 16 + l15;
      if (cc >= N) continue;
      float bv = bias ? bias[cc] : 0.f;
#pragma unroll
      for (int rg = 0; rg < 4; rg++) {
        int rr = row0 + wm + i * 16 + quad * 4 + rg;
        if (rr < M) C[(long)rr * ldc + cc] = acc[i][j][rg] + bv;
      }
    }
}

// ---------------- fused STFT+xW GEMM: pre-split A (gathered XP), combined B ----------------
// C[38464, 1026]: cols <514 -> S; cols 514..1025 -> XW (+bsum). K=512, tile 128x128.
__launch_bounds__(256)
__global__ void k_gemm4(const unsigned short* __restrict__ Ah, const unsigned short* __restrict__ Al,
                        const unsigned short* __restrict__ Bh, const unsigned short* __restrict__ Bl,
                        const float* __restrict__ bsum, float* __restrict__ S,
                        float* __restrict__ XW) {
  __shared__ __align__(16) unsigned short sAh[128 * 40];
  __shared__ __align__(16) unsigned short sAl[128 * 40];
  __shared__ __align__(16) unsigned short sBh[128 * 40];
  __shared__ __align__(16) unsigned short sBl[128 * 40];
  const int tid = threadIdx.x;
  const int row0 = blockIdx.y * 128, col0 = blockIdx.x * 128;
  const int sr0 = tid >> 2, c4 = (tid & 3) * 8, cq = tid & 3;
  long ab0, ab1;
  { int rr = row0 + sr0;      int n = rr / TT, t = rr - n * TT; ab0 = (long)n * XPLEN + (long)t * HOP; }
  { int rr = row0 + sr0 + 64; int n = rr / TT, t = rr - n * TT; ab1 = (long)n * XPLEN + (long)t * HOP; }
  const int lane = tid & 63, w = tid >> 6;
  const int wm = (w >> 1) * 64, wn = (w & 1) * 64;
  const int l15 = lane & 15, quad = lane >> 4;
  f32x4 acc[4][4] = {};
  uint4* aH4 = (uint4*)sAh; uint4* aL4 = (uint4*)sAl;
  uint4* bH4 = (uint4*)sBh; uint4* bL4 = (uint4*)sBl;
  for (int k0 = 0; k0 < NFFT; k0 += 32) {
    aH4[sr0 * 5 + cq]        = *(const uint4*)(Ah + ab0 + k0 + c4);
    aL4[sr0 * 5 + cq]        = *(const uint4*)(Al + ab0 + k0 + c4);
    aH4[(sr0 + 64) * 5 + cq] = *(const uint4*)(Ah + ab1 + k0 + c4);
    aL4[(sr0 + 64) * 5 + cq] = *(const uint4*)(Al + ab1 + k0 + c4);
    {
      long go = (long)(col0 + sr0) * KPAD + k0 + c4;
      bH4[sr0 * 5 + cq] = *(const uint4*)(Bh + go);
      bL4[sr0 * 5 + cq] = *(const uint4*)(Bl + go);
      go = (long)(col0 + sr0 + 64) * KPAD + k0 + c4;
      bH4[(sr0 + 64) * 5 + cq] = *(const uint4*)(Bh + go);
      bL4[(sr0 + 64) * 5 + cq] = *(const uint4*)(Bl + go);
    }
    __syncthreads();
    bf16x8 ah[4], al[4], bh[4], bl[4];
#pragma unroll
    for (int i = 0; i < 4; i++) {
      int off = (wm + i * 16 + l15) * 40 + quad * 8;
      ah[i] = *(const bf16x8*)(sAh + off);
      al[i] = *(const bf16x8*)(sAl + off);
      int boff = (wn + i * 16 + l15) * 40 + quad * 8;
      bh[i] = *(const bf16x8*)(sBh + boff);
      bl[i] = *(const bf16x8*)(sBl + boff);
    }
#pragma unroll
    for (int i = 0; i < 4; i++)
#pragma unroll
      for (int j = 0; j < 4; j++) {
        acc[i][j] = __builtin_amdgcn_mfma_f32_16x16x32_bf16(al[i], bh[j], acc[i][j], 0, 0, 0);
        acc[i][j] = __builtin_amdgcn_mfma_f32_16x16x32_bf16(ah[i], bl[j], acc[i][j], 0, 0, 0);
        acc[i][j] = __builtin_amdgcn_mfma_f32_16x16x32_bf16(ah[i], bh[j], acc[i][j], 0, 0, 0);
      }
    __syncthreads();
  }
#pragma unroll
  for (int i = 0; i < 4; i++)
#pragma unroll
    for (int j = 0; j < 4; j++) {
      int cc = col0 + wn + j * 16 + l15;
      if (cc >= NCOMB) continue;
#pragma unroll
      for (int rg = 0; rg < 4; rg++) {
        int rr = row0 + wm + i * 16 + quad * 4 + rg;
        if (rr >= NROWS) continue;
        float v = acc[i][j][rg];
        if (cc < DD) S[(long)rr * DD + cc] = v;
        else         XW[(long)rr * G4 + (cc - 514)] = v + bsum[cc - 514];
      }
    }
}

// ---------------- iSTFT GEMM: pre-split A (pitch KPAD), B = BI split ----------------
__launch_bounds__(256)
__global__ void k_gemm5(const unsigned short* __restrict__ Ah, const unsigned short* __restrict__ Al,
                        const unsigned short* __restrict__ Bh, const unsigned short* __restrict__ Bl,
                        float* __restrict__ C, int M, int N, int ldc) {
  __shared__ __align__(16) unsigned short sAh[128 * 40];
  __shared__ __align__(16) unsigned short sAl[128 * 40];
  __shared__ __align__(16) unsigned short sBh[128 * 40];
  __shared__ __align__(16) unsigned short sBl[128 * 40];
  const int tid = threadIdx.x;
  const int row0 = blockIdx.y * 128, col0 = blockIdx.x * 128;
  const int sr0 = tid >> 2, c4 = (tid & 3) * 8, cq = tid & 3;
  const int lane = tid & 63, w = tid >> 6;
  const int wm = (w >> 1) * 64, wn = (w & 1) * 64;
  const int l15 = lane & 15, quad = lane >> 4;
  f32x4 acc[4][4] = {};
  uint4* aH4 = (uint4*)sAh; uint4* aL4 = (uint4*)sAl;
  uint4* bH4 = (uint4*)sBh; uint4* bL4 = (uint4*)sBl;
  for (int k0 = 0; k0 < KPAD; k0 += 32) {
    {
      long go = (long)(row0 + sr0) * KPAD + k0 + c4;
      aH4[sr0 * 5 + cq] = *(const uint4*)(Ah + go);
      aL4[sr0 * 5 + cq] = *(const uint4*)(Al + go);
      go = (long)(row0 + sr0 + 64) * KPAD + k0 + c4;
      aH4[(sr0 + 64) * 5 + cq] = *(const uint4*)(Ah + go);
      aL4[(sr0 + 64) * 5 + cq] = *(const uint4*)(Al + go);
    }
    {
      long go = (long)(col0 + sr0) * KPAD + k0 + c4;
      bH4[sr0 * 5 + cq] = *(const uint4*)(Bh + go);
      bL4[sr0 * 5 + cq] = *(const uint4*)(Bl + go);
      go = (long)(col0 + sr0 + 64) * KPAD + k0 + c4;
      bH4[(sr0 + 64) * 5 + cq] = *(const uint4*)(Bh + go);
      bL4[(sr0 + 64) * 5 + cq] = *(const uint4*)(Bl + go);
    }
    __syncthreads();
    bf16x8 ah[4], al[4], bh[4], bl[4];
#pragma unroll
    for (int i = 0; i < 4; i++) {
      int off = (wm + i * 16 + l15) * 40 + quad * 8;
      ah[i] = *(const bf16x8*)(sAh + off);
      al[i] = *(const bf16x8*)(sAl + off);
      int boff = (wn + i * 16 + l15) * 40 + quad * 8;
      bh[i] = *(const bf16x8*)(sBh + boff);
      bl[i] = *(const bf16x8*)(sBl + boff);
    }
#pragma unroll
    for (int i = 0; i < 4; i++)
#pragma unroll
      for (int j = 0; j < 4; j++) {
        acc[i][j] = __builtin_amdgcn_mfma_f32_16x16x32_bf16(al[i], bh[j], acc[i][j], 0, 0, 0);
        acc[i][j] = __builtin_amdgcn_mfma_f32_16x16x32_bf16(ah[i], bl[j], acc[i][j], 0, 0, 0);
        acc[i][j] = __builtin_amdgcn_mfma_f32_16x16x32_bf16(ah[i], bh[j], acc[i][j], 0, 0, 0);
      }
    __syncthreads();
  }
#pragma unroll
  for (int i = 0; i < 4; i++)
#pragma unroll
    for (int j = 0; j < 4; j++) {
      int cc = col0 + wn + j * 16 + l15;
      if (cc >= N) continue;
#pragma unroll
      for (int rg = 0; rg < 4; rg++) {
        int rr = row0 + wm + i * 16 + quad * 4 + rg;
        if (rr < M) C[(long)rr * ldc + cc] = acc[i][j][rg];
      }
    }
}

// ---------------- LSTM v13: 2 waves, 4 gate-rows per thread, zero exchange ----------------
// Thread e (0..127) computes ALL FOUR gate rows of element e: {e, 128+e, 256+e,
// 384+e} = (i,f,g,o). The cell update is entirely in-register: no gl[] buffer,
// no cross-thread gate exchange, no serial tail. h double-buffered in LDS ->
// exactly ONE raw s_barrier per step (lgkmcnt-only drain; VMEM in flight).
// Cost: per-wave dot issue doubles (256 fdot2) on 2 of 4 SIMDs - traded against
// v11's gl round-trip + 2 barriers + 2-wave serial tail. Weights wp[4][64]
// (256 VGPR) statically indexed, launch_bounds(128,1) for the 512-VGPR budget.
// Accumulation pairing and nonlinearity formulas bit-identical to v11.
__device__ __forceinline__ float tanh_fast(float x) {
  float e = __expf(2.f * x);
  return 1.f - 2.f / (e + 1.f);
}

__launch_bounds__(128, 1)
__global__ void k_lstm(const float* __restrict__ XW, const unsigned int* __restrict__ WhhP4,
                       float* __restrict__ Hout) {
  __shared__ __align__(16) unsigned int hl2[2][64];
  const int e = threadIdx.x;   // element 0..127
  const int n = blockIdx.x;
  const uint4* W4 = (const uint4*)WhhP4;
  unsigned int wp[4][64];
#pragma unroll
  for (int r = 0; r < 4; r++) {
    const int row = r * HH + e;
#pragma unroll
    for (int i4 = 0; i4 < 16; i4++) {
      uint4 v = W4[i4 * G4 + row];
      wp[r][4 * i4]     = v.x;
      wp[r][4 * i4 + 1] = v.y;
      wp[r][4 * i4 + 2] = v.z;
      wp[r][4 * i4 + 3] = v.w;
    }
  }
  float cst = 0.f;
  if (e < 64) hl2[0][e] = 0u;
  const float* xwrow = XW + (long)n * TT * G4 + e;   // row r is at offset r*HH
  float xn[4];
#pragma unroll
  for (int r = 0; r < 4; r++) xn[r] = xwrow[r * HH];
  float* hop = Hout + (long)n * TT * HH + e;
  __syncthreads();
  for (int t = 0; t < TT; t++) {
    const int cur = t & 1;
    float xv[4];
#pragma unroll
    for (int r = 0; r < 4; r++) xv[r] = xn[r];
    if (t + 1 < TT) {
      const float* p = xwrow + (long)(t + 1) * G4;
#pragma unroll
      for (int r = 0; r < 4; r++) xn[r] = p[r * HH];
    }
    const uint4* h4 = (const uint4*)hl2[cur];
    float a0[4] = {}, a1[4] = {}, a2[4] = {}, a3[4] = {};
#pragma unroll
    for (int k = 0; k < 16; k++) {
      uint4 hv4 = h4[k];   // uniform address -> LDS broadcast, conflict-free
#pragma unroll
      for (int r = 0; r < 4; r++) {
        a0[r] = __builtin_amdgcn_fdot2(__builtin_bit_cast(h2v, hv4.x), __builtin_bit_cast(h2v, wp[r][4 * k]),     a0[r], false);
        a1[r] = __builtin_amdgcn_fdot2(__builtin_bit_cast(h2v, hv4.y), __builtin_bit_cast(h2v, wp[r][4 * k + 1]), a1[r], false);
        a2[r] = __builtin_amdgcn_fdot2(__builtin_bit_cast(h2v, hv4.z), __builtin_bit_cast(h2v, wp[r][4 * k + 2]), a2[r], false);
        a3[r] = __builtin_amdgcn_fdot2(__builtin_bit_cast(h2v, hv4.w), __builtin_bit_cast(h2v, wp[r][4 * k + 3]), a3[r], false);
      }
    }
    float g[4];
#pragma unroll
    for (int r = 0; r < 4; r++) g[r] = ((a0[r] + a1[r]) + (a2[r] + a3[r])) + xv[r];
    float si = 1.f / (1.f + __expf(-g[0]));
    float sf = 1.f / (1.f + __expf(-g[1]));
    float tg = tanh_fast(g[2]);
    float so = 1.f / (1.f + __expf(-g[3]));
    cst = sf * cst + si * tg;
    float hv = so * tanh_fast(cst);
    ((_Float16*)hl2[cur ^ 1])[e] = (_Float16)hv;
    hop[(long)t * HH] = hv;
    asm volatile("s_waitcnt lgkmcnt(0)" ::: "memory");
    __builtin_amdgcn_s_barrier();
  }
}

// ---------------- mask GEMM (split-bf16 MFMA) + mask apply + transpose ----------------
// MS layout: [b][f][c][t] complex-interleaved (re,im)
__launch_bounds__(256)
__global__ void k_maskms(const float* __restrict__ Hout,
                         const unsigned short* __restrict__ Wsh,
                         const unsigned short* __restrict__ Wsl,
                         const float* __restrict__ bias, const float* __restrict__ S,
                         float* __restrict__ MS) {
  __shared__ __align__(16) unsigned short sAh[64 * 40];
  __shared__ __align__(16) unsigned short sAl[64 * 40];
  __shared__ __align__(16) unsigned short sBh[64 * 40];
  __shared__ __align__(16) unsigned short sBl[64 * 40];
  __shared__ float Cs[64][68];
  __shared__ float SR[64][33];
  __shared__ float SI[64][33];
  const int tid = threadIdx.x;
  const int f0 = blockIdx.x * 32;
  const int row0 = blockIdx.y * 64;
  const int lane = tid & 63, w = tid >> 6;
  const int wm = w * 16;
  const int l15 = lane & 15, quad = lane >> 4;
  const int sar = tid >> 2;
  const int sak = (tid & 3) * 8;
  const int np = ((sar < 32) ? 0 : 320 - 32) + f0 + sar;
  unsigned int* aH = (unsigned int*)sAh;
  unsigned int* aL = (unsigned int*)sAl;
  f32x4 acc[4] = {};
  for (int k0 = 0; k0 < HH; k0 += 32) {
    {
      const float* ap = Hout + (long)(row0 + sar) * HH + k0 + sak;
      float4 v0 = *(const float4*)ap;
      float4 v1 = *(const float4*)(ap + 4);
      float vv[8] = {v0.x, v0.y, v0.z, v0.w, v1.x, v1.y, v1.z, v1.w};
#pragma unroll
      for (int i = 0; i < 4; i++) {
        unsigned int h0 = __float_as_uint(vv[2 * i]) >> 16, h1 = __float_as_uint(vv[2 * i + 1]) >> 16;
        float r0 = vv[2 * i] - __uint_as_float(h0 << 16), r1 = vv[2 * i + 1] - __uint_as_float(h1 << 16);
        unsigned int l0 = __float_as_uint(r0) >> 16, l1 = __float_as_uint(r1) >> 16;
        aH[sar * 20 + (sak >> 1) + i] = h0 | (h1 << 16);
        aL[sar * 20 + (sak >> 1) + i] = l0 | (l1 << 16);
      }
    }
    {
      long go = (long)np * HH + k0 + sak;
      *(uint4*)(sBh + sar * 40 + sak) = *(const uint4*)(Wsh + go);
      *(uint4*)(sBl + sar * 40 + sak) = *(const uint4*)(Wsl + go);
    }
    __syncthreads();
    bf16x8 ah = *(const bf16x8*)(sAh + (wm + l15) * 40 + quad * 8);
    bf16x8 al = *(const bf16x8*)(sAl + (wm + l15) * 40 + quad * 8);
#pragma unroll
    for (int ct = 0; ct < 4; ct++) {
      bf16x8 bh = *(const bf16x8*)(sBh + (ct * 16 + l15) * 40 + quad * 8);
      bf16x8 bl = *(const bf16x8*)(sBl + (ct * 16 + l15) * 40 + quad * 8);
      acc[ct] = __builtin_amdgcn_mfma_f32_16x16x32_bf16(al, bh, acc[ct], 0, 0, 0);
      acc[ct] = __builtin_amdgcn_mfma_f32_16x16x32_bf16(ah, bl, acc[ct], 0, 0, 0);
      acc[ct] = __builtin_amdgcn_mfma_f32_16x16x32_bf16(ah, bh, acc[ct], 0, 0, 0);
    }
    __syncthreads();
  }
#pragma unroll
  for (int ct = 0; ct < 4; ct++) {
    int col = ct * 16 + l15;
    int f = f0 + (col & 31);
    int fcol = (col < 32) ? f : NF + f;
    float bv = (f < NF) ? bias[fcol] : 0.f;
#pragma unroll
    for (int rg = 0; rg < 4; rg++) Cs[wm + quad * 4 + rg][col] = acc[ct][rg] + bv;
  }
  __syncthreads();
  {
    int fl = tid & 31, r8 = tid >> 5;
    int f = f0 + fl;
#pragma unroll
    for (int i = 0; i < 8; i++) {
      int rl = r8 * 8 + i;
      int rr = row0 + rl;
      float rm = Cs[rl][fl], im = Cs[rl][32 + fl];
      float sr = 0.f, si = 0.f;
      if (f < NF) { sr = S[(long)rr * DD + f]; si = S[(long)rr * DD + NF + f]; }
      SR[rl][fl] = rm * sr - im * si;
      SI[rl][fl] = rm * si + im * sr;
    }
  }
  __syncthreads();
  {
    int tl = tid & 63, fq = tid >> 6;
    int rr = row0 + tl;
    int n = rr / TT, t = rr - n * TT;
    int b = n >> 3, c = n & 7;
#pragma unroll
    for (int i = 0; i < 8; i++) {
      int fl = fq * 8 + i;
      int f = f0 + fl;
      if (f < NF) {
        long addr = ((((long)b * NF + f) * 8 + c) * (long)TT + t) * 2;
        *(float2*)&MS[addr] = make_float2(SR[tl][fl], SI[tl][fl]);
      }
    }
  }
}

// ---------------- PSD: one block per (b,f); complex-interleaved MS ----------------
__launch_bounds__(256)
__global__ void k_psd(const float* __restrict__ MS, float* __restrict__ PSD) {
  __shared__ float buf[9616];
  __shared__ float part[64][8];
  const int tid = threadIdx.x;
  const long base = (long)blockIdx.x * 9616;
  for (int i = tid; i < 9616; i += 256) buf[i] = MS[base + i];
  __syncthreads();
  int p = tid & 63, q = tid >> 6;
  int c = p >> 3, e = p & 7;
  const float2* xc = (const float2*)&buf[c * 1202];
  const float2* xe = (const float2*)&buf[e * 1202];
  int t0 = q * 150, t1 = (q == 3) ? TT : t0 + 150;
  float ar = 0.f, ai = 0.f;
  for (int t = t0; t < t1; t++) {
    float2 m = xc[t];
    float2 v = xe[t];
    ar += m.x * v.x + m.y * v.y;
    ai += m.y * v.x - m.x * v.y;
  }
  part[p][q * 2] = ar; part[p][q * 2 + 1] = ai;
  __syncthreads();
  if (tid < 64) {
    float sr = part[tid][0] + part[tid][2] + part[tid][4] + part[tid][6];
    float si = part[tid][1] + part[tid][3] + part[tid][5] + part[tid][7];
    PSD[((long)blockIdx.x * 64 + tid) * 2]     = sr * (1.f / 601.f);
    PSD[((long)blockIdx.x * 64 + tid) * 2 + 1] = si * (1.f / 601.f);
  }
}

// ---------------- 8x8 complex solve + MVDR weight ----------------
__launch_bounds__(64)
__global__ void k_solve(const float* __restrict__ PS, const float* __restrict__ PN,
                        float* __restrict__ WV) {
  int idx = blockIdx.x * 64 + threadIdx.x;
  if (idx >= NB * NF) return;
  float Ar[8][8], Ai[8][8], Br[8][8], Bi[8][8];
  const float* pn = PN + (long)idx * 128;
  const float* ps = PS + (long)idx * 128;
  for (int i = 0; i < 8; i++)
    for (int j = 0; j < 8; j++) {
      Ar[i][j] = pn[(i * 8 + j) * 2]; Ai[i][j] = pn[(i * 8 + j) * 2 + 1];
      Br[i][j] = ps[(i * 8 + j) * 2]; Bi[i][j] = ps[(i * 8 + j) * 2 + 1];
    }
  float tr = 0.f;
  for (int i = 0; i < 8; i++) tr += Ar[i][i];
  float load = 1e-6f * tr / 8.f + 1e-8f;
  for (int i = 0; i < 8; i++) Ar[i][i] += load;
  for (int k = 0; k < 8; k++) {
    int piv = k; float mx = Ar[k][k] * Ar[k][k] + Ai[k][k] * Ai[k][k];
    for (int i = k + 1; i < 8; i++) {
      float m2 = Ar[i][k] * Ar[i][k] + Ai[i][k] * Ai[i][k];
      if (m2 > mx) { mx = m2; piv = i; }
    }
    if (piv != k) {
      for (int j = 0; j < 8; j++) {
        float t0;
        t0 = Ar[k][j]; Ar[k][j] = Ar[piv][j]; Ar[piv][j] = t0;
        t0 = Ai[k][j]; Ai[k][j] = Ai[piv][j]; Ai[piv][j] = t0;
        t0 = Br[k][j]; Br[k][j] = Br[piv][j]; Br[piv][j] = t0;
        t0 = Bi[k][j]; Bi[k][j] = Bi[piv][j]; Bi[piv][j] = t0;
      }
    }
    float dr = Ar[k][k], di = Ai[k][k];
    float inv = 1.f / (dr * dr + di * di);
    float irr = dr * inv, iii = -di * inv;
    for (int j = 0; j < 8; j++) {
      float xr = Ar[k][j], xi = Ai[k][j];
      Ar[k][j] = xr * irr - xi * iii; Ai[k][j] = xr * iii + xi * irr;
      xr = Br[k][j]; xi = Bi[k][j];
      Br[k][j] = xr * irr - xi * iii; Bi[k][j] = xr * iii + xi * irr;
    }
    for (int i = 0; i < 8; i++) {
      if (i == k) continue;
      float fr = Ar[i][k], fi = Ai[i][k];
      for (int j = 0; j < 8; j++) {
        float kr = Ar[k][j], ki = Ai[k][j];
        Ar[i][j] -= fr * kr - fi * ki;
        Ai[i][j] -= fr * ki + fi * kr;
        kr = Br[k][j]; ki = Bi[k][j];
        Br[i][j] -= fr * kr - fi * ki;
        Bi[i][j] -= fr * ki + fi * kr;
      }
    }
  }
  float trr = 1e-8f, tri = 0.f;
  for (int i = 0; i < 8; i++) { trr += Br[i][i]; tri += Bi[i][i]; }
  float inv = 1.f / (trr * trr + tri * tri);
  for (int c = 0; c < 8; c++) {
    float xr = Br[c][0], xi = Bi[c][0];
    WV[((long)idx * 8 + c) * 2]     = (xr * trr + xi * tri) * inv;
    WV[((long)idx * 8 + c) * 2 + 1] = (xi * trr - xr * tri) * inv;
  }
}

// ---------------- beamform -> pre-split ENH (KPAD rows) ----------------
__launch_bounds__(320)
__global__ void k_beam(const float* __restrict__ S, const float* __restrict__ WV,
                       unsigned short* __restrict__ ENHh, unsigned short* __restrict__ ENHl) {
  __shared__ float WL[NF * 16];
  int bb = blockIdx.x / TT, t = blockIdx.x - bb * TT;
  for (int i = threadIdx.x; i < NF * 16; i += 320) WL[i] = WV[(long)bb * NF * 16 + i];
  __syncthreads();
  int f = threadIdx.x;
  long base = ((long)bb * TT + t) * KPAD;
  if (f < NF) {
    float er = 0.f, ei = 0.f;
#pragma unroll
    for (int c = 0; c < 8; c++) {
      float wr = WL[(f * 8 + c) * 2], wi = WL[(f * 8 + c) * 2 + 1];
      const float* srow = S + (((long)(bb * 8 + c) * TT) + t) * DD;
      float sr = srow[f], si = srow[NF + f];
      er += wr * sr + wi * si;
      ei += wr * si - wi * sr;
    }
    split_bf16(er, &ENHh[base + f], &ENHl[base + f]);
    split_bf16(ei, &ENHh[base + NF + f], &ENHl[base + NF + f]);
  }
  int z = threadIdx.x - 288;   // threads 288..317 zero the 30 K-pad cols
  if (z >= 0 && z < 30) { ENHh[base + DD + z] = 0; ENHl[base + DD + z] = 0; }
}

// ---------------- overlap-add + normalize + crop ----------------
__global__ void k_ola(const float* __restrict__ IFR, const float* __restrict__ WSQ,
                      float* __restrict__ out) {
  int idx = blockIdx.x * 256 + threadIdx.x;
  if (idx >= NB * LSEQ) return;
  int b = idx / LSEQ, l = idx - b * LSEQ;
  int p = l + FPAD;
  int t0 = (p <= 511) ? 0 : (p - 352) / 160;
  int t1 = p / 160; if (t1 > 600) t1 = 600;
  float s = 0.f;
  for (int t = t0; t <= t1; t++) s += IFR[((long)b * TT + t) * NFFT + (p - t * HOP)];
  out[idx] = s / fmaxf(WSQ[p], 1e-11f);
}

// ---------------- driver ----------------
extern "C" void kernel_launch(void* const* d_in, const int* in_sizes, int n_in,
                              void* d_out, int out_size, void* d_ws, size_t ws_size,
                              hipStream_t stream) {
  (void)in_sizes; (void)n_in; (void)out_size; (void)ws_size;
  const float* x   = (const float*)d_in[0];
  const float* Wih = (const float*)d_in[1];
  const float* Whh = (const float*)d_in[2];
  const float* bih = (const float*)d_in[3];
  const float* bhh = (const float*)d_in[4];
  const float* W1  = (const float*)d_in[5];
  const float* b1  = (const float*)d_in[6];
  const float* W2  = (const float*)d_in[7];
  const float* b2  = (const float*)d_in[8];
  float* ws = (float*)d_ws;

  // XP region: pre-split XPh/XPl (exactly fills old XP fp32 footprint); IFR aliases later.
  unsigned short* XPh = (unsigned short*)(ws + 0);            // 6,176,768 ush = 3,088,384 fl
  unsigned short* XPl = (unsigned short*)(ws + 3088384);      // -> region ends 6,176,768 fl
  float* S     = ws + 6176768;    // 19,774,496
  float* XWM   = ws + 25951264;   // 19,774,496 (XW then MS; WhhP4 in tail)
  float* HOUT  = ws + 45725760;   // 4,924,288 (pre-GEMM scratch + post-beam ENH split live here too)
  float* PSD_S = ws + 50650048;   // 263,168
  float* PSD_N = ws + 50913216;   // 263,168
  float* WV    = ws + 51176384;   // 32,896
  float* BSUM  = ws + 51209280;   // 512
  float* WSQ   = ws + 51209792;   // 96,512 -> 51,306,304
  unsigned short* W1sh = (unsigned short*)(ws + 51306304);
  unsigned short* W1sl = (unsigned short*)(ws + 51347264);
  unsigned short* W2sh = (unsigned short*)(ws + 51388224);
  unsigned short* W2sl = (unsigned short*)(ws + 51429184); // -> 51,470,144
  unsigned short* WTth = (unsigned short*)(ws + 51470144); // 139,264 fl
  unsigned short* WTtl = (unsigned short*)(ws + 51609408); // -> 51,748,672
  unsigned short* BIth = (unsigned short*)(ws + 51748672); // 139,264 fl
  unsigned short* BItl = (unsigned short*)(ws + 51887936); // -> end 52,027,200 (~208 MB)
  float* MS    = XWM;
  float* IFR   = ws + 0;          // aliases XP region after gemm4
  unsigned int* WhhP4 = (unsigned int*)(XWM + 19693568);   // after true end of XW
  // Pre-GEMM scratch inside HOUT (dead until k_lstm):
  float* BFf = HOUT;                                        // 263,168 fl
  float* BWf = HOUT + 263168;                               // 262,144 fl
  unsigned short* BCh = (unsigned short*)(HOUT + 525312);   // 1152*544 ush = 313,344 fl
  unsigned short* BCl = (unsigned short*)(HOUT + 838656);   // -> 1,152,000 fl < 4,924,288
  // Post-beam ENH split in HOUT (Hout consumed by maskms before k_beam):
  unsigned short* ENHh = (unsigned short*)HOUT;             // 4808*544 ush = 1,307,776 fl
  unsigned short* ENHl = (unsigned short*)(HOUT + 1307776);

  k_wsq<<<(XPLEN + 255) / 256, 256, 0, stream>>>(WSQ);
  k_bff<<<(NFFT * DD + 255) / 256, 256, 0, stream>>>(BFf);
  k_wtsplit<<<(G4 * KPAD + 255) / 256, 256, 0, stream>>>(Wih, WTth, WTtl);
  k_bisplit<<<(NFFT * KPAD + 255) / 256, 256, 0, stream>>>(BIth, BItl);
  k_bsum<<<2, 256, 0, stream>>>(bih, bhh, BSUM);
  k_wmsplit<<<(2 * 640 * HH + 255) / 256, 256, 0, stream>>>(W1, W2, W1sh, W1sl, W2sh, W2sl);
  k_wpack<<<(G4 * 64 + 255) / 256, 256, 0, stream>>>(Whh, WhhP4);
  k_xp<<<(NSEQ * XPLEN + 255) / 256, 256, 0, stream>>>(x, XPh, XPl);

  // BW = BF @ Wih^T  (512x512, K=514) — small gemm3
  {
    dim3 g(4, 4);
    k_gemm3<0><<<g, 256, 0, stream>>>(BFf, WTth, WTtl, nullptr, BWf, 512, 512, DD, DD, G4);
  }
  // combined split B = [BF | BW]
  k_bcomb<<<(1152 * KPAD + 255) / 256, 256, 0, stream>>>(BWf, BCh, BCl);

  // fused STFT + xW: S[38464,514] and XW[38464,512] in one gather-GEMM
  {
    dim3 g(9, 301);
    k_gemm4<<<g, 256, 0, stream>>>(XPh, XPl, BCh, BCl, BSUM, S, XWM);
  }

  k_lstm<<<64, 128, 0, stream>>>(XWM, WhhP4, HOUT);

  dim3 gm(9, 601);
  k_maskms<<<gm, 256, 0, stream>>>(HOUT, W1sh, W1sl, b1, S, MS);
  k_psd<<<NB * NF, 256, 0, stream>>>(MS, PSD_S);
  k_maskms<<<gm, 256, 0, stream>>>(HOUT, W2sh, W2sl, b2, S, MS);
  k_psd<<<NB * NF, 256, 0, stream>>>(MS, PSD_N);

  k_solve<<<(NB * NF + 63) / 64, 64, 0, stream>>>(PSD_S, PSD_N, WV);
  k_beam<<<NB * TT, 320, 0, stream>>>(S, WV, ENHh, ENHl);

  // iSTFT: IFR[4808,512] = ENH @ BI (pre-split A)
  {
    dim3 g(4, 38);
    k_gemm5<<<g, 256, 0, stream>>>(ENHh, ENHl, BIth, BItl, IFR, NB * TT, NFFT, NFFT);
  }

  k_ola<<<(NB * LSEQ + 255) / 256, 256, 0, stream>>>(IFR, WSQ, (float*)d_out);
}

// Round 6
// 1167.452 us; speedup vs baseline: 1.3226x; 1.3226x over previous
//
#include <hip/hip_runtime.h>
#include <math.h>

#define NFFT  512
#define WINL  320
#define HOP   160
#define FPAD  256
#define NF    257
#define TT    601
#define LSEQ  96000
#define XPLEN 96512
#define NCH   8
#define NB    8
#define NSEQ  64
#define NROWS 38464   // NSEQ*TT
#define DD    514
#define HH    128
#define G4    512
#define KPAD  544     // 17*32, zero-padded K for split-B arrays
#define NCOMB 1026    // 514 (S cols) + 512 (XW cols)

typedef _Float16 h2v __attribute__((ext_vector_type(2)));
typedef short bf16x8 __attribute__((ext_vector_type(8)));
typedef float f32x4 __attribute__((ext_vector_type(4)));

// ---------------- init helpers ----------------
__device__ __forceinline__ float winval(int k) {
  if (k < 96 || k >= 416) return 0.f;
  return 0.5f - 0.5f * cosf((float)(2.0 * M_PI / 320.0) * (float)(k - 96));
}

__device__ __forceinline__ void split_bf16(float v, unsigned short* h, unsigned short* l) {
  unsigned int hb = __float_as_uint(v) >> 16;
  float r = v - __uint_as_float(hb << 16);
  *h = (unsigned short)hb;
  *l = (unsigned short)(__float_as_uint(r) >> 16);
}

__global__ void k_wsq(float* __restrict__ wsq) {
  int p = blockIdx.x * 256 + threadIdx.x;
  if (p >= XPLEN) return;
  int t0 = (p <= 511) ? 0 : (p - 352) / 160;
  int t1 = p / 160; if (t1 > 600) t1 = 600;
  float s = 0.f;
  for (int t = t0; t <= t1; t++) { float w = winval(p - t * HOP); s += w * w; }
  wsq[p] = s;
}

// fp32 forward-DFT matrix BFf[k][d] (512 x 514), for the BW precompute GEMM
__global__ void k_bff(float* __restrict__ BFf) {
  int idx = blockIdx.x * 256 + threadIdx.x;
  if (idx >= NFFT * DD) return;
  int k = idx / DD, d = idx - k * DD;
  float w = winval(k);
  int f = (d < NF) ? d : d - NF;
  int m = (k * f) & 511;
  float th = (float)(M_PI / 256.0) * (float)m;
  BFf[idx] = ((d < NF) ? cosf(th) : -sinf(th)) * w;
}

// WT split: Bt[n][k] = Wih[n][k]  (used by the BW precompute)
__global__ void k_wtsplit(const float* __restrict__ Wih, unsigned short* __restrict__ H,
                          unsigned short* __restrict__ L) {
  int idx = blockIdx.x * 256 + threadIdx.x;
  if (idx >= G4 * KPAD) return;
  int n = idx / KPAD, k = idx - n * KPAD;
  float v = (k < DD) ? Wih[n * DD + k] : 0.f;
  split_bf16(v, &H[idx], &L[idx]);
}

// Combined split B for the fused STFT+xW GEMM: BC[n][k], n in [0,1152)
__global__ void k_bcomb(const float* __restrict__ BWf, unsigned short* __restrict__ H,
                        unsigned short* __restrict__ L) {
  int idx = blockIdx.x * 256 + threadIdx.x;
  if (idx >= 1152 * KPAD) return;
  int n = idx / KPAD, k = idx - n * KPAD;
  float v = 0.f;
  if (k < NFFT) {
    if (n < DD) {
      float w = winval(k);
      int f = (n < NF) ? n : n - NF;
      int m = (k * f) & 511;
      float th = (float)(M_PI / 256.0) * (float)m;
      v = ((n < NF) ? cosf(th) : -sinf(th)) * w;
    } else if (n < NCOMB) {
      v = BWf[k * G4 + (n - 514)];
    }
  }
  split_bf16(v, &H[idx], &L[idx]);
}

// BI split: Bt[n][kk] = BI[kk][n]
__global__ void k_bisplit(unsigned short* __restrict__ H, unsigned short* __restrict__ L) {
  int idx = blockIdx.x * 256 + threadIdx.x;
  if (idx >= NFFT * KPAD) return;
  int n = idx / KPAD, kk = idx - n * KPAD;
  float v = 0.f;
  if (kk < DD) {
    float w = winval(n);
    int f = (kk < NF) ? kk : kk - NF;
    int edge = (f == 0 || f == 256);
    float alpha = edge ? 1.f : 2.f;
    int m = (n * f) & 511;
    float th = (float)(M_PI / 256.0) * (float)m;
    float c;
    if (kk < NF) c = alpha * cosf(th);
    else         c = edge ? 0.f : -alpha * sinf(th);
    v = c * w * (1.f / 512.f);
  }
  split_bf16(v, &H[idx], &L[idx]);
}

__global__ void k_bsum(const float* __restrict__ bih, const float* __restrict__ bhh,
                       float* __restrict__ BSUM) {
  int idx = blockIdx.x * 256 + threadIdx.x;
  if (idx < G4) BSUM[idx] = bih[idx] + bhh[idx];
}

// W1/W2 mask-weight split: Ws[n'][k], n' = ri*320 + f
__global__ void k_wmsplit(const float* __restrict__ W1, const float* __restrict__ W2,
                          unsigned short* __restrict__ W1h, unsigned short* __restrict__ W1l,
                          unsigned short* __restrict__ W2h, unsigned short* __restrict__ W2l) {
  int idx = blockIdx.x * 256 + threadIdx.x;
  if (idx >= 2 * 640 * HH) return;
  int m = idx / (640 * HH);
  int rem = idx - m * 640 * HH;
  int np = rem / HH, k = rem - np * HH;
  int ri = np / 320, f = np - ri * 320;
  float v = 0.f;
  if (f < NF) {
    int fcol = (ri == 0) ? f : NF + f;
    v = (m == 0) ? W1[fcol * HH + k] : W2[fcol * HH + k];
  }
  unsigned short h, l;
  split_bf16(v, &h, &l);
  if (m == 0) { W1h[rem] = h; W1l[rem] = l; }
  else        { W2h[rem] = h; W2l[rem] = l; }
}

// pack Whh into f16 pairs, uint4-transposed (v8 layout, indexed by gate row)
__global__ void k_wpack(const float* __restrict__ Whh, unsigned int* __restrict__ WhhP4) {
  int idx = blockIdx.x * 256 + threadIdx.x;
  if (idx >= G4 * 64) return;
  int j = idx >> 6, k2 = idx & 63;
  _Float16 lo = (_Float16)Whh[j * HH + 2 * k2];
  _Float16 hi = (_Float16)Whh[j * HH + 2 * k2 + 1];
  unsigned int u = ((unsigned int)__builtin_bit_cast(unsigned short, hi) << 16)
                 |  (unsigned int)__builtin_bit_cast(unsigned short, lo);
  WhhP4[(k2 >> 2) * (G4 * 4) + j * 4 + (k2 & 3)] = u;
}

// reflect-padded multichannel extraction, pre-split to bf16 hi/lo: XPh/XPl[n][i]
__global__ void k_xp(const float* __restrict__ x, unsigned short* __restrict__ XPh,
                     unsigned short* __restrict__ XPl) {
  int idx = blockIdx.x * 256 + threadIdx.x;
  if (idx >= NSEQ * XPLEN) return;
  int n = idx / XPLEN, i = idx - n * XPLEN;
  int j = i - FPAD;
  if (j < 0) j = -j;
  else if (j >= LSEQ) j = 2 * LSEQ - 2 - j;
  int b = n >> 3, c = n & 7;
  float v = x[((long)b * LSEQ + j) * NCH + c];
  split_bf16(v, &XPh[idx], &XPl[idx]);
}

// ---------------- split-bf16 MFMA GEMM (fp32 A): C[M,N] = A[M,K] * Bt^T (+bias) ----------------
template <int GATHER>
__launch_bounds__(256)
__global__ void k_gemm3(const float* __restrict__ A,
                        const unsigned short* __restrict__ Bth,
                        const unsigned short* __restrict__ Btl,
                        const float* __restrict__ bias, float* __restrict__ C,
                        int M, int N, int K, int lda, int ldc) {
  __shared__ __align__(16) unsigned short sAh[128 * 40];
  __shared__ __align__(16) unsigned short sAl[128 * 40];
  __shared__ __align__(16) unsigned short sBh[128 * 40];
  __shared__ __align__(16) unsigned short sBl[128 * 40];
  const int tid = threadIdx.x;
  const int row0 = blockIdx.y * 128, col0 = blockIdx.x * 128;
  const int sar = tid >> 1, sak = (tid & 1) * 16;
  const int arow = row0 + sar;
  long abase = (long)arow * lda;
  const bool arok = (arow < M);
  const int lane = tid & 63, w = tid >> 6;
  const int wm = (w >> 1) * 64, wn = (w & 1) * 64;
  const int l15 = lane & 15, quad = lane >> 4;
  f32x4 acc[4][4] = {};
  unsigned int* aH = (unsigned int*)sAh;
  unsigned int* aL = (unsigned int*)sAl;
  uint4* bH = (uint4*)sBh;
  uint4* bL = (uint4*)sBl;
  for (int k0 = 0; k0 < K; k0 += 32) {
#pragma unroll
    for (int i = 0; i < 8; i++) {
      int kk = k0 + sak + 2 * i;
      float v0 = 0.f, v1 = 0.f;
      if (arok) {
        if (kk + 1 < K) { float2 t2 = *(const float2*)(A + abase + kk); v0 = t2.x; v1 = t2.y; }
        else if (kk < K) { v0 = A[abase + kk]; }
      }
      unsigned int h0 = __float_as_uint(v0) >> 16, h1 = __float_as_uint(v1) >> 16;
      float r0 = v0 - __uint_as_float(h0 << 16), r1 = v1 - __uint_as_float(h1 << 16);
      unsigned int l0 = __float_as_uint(r0) >> 16, l1 = __float_as_uint(r1) >> 16;
      aH[sar * 20 + (sak >> 1) + i] = h0 | (h1 << 16);
      aL[sar * 20 + (sak >> 1) + i] = l0 | (l1 << 16);
    }
#pragma unroll
    for (int h = 0; h < 2; h++) {
      int idx = tid + h * 256;
      int r = idx >> 2, c = idx & 3;
      long go = (long)(col0 + r) * KPAD + k0 + c * 8;
      bH[r * 5 + c] = *(const uint4*)(Bth + go);
      bL[r * 5 + c] = *(const uint4*)(Btl + go);
    }
    __syncthreads();
    bf16x8 ah[4], al[4], bh[4], bl[4];
#pragma unroll
    for (int i = 0; i < 4; i++) {
      int off = (wm + i * 16 + l15) * 40 + quad * 8;
      ah[i] = *(const bf16x8*)(sAh + off);
      al[i] = *(const bf16x8*)(sAl + off);
      int boff = (wn + i * 16 + l15) * 40 + quad * 8;
      bh[i] = *(const bf16x8*)(sBh + boff);
      bl[i] = *(const bf16x8*)(sBl + boff);
    }
#pragma unroll
    for (int i = 0; i < 4; i++)
#pragma unroll
      for (int j = 0; j < 4; j++) {
        acc[i][j] = __builtin_amdgcn_mfma_f32_16x16x32_bf16(al[i], bh[j], acc[i][j], 0, 0, 0);
        acc[i][j] = __builtin_amdgcn_mfma_f32_16x16x32_bf16(ah[i], bl[j], acc[i][j], 0, 0, 0);
        acc[i][j] = __builtin_amdgcn_mfma_f32_16x16x32_bf16(ah[i], bh[j], acc[i][j], 0, 0, 0);
      }
    __syncthreads();
  }
#pragma unroll
  for (int i = 0; i < 4; i++)
#pragma unroll
    for (int j = 0; j < 4; j++) {
      int cc = col0 + wn + j * 16 + l15;
      if (cc >= N) continue;
      float bv = bias ? bias[cc] : 0.f;
#pragma unroll
      for (int rg = 0; rg < 4; rg++) {
        int rr = row0 + wm + i * 16 + quad * 4 + rg;
        if (rr < M) C[(long)rr * ldc + cc] = acc[i][j][rg] + bv;
      }
    }
}

// ---------------- fused STFT+xW GEMM: pre-split A (gathered XP), combined B ----------------
// C[38464, 1026]: cols <514 -> S; cols 514..1025 -> XW (+bsum). K=512, tile 128x128.
__launch_bounds__(256)
__global__ void k_gemm4(const unsigned short* __restrict__ Ah, const unsigned short* __restrict__ Al,
                        const unsigned short* __restrict__ Bh, const unsigned short* __restrict__ Bl,
                        const float* __restrict__ bsum, float* __restrict__ S,
                        float* __restrict__ XW) {
  __shared__ __align__(16) unsigned short sAh[128 * 40];
  __shared__ __align__(16) unsigned short sAl[128 * 40];
  __shared__ __align__(16) unsigned short sBh[128 * 40];
  __shared__ __align__(16) unsigned short sBl[128 * 40];
  const int tid = threadIdx.x;
  const int row0 = blockIdx.y * 128, col0 = blockIdx.x * 128;
  const int sr0 = tid >> 2, c4 = (tid & 3) * 8, cq = tid & 3;
  long ab0, ab1;
  { int rr = row0 + sr0;      int n = rr / TT, t = rr - n * TT; ab0 = (long)n * XPLEN + (long)t * HOP; }
  { int rr = row0 + sr0 + 64; int n = rr / TT, t = rr - n * TT; ab1 = (long)n * XPLEN + (long)t * HOP; }
  const int lane = tid & 63, w = tid >> 6;
  const int wm = (w >> 1) * 64, wn = (w & 1) * 64;
  const int l15 = lane & 15, quad = lane >> 4;
  f32x4 acc[4][4] = {};
  uint4* aH4 = (uint4*)sAh; uint4* aL4 = (uint4*)sAl;
  uint4* bH4 = (uint4*)sBh; uint4* bL4 = (uint4*)sBl;
  for (int k0 = 0; k0 < NFFT; k0 += 32) {
    aH4[sr0 * 5 + cq]        = *(const uint4*)(Ah + ab0 + k0 + c4);
    aL4[sr0 * 5 + cq]        = *(const uint4*)(Al + ab0 + k0 + c4);
    aH4[(sr0 + 64) * 5 + cq] = *(const uint4*)(Ah + ab1 + k0 + c4);
    aL4[(sr0 + 64) * 5 + cq] = *(const uint4*)(Al + ab1 + k0 + c4);
    {
      long go = (long)(col0 + sr0) * KPAD + k0 + c4;
      bH4[sr0 * 5 + cq] = *(const uint4*)(Bh + go);
      bL4[sr0 * 5 + cq] = *(const uint4*)(Bl + go);
      go = (long)(col0 + sr0 + 64) * KPAD + k0 + c4;
      bH4[(sr0 + 64) * 5 + cq] = *(const uint4*)(Bh + go);
      bL4[(sr0 + 64) * 5 + cq] = *(const uint4*)(Bl + go);
    }
    __syncthreads();
    bf16x8 ah[4], al[4], bh[4], bl[4];
#pragma unroll
    for (int i = 0; i < 4; i++) {
      int off = (wm + i * 16 + l15) * 40 + quad * 8;
      ah[i] = *(const bf16x8*)(sAh + off);
      al[i] = *(const bf16x8*)(sAl + off);
      int boff = (wn + i * 16 + l15) * 40 + quad * 8;
      bh[i] = *(const bf16x8*)(sBh + boff);
      bl[i] = *(const bf16x8*)(sBl + boff);
    }
#pragma unroll
    for (int i = 0; i < 4; i++)
#pragma unroll
      for (int j = 0; j < 4; j++) {
        acc[i][j] = __builtin_amdgcn_mfma_f32_16x16x32_bf16(al[i], bh[j], acc[i][j], 0, 0, 0);
        acc[i][j] = __builtin_amdgcn_mfma_f32_16x16x32_bf16(ah[i], bl[j], acc[i][j], 0, 0, 0);
        acc[i][j] = __builtin_amdgcn_mfma_f32_16x16x32_bf16(ah[i], bh[j], acc[i][j], 0, 0, 0);
      }
    __syncthreads();
  }
#pragma unroll
  for (int i = 0; i < 4; i++)
#pragma unroll
    for (int j = 0; j < 4; j++) {
      int cc = col0 + wn + j * 16 + l15;
      if (cc >= NCOMB) continue;
#pragma unroll
      for (int rg = 0; rg < 4; rg++) {
        int rr = row0 + wm + i * 16 + quad * 4 + rg;
        if (rr >= NROWS) continue;
        float v = acc[i][j][rg];
        if (cc < DD) S[(long)rr * DD + cc] = v;
        else         XW[(long)rr * G4 + (cc - 514)] = v + bsum[cc - 514];
      }
    }
}

// ---------------- iSTFT GEMM: pre-split A (pitch KPAD), B = BI split ----------------
__launch_bounds__(256)
__global__ void k_gemm5(const unsigned short* __restrict__ Ah, const unsigned short* __restrict__ Al,
                        const unsigned short* __restrict__ Bh, const unsigned short* __restrict__ Bl,
                        float* __restrict__ C, int M, int N, int ldc) {
  __shared__ __align__(16) unsigned short sAh[128 * 40];
  __shared__ __align__(16) unsigned short sAl[128 * 40];
  __shared__ __align__(16) unsigned short sBh[128 * 40];
  __shared__ __align__(16) unsigned short sBl[128 * 40];
  const int tid = threadIdx.x;
  const int row0 = blockIdx.y * 128, col0 = blockIdx.x * 128;
  const int sr0 = tid >> 2, c4 = (tid & 3) * 8, cq = tid & 3;
  const int lane = tid & 63, w = tid >> 6;
  const int wm = (w >> 1) * 64, wn = (w & 1) * 64;
  const int l15 = lane & 15, quad = lane >> 4;
  f32x4 acc[4][4] = {};
  uint4* aH4 = (uint4*)sAh; uint4* aL4 = (uint4*)sAl;
  uint4* bH4 = (uint4*)sBh; uint4* bL4 = (uint4*)sBl;
  for (int k0 = 0; k0 < KPAD; k0 += 32) {
    {
      long go = (long)(row0 + sr0) * KPAD + k0 + c4;
      aH4[sr0 * 5 + cq] = *(const uint4*)(Ah + go);
      aL4[sr0 * 5 + cq] = *(const uint4*)(Al + go);
      go = (long)(row0 + sr0 + 64) * KPAD + k0 + c4;
      aH4[(sr0 + 64) * 5 + cq] = *(const uint4*)(Ah + go);
      aL4[(sr0 + 64) * 5 + cq] = *(const uint4*)(Al + go);
    }
    {
      long go = (long)(col0 + sr0) * KPAD + k0 + c4;
      bH4[sr0 * 5 + cq] = *(const uint4*)(Bh + go);
      bL4[sr0 * 5 + cq] = *(const uint4*)(Bl + go);
      go = (long)(col0 + sr0 + 64) * KPAD + k0 + c4;
      bH4[(sr0 + 64) * 5 + cq] = *(const uint4*)(Bh + go);
      bL4[(sr0 + 64) * 5 + cq] = *(const uint4*)(Bl + go);
    }
    __syncthreads();
    bf16x8 ah[4], al[4], bh[4], bl[4];
#pragma unroll
    for (int i = 0; i < 4; i++) {
      int off = (wm + i * 16 + l15) * 40 + quad * 8;
      ah[i] = *(const bf16x8*)(sAh + off);
      al[i] = *(const bf16x8*)(sAl + off);
      int boff = (wn + i * 16 + l15) * 40 + quad * 8;
      bh[i] = *(const bf16x8*)(sBh + boff);
      bl[i] = *(const bf16x8*)(sBl + boff);
    }
#pragma unroll
    for (int i = 0; i < 4; i++)
#pragma unroll
      for (int j = 0; j < 4; j++) {
        acc[i][j] = __builtin_amdgcn_mfma_f32_16x16x32_bf16(al[i], bh[j], acc[i][j], 0, 0, 0);
        acc[i][j] = __builtin_amdgcn_mfma_f32_16x16x32_bf16(ah[i], bl[j], acc[i][j], 0, 0, 0);
        acc[i][j] = __builtin_amdgcn_mfma_f32_16x16x32_bf16(ah[i], bh[j], acc[i][j], 0, 0, 0);
      }
    __syncthreads();
  }
#pragma unroll
  for (int i = 0; i < 4; i++)
#pragma unroll
    for (int j = 0; j < 4; j++) {
      int cc = col0 + wn + j * 16 + l15;
      if (cc >= N) continue;
#pragma unroll
      for (int rg = 0; rg < 4; rg++) {
        int rr = row0 + wm + i * 16 + quad * 4 + rg;
        if (rr < M) C[(long)rr * ldc + cc] = acc[i][j][rg];
      }
    }
}

// ---------------- LSTM v14: v11 structure (proven best) + 2-deep xnext prefetch ----------------
// v11 = v8 + (a) raw s_barrier with lgkmcnt-only drain (VMEM stays in flight),
// (b) h broadcast via uniform ds_read_b128, (c) distributed nonlinearity.
// v14 adds: XW prefetch issued TWO steps ahead (consume at t from a load issued
// at t-2) -> ~2600-cycle window vs HBM/L3 latency of 400-900 cycles, instead of
// the marginal ~1300-cycle single-step window. One extra VGPR; arithmetic
// bit-identical to v11.
__device__ __forceinline__ float tanh_fast(float x) {
  float e = __expf(2.f * x);
  return 1.f - 2.f / (e + 1.f);
}

__launch_bounds__(512, 2)
__global__ void k_lstm(const float* __restrict__ XW, const unsigned int* __restrict__ WhhP4,
                       float* __restrict__ Hout) {
  __shared__ __align__(16) unsigned int hl2[64];
  __shared__ float gl[G4];
  const int j = threadIdx.x;
  const int n = blockIdx.x;
  const uint4* W4 = (const uint4*)WhhP4;
  unsigned int wp[64];
#pragma unroll
  for (int i4 = 0; i4 < 16; i4++) {
    uint4 v = W4[i4 * G4 + j];
    wp[4 * i4]     = v.x;
    wp[4 * i4 + 1] = v.y;
    wp[4 * i4 + 2] = v.z;
    wp[4 * i4 + 3] = v.w;
  }
  float cst = 0.f;
  if (j < 64) hl2[j] = 0u;
  const float* xwrow = XW + (long)n * TT * G4 + j;
  float xnext  = xwrow[0];
  float xnext2 = xwrow[G4];          // TT >= 2 always
  const uint4* h4 = (const uint4*)hl2;
  const bool isg = (j >= 2 * HH) && (j < 3 * HH);   // 'g' gate rows -> tanh, else sigmoid
  __syncthreads();
  for (int t = 0; t < TT; t++) {
    float xv = xnext;
    xnext = xnext2;
    if (t + 2 < TT) xnext2 = xwrow[(long)(t + 2) * G4];
    float a0 = 0.f, a1 = 0.f, a2 = 0.f, a3 = 0.f;
#pragma unroll
    for (int k = 0; k < 16; k++) {
      uint4 hv4 = h4[k];   // uniform address -> LDS broadcast, conflict-free
      a0 = __builtin_amdgcn_fdot2(__builtin_bit_cast(h2v, hv4.x), __builtin_bit_cast(h2v, wp[4 * k]),     a0, false);
      a1 = __builtin_amdgcn_fdot2(__builtin_bit_cast(h2v, hv4.y), __builtin_bit_cast(h2v, wp[4 * k + 1]), a1, false);
      a2 = __builtin_amdgcn_fdot2(__builtin_bit_cast(h2v, hv4.z), __builtin_bit_cast(h2v, wp[4 * k + 2]), a2, false);
      a3 = __builtin_amdgcn_fdot2(__builtin_bit_cast(h2v, hv4.w), __builtin_bit_cast(h2v, wp[4 * k + 3]), a3, false);
    }
    float a = ((a0 + a1) + (a2 + a3)) + xv;
    float nl;
    if (isg) nl = tanh_fast(a);
    else     nl = 1.f / (1.f + __expf(-a));
    gl[j] = nl;
    asm volatile("s_waitcnt lgkmcnt(0)" ::: "memory");
    __builtin_amdgcn_s_barrier();
    if (j < HH) {
      float ni = gl[j], nf = gl[HH + j], ng = gl[2 * HH + j], no = gl[3 * HH + j];
      cst = nf * cst + ni * ng;
      float hv = no * tanh_fast(cst);
      ((_Float16*)hl2)[j] = (_Float16)hv;
      Hout[((long)n * TT + t) * HH + j] = hv;
    }
    asm volatile("s_waitcnt lgkmcnt(0)" ::: "memory");
    __builtin_amdgcn_s_barrier();
  }
}

// ---------------- mask GEMM (split-bf16 MFMA) + mask apply + transpose ----------------
// MS layout: [b][f][c][t] complex-interleaved (re,im)
__launch_bounds__(256)
__global__ void k_maskms(const float* __restrict__ Hout,
                         const unsigned short* __restrict__ Wsh,
                         const unsigned short* __restrict__ Wsl,
                         const float* __restrict__ bias, const float* __restrict__ S,
                         float* __restrict__ MS) {
  __shared__ __align__(16) unsigned short sAh[64 * 40];
  __shared__ __align__(16) unsigned short sAl[64 * 40];
  __shared__ __align__(16) unsigned short sBh[64 * 40];
  __shared__ __align__(16) unsigned short sBl[64 * 40];
  __shared__ float Cs[64][68];
  __shared__ float SR[64][33];
  __shared__ float SI[64][33];
  const int tid = threadIdx.x;
  const int f0 = blockIdx.x * 32;
  const int row0 = blockIdx.y * 64;
  const int lane = tid & 63, w = tid >> 6;
  const int wm = w * 16;
  const int l15 = lane & 15, quad = lane >> 4;
  const int sar = tid >> 2;
  const int sak = (tid & 3) * 8;
  const int np = ((sar < 32) ? 0 : 320 - 32) + f0 + sar;
  unsigned int* aH = (unsigned int*)sAh;
  unsigned int* aL = (unsigned int*)sAl;
  f32x4 acc[4] = {};
  for (int k0 = 0; k0 < HH; k0 += 32) {
    {
      const float* ap = Hout + (long)(row0 + sar) * HH + k0 + sak;
      float4 v0 = *(const float4*)ap;
      float4 v1 = *(const float4*)(ap + 4);
      float vv[8] = {v0.x, v0.y, v0.z, v0.w, v1.x, v1.y, v1.z, v1.w};
#pragma unroll
      for (int i = 0; i < 4; i++) {
        unsigned int h0 = __float_as_uint(vv[2 * i]) >> 16, h1 = __float_as_uint(vv[2 * i + 1]) >> 16;
        float r0 = vv[2 * i] - __uint_as_float(h0 << 16), r1 = vv[2 * i + 1] - __uint_as_float(h1 << 16);
        unsigned int l0 = __float_as_uint(r0) >> 16, l1 = __float_as_uint(r1) >> 16;
        aH[sar * 20 + (sak >> 1) + i] = h0 | (h1 << 16);
        aL[sar * 20 + (sak >> 1) + i] = l0 | (l1 << 16);
      }
    }
    {
      long go = (long)np * HH + k0 + sak;
      *(uint4*)(sBh + sar * 40 + sak) = *(const uint4*)(Wsh + go);
      *(uint4*)(sBl + sar * 40 + sak) = *(const uint4*)(Wsl + go);
    }
    __syncthreads();
    bf16x8 ah = *(const bf16x8*)(sAh + (wm + l15) * 40 + quad * 8);
    bf16x8 al = *(const bf16x8*)(sAl + (wm + l15) * 40 + quad * 8);
#pragma unroll
    for (int ct = 0; ct < 4; ct++) {
      bf16x8 bh = *(const bf16x8*)(sBh + (ct * 16 + l15) * 40 + quad * 8);
      bf16x8 bl = *(const bf16x8*)(sBl + (ct * 16 + l15) * 40 + quad * 8);
      acc[ct] = __builtin_amdgcn_mfma_f32_16x16x32_bf16(al, bh, acc[ct], 0, 0, 0);
      acc[ct] = __builtin_amdgcn_mfma_f32_16x16x32_bf16(ah, bl, acc[ct], 0, 0, 0);
      acc[ct] = __builtin_amdgcn_mfma_f32_16x16x32_bf16(ah, bh, acc[ct], 0, 0, 0);
    }
    __syncthreads();
  }
#pragma unroll
  for (int ct = 0; ct < 4; ct++) {
    int col = ct * 16 + l15;
    int f = f0 + (col & 31);
    int fcol = (col < 32) ? f : NF + f;
    float bv = (f < NF) ? bias[fcol] : 0.f;
#pragma unroll
    for (int rg = 0; rg < 4; rg++) Cs[wm + quad * 4 + rg][col] = acc[ct][rg] + bv;
  }
  __syncthreads();
  {
    int fl = tid & 31, r8 = tid >> 5;
    int f = f0 + fl;
#pragma unroll
    for (int i = 0; i < 8; i++) {
      int rl = r8 * 8 + i;
      int rr = row0 + rl;
      float rm = Cs[rl][fl], im = Cs[rl][32 + fl];
      float sr = 0.f, si = 0.f;
      if (f < NF) { sr = S[(long)rr * DD + f]; si = S[(long)rr * DD + NF + f]; }
      SR[rl][fl] = rm * sr - im * si;
      SI[rl][fl] = rm * si + im * sr;
    }
  }
  __syncthreads();
  {
    int tl = tid & 63, fq = tid >> 6;
    int rr = row0 + tl;
    int n = rr / TT, t = rr - n * TT;
    int b = n >> 3, c = n & 7;
#pragma unroll
    for (int i = 0; i < 8; i++) {
      int fl = fq * 8 + i;
      int f = f0 + fl;
      if (f < NF) {
        long addr = ((((long)b * NF + f) * 8 + c) * (long)TT + t) * 2;
        *(float2*)&MS[addr] = make_float2(SR[tl][fl], SI[tl][fl]);
      }
    }
  }
}

// ---------------- PSD: one block per (b,f); complex-interleaved MS ----------------
__launch_bounds__(256)
__global__ void k_psd(const float* __restrict__ MS, float* __restrict__ PSD) {
  __shared__ float buf[9616];
  __shared__ float part[64][8];
  const int tid = threadIdx.x;
  const long base = (long)blockIdx.x * 9616;
  for (int i = tid; i < 9616; i += 256) buf[i] = MS[base + i];
  __syncthreads();
  int p = tid & 63, q = tid >> 6;
  int c = p >> 3, e = p & 7;
  const float2* xc = (const float2*)&buf[c * 1202];
  const float2* xe = (const float2*)&buf[e * 1202];
  int t0 = q * 150, t1 = (q == 3) ? TT : t0 + 150;
  float ar = 0.f, ai = 0.f;
  for (int t = t0; t < t1; t++) {
    float2 m = xc[t];
    float2 v = xe[t];
    ar += m.x * v.x + m.y * v.y;
    ai += m.y * v.x - m.x * v.y;
  }
  part[p][q * 2] = ar; part[p][q * 2 + 1] = ai;
  __syncthreads();
  if (tid < 64) {
    float sr = part[tid][0] + part[tid][2] + part[tid][4] + part[tid][6];
    float si = part[tid][1] + part[tid][3] + part[tid][5] + part[tid][7];
    PSD[((long)blockIdx.x * 64 + tid) * 2]     = sr * (1.f / 601.f);
    PSD[((long)blockIdx.x * 64 + tid) * 2 + 1] = si * (1.f / 601.f);
  }
}

// ---------------- 8x8 complex solve + MVDR weight ----------------
__launch_bounds__(64)
__global__ void k_solve(const float* __restrict__ PS, const float* __restrict__ PN,
                        float* __restrict__ WV) {
  int idx = blockIdx.x * 64 + threadIdx.x;
  if (idx >= NB * NF) return;
  float Ar[8][8], Ai[8][8], Br[8][8], Bi[8][8];
  const float* pn = PN + (long)idx * 128;
  const float* ps = PS + (long)idx * 128;
  for (int i = 0; i < 8; i++)
    for (int j = 0; j < 8; j++) {
      Ar[i][j] = pn[(i * 8 + j) * 2]; Ai[i][j] = pn[(i * 8 + j) * 2 + 1];
      Br[i][j] = ps[(i * 8 + j) * 2]; Bi[i][j] = ps[(i * 8 + j) * 2 + 1];
    }
  float tr = 0.f;
  for (int i = 0; i < 8; i++) tr += Ar[i][i];
  float load = 1e-6f * tr / 8.f + 1e-8f;
  for (int i = 0; i < 8; i++) Ar[i][i] += load;
  for (int k = 0; k < 8; k++) {
    int piv = k; float mx = Ar[k][k] * Ar[k][k] + Ai[k][k] * Ai[k][k];
    for (int i = k + 1; i < 8; i++) {
      float m2 = Ar[i][k] * Ar[i][k] + Ai[i][k] * Ai[i][k];
      if (m2 > mx) { mx = m2; piv = i; }
    }
    if (piv != k) {
      for (int j = 0; j < 8; j++) {
        float t0;
        t0 = Ar[k][j]; Ar[k][j] = Ar[piv][j]; Ar[piv][j] = t0;
        t0 = Ai[k][j]; Ai[k][j] = Ai[piv][j]; Ai[piv][j] = t0;
        t0 = Br[k][j]; Br[k][j] = Br[piv][j]; Br[piv][j] = t0;
        t0 = Bi[k][j]; Bi[k][j] = Bi[piv][j]; Bi[piv][j] = t0;
      }
    }
    float dr = Ar[k][k], di = Ai[k][k];
    float inv = 1.f / (dr * dr + di * di);
    float irr = dr * inv, iii = -di * inv;
    for (int j = 0; j < 8; j++) {
      float xr = Ar[k][j], xi = Ai[k][j];
      Ar[k][j] = xr * irr - xi * iii; Ai[k][j] = xr * iii + xi * irr;
      xr = Br[k][j]; xi = Bi[k][j];
      Br[k][j] = xr * irr - xi * iii; Bi[k][j] = xr * iii + xi * irr;
    }
    for (int i = 0; i < 8; i++) {
      if (i == k) continue;
      float fr = Ar[i][k], fi = Ai[i][k];
      for (int j = 0; j < 8; j++) {
        float kr = Ar[k][j], ki = Ai[k][j];
        Ar[i][j] -= fr * kr - fi * ki;
        Ai[i][j] -= fr * ki + fi * kr;
        kr = Br[k][j]; ki = Bi[k][j];
        Br[i][j] -= fr * kr - fi * ki;
        Bi[i][j] -= fr * ki + fi * kr;
      }
    }
  }
  float trr = 1e-8f, tri = 0.f;
  for (int i = 0; i < 8; i++) { trr += Br[i][i]; tri += Bi[i][i]; }
  float inv = 1.f / (trr * trr + tri * tri);
  for (int c = 0; c < 8; c++) {
    float xr = Br[c][0], xi = Bi[c][0];
    WV[((long)idx * 8 + c) * 2]     = (xr * trr + xi * tri) * inv;
    WV[((long)idx * 8 + c) * 2 + 1] = (xi * trr - xr * tri) * inv;
  }
}

// ---------------- beamform -> pre-split ENH (KPAD rows) ----------------
__launch_bounds__(320)
__global__ void k_beam(const float* __restrict__ S, const float* __restrict__ WV,
                       unsigned short* __restrict__ ENHh, unsigned short* __restrict__ ENHl) {
  __shared__ float WL[NF * 16];
  int bb = blockIdx.x / TT, t = blockIdx.x - bb * TT;
  for (int i = threadIdx.x; i < NF * 16; i += 320) WL[i] = WV[(long)bb * NF * 16 + i];
  __syncthreads();
  int f = threadIdx.x;
  long base = ((long)bb * TT + t) * KPAD;
  if (f < NF) {
    float er = 0.f, ei = 0.f;
#pragma unroll
    for (int c = 0; c < 8; c++) {
      float wr = WL[(f * 8 + c) * 2], wi = WL[(f * 8 + c) * 2 + 1];
      const float* srow = S + (((long)(bb * 8 + c) * TT) + t) * DD;
      float sr = srow[f], si = srow[NF + f];
      er += wr * sr + wi * si;
      ei += wr * si - wi * sr;
    }
    split_bf16(er, &ENHh[base + f], &ENHl[base + f]);
    split_bf16(ei, &ENHh[base + NF + f], &ENHl[base + NF + f]);
  }
  int z = threadIdx.x - 288;   // threads 288..317 zero the 30 K-pad cols
  if (z >= 0 && z < 30) { ENHh[base + DD + z] = 0; ENHl[base + DD + z] = 0; }
}

// ---------------- overlap-add + normalize + crop ----------------
__global__ void k_ola(const float* __restrict__ IFR, const float* __restrict__ WSQ,
                      float* __restrict__ out) {
  int idx = blockIdx.x * 256 + threadIdx.x;
  if (idx >= NB * LSEQ) return;
  int b = idx / LSEQ, l = idx - b * LSEQ;
  int p = l + FPAD;
  int t0 = (p <= 511) ? 0 : (p - 352) / 160;
  int t1 = p / 160; if (t1 > 600) t1 = 600;
  float s = 0.f;
  for (int t = t0; t <= t1; t++) s += IFR[((long)b * TT + t) * NFFT + (p - t * HOP)];
  out[idx] = s / fmaxf(WSQ[p], 1e-11f);
}

// ---------------- driver ----------------
extern "C" void kernel_launch(void* const* d_in, const int* in_sizes, int n_in,
                              void* d_out, int out_size, void* d_ws, size_t ws_size,
                              hipStream_t stream) {
  (void)in_sizes; (void)n_in; (void)out_size; (void)ws_size;
  const float* x   = (const float*)d_in[0];
  const float* Wih = (const float*)d_in[1];
  const float* Whh = (const float*)d_in[2];
  const float* bih = (const float*)d_in[3];
  const float* bhh = (const float*)d_in[4];
  const float* W1  = (const float*)d_in[5];
  const float* b1  = (const float*)d_in[6];
  const float* W2  = (const float*)d_in[7];
  const float* b2  = (const float*)d_in[8];
  float* ws = (float*)d_ws;

  // XP region: pre-split XPh/XPl (exactly fills old XP fp32 footprint); IFR aliases later.
  unsigned short* XPh = (unsigned short*)(ws + 0);            // 6,176,768 ush = 3,088,384 fl
  unsigned short* XPl = (unsigned short*)(ws + 3088384);      // -> region ends 6,176,768 fl
  float* S     = ws + 6176768;    // 19,774,496
  float* XWM   = ws + 25951264;   // 19,774,496 (XW then MS; WhhP4 in tail)
  float* HOUT  = ws + 45725760;   // 4,924,288 (pre-GEMM scratch + post-beam ENH split live here too)
  float* PSD_S = ws + 50650048;   // 263,168
  float* PSD_N = ws + 50913216;   // 263,168
  float* WV    = ws + 51176384;   // 32,896
  float* BSUM  = ws + 51209280;   // 512
  float* WSQ   = ws + 51209792;   // 96,512 -> 51,306,304
  unsigned short* W1sh = (unsigned short*)(ws + 51306304);
  unsigned short* W1sl = (unsigned short*)(ws + 51347264);
  unsigned short* W2sh = (unsigned short*)(ws + 51388224);
  unsigned short* W2sl = (unsigned short*)(ws + 51429184); // -> 51,470,144
  unsigned short* WTth = (unsigned short*)(ws + 51470144); // 139,264 fl
  unsigned short* WTtl = (unsigned short*)(ws + 51609408); // -> 51,748,672
  unsigned short* BIth = (unsigned short*)(ws + 51748672); // 139,264 fl
  unsigned short* BItl = (unsigned short*)(ws + 51887936); // -> end 52,027,200 (~208 MB)
  float* MS    = XWM;
  float* IFR   = ws + 0;          // aliases XP region after gemm4
  unsigned int* WhhP4 = (unsigned int*)(XWM + 19693568);   // after true end of XW
  // Pre-GEMM scratch inside HOUT (dead until k_lstm):
  float* BFf = HOUT;                                        // 263,168 fl
  float* BWf = HOUT + 263168;                               // 262,144 fl
  unsigned short* BCh = (unsigned short*)(HOUT + 525312);   // 1152*544 ush = 313,344 fl
  unsigned short* BCl = (unsigned short*)(HOUT + 838656);   // -> 1,152,000 fl < 4,924,288
  // Post-beam ENH split in HOUT (Hout consumed by maskms before k_beam):
  unsigned short* ENHh = (unsigned short*)HOUT;             // 4808*544 ush = 1,307,776 fl
  unsigned short* ENHl = (unsigned short*)(HOUT + 1307776);

  k_wsq<<<(XPLEN + 255) / 256, 256, 0, stream>>>(WSQ);
  k_bff<<<(NFFT * DD + 255) / 256, 256, 0, stream>>>(BFf);
  k_wtsplit<<<(G4 * KPAD + 255) / 256, 256, 0, stream>>>(Wih, WTth, WTtl);
  k_bisplit<<<(NFFT * KPAD + 255) / 256, 256, 0, stream>>>(BIth, BItl);
  k_bsum<<<2, 256, 0, stream>>>(bih, bhh, BSUM);
  k_wmsplit<<<(2 * 640 * HH + 255) / 256, 256, 0, stream>>>(W1, W2, W1sh, W1sl, W2sh, W2sl);
  k_wpack<<<(G4 * 64 + 255) / 256, 256, 0, stream>>>(Whh, WhhP4);
  k_xp<<<(NSEQ * XPLEN + 255) / 256, 256, 0, stream>>>(x, XPh, XPl);

  // BW = BF @ Wih^T  (512x512, K=514) — small gemm3
  {
    dim3 g(4, 4);
    k_gemm3<0><<<g, 256, 0, stream>>>(BFf, WTth, WTtl, nullptr, BWf, 512, 512, DD, DD, G4);
  }
  // combined split B = [BF | BW]
  k_bcomb<<<(1152 * KPAD + 255) / 256, 256, 0, stream>>>(BWf, BCh, BCl);

  // fused STFT + xW: S[38464,514] and XW[38464,512] in one gather-GEMM
  {
    dim3 g(9, 301);
    k_gemm4<<<g, 256, 0, stream>>>(XPh, XPl, BCh, BCl, BSUM, S, XWM);
  }

  k_lstm<<<64, 512, 0, stream>>>(XWM, WhhP4, HOUT);

  dim3 gm(9, 601);
  k_maskms<<<gm, 256, 0, stream>>>(HOUT, W1sh, W1sl, b1, S, MS);
  k_psd<<<NB * NF, 256, 0, stream>>>(MS, PSD_S);
  k_maskms<<<gm, 256, 0, stream>>>(HOUT, W2sh, W2sl, b2, S, MS);
  k_psd<<<NB * NF, 256, 0, stream>>>(MS, PSD_N);

  k_solve<<<(NB * NF + 63) / 64, 64, 0, stream>>>(PSD_S, PSD_N, WV);
  k_beam<<<NB * TT, 320, 0, stream>>>(S, WV, ENHh, ENHl);

  // iSTFT: IFR[4808,512] = ENH @ BI (pre-split A)
  {
    dim3 g(4, 38);
    k_gemm5<<<g, 256, 0, stream>>>(ENHh, ENHl, BIth, BItl, IFR, NB * TT, NFFT, NFFT);
  }

  k_ola<<<(NB * LSEQ + 255) / 256, 256, 0, stream>>>(IFR, WSQ, (float*)d_out);
}

// Round 7
// 1150.293 us; speedup vs baseline: 1.3423x; 1.0149x over previous
//
#include <hip/hip_runtime.h>
#include <math.h>

#define NFFT  512
#define WINL  320
#define HOP   160
#define FPAD  256
#define NF    257
#define TT    601
#define LSEQ  96000
#define XPLEN 96512
#define NCH   8
#define NB    8
#define NSEQ  64
#define NROWS 38464   // NSEQ*TT
#define DD    514
#define HH    128
#define G4    512
#define KPAD  544     // 17*32, zero-padded K for split-B arrays
#define NCOMB 1026    // 514 (S cols) + 512 (XW cols)

// fused-init block ranges (all exact multiples of 256 threads)
#define NXP   24128   // NSEQ*XPLEN/256
#define NWSQ  377     // XPLEN/256
#define NBFF  1028    // NFFT*DD/256
#define NWT   1088    // G4*KPAD/256
#define NBI   1088    // NFFT*KPAD/256
#define NBS   2       // G4/256
#define NWM   640     // 2*640*HH/256
#define NWP   128     // G4*64/256
#define NINIT (NXP + NWSQ + NBFF + NWT + NBI + NBS + NWM + NWP)   // 28479

typedef _Float16 h2v __attribute__((ext_vector_type(2)));
typedef short bf16x8 __attribute__((ext_vector_type(8)));
typedef float f32x4 __attribute__((ext_vector_type(4)));

// ---------------- init helpers ----------------
__device__ __forceinline__ float winval(int k) {
  if (k < 96 || k >= 416) return 0.f;
  return 0.5f - 0.5f * cosf((float)(2.0 * M_PI / 320.0) * (float)(k - 96));
}

__device__ __forceinline__ void split_bf16(float v, unsigned short* h, unsigned short* l) {
  unsigned int hb = __float_as_uint(v) >> 16;
  float r = v - __uint_as_float(hb << 16);
  *h = (unsigned short)hb;
  *l = (unsigned short)(__float_as_uint(r) >> 16);
}

// ---------------- fused init: 8 independent prep kernels in one launch ----------------
// Block-range dispatch (block-level branch, no warp divergence). Bodies are
// verbatim copies of the previous standalone kernels; all sizes are exact
// multiples of 256 so the internal bounds guards are redundant but kept.
__global__ void k_init(const float* __restrict__ x, const float* __restrict__ Wih,
                       const float* __restrict__ Whh, const float* __restrict__ bih,
                       const float* __restrict__ bhh, const float* __restrict__ W1,
                       const float* __restrict__ W2,
                       unsigned short* __restrict__ XPh, unsigned short* __restrict__ XPl,
                       float* __restrict__ wsq, float* __restrict__ BFf,
                       unsigned short* __restrict__ WTh, unsigned short* __restrict__ WTl,
                       unsigned short* __restrict__ BIh, unsigned short* __restrict__ BIl,
                       float* __restrict__ BSUM,
                       unsigned short* __restrict__ W1h, unsigned short* __restrict__ W1l,
                       unsigned short* __restrict__ W2h, unsigned short* __restrict__ W2l,
                       unsigned int* __restrict__ WhhP4) {
  int b = blockIdx.x;
  const int tid = threadIdx.x;

  if (b < NXP) {                       // ---- k_xp ----
    int idx = b * 256 + tid;
    if (idx < NSEQ * XPLEN) {
      int n = idx / XPLEN, i = idx - n * XPLEN;
      int j = i - FPAD;
      if (j < 0) j = -j;
      else if (j >= LSEQ) j = 2 * LSEQ - 2 - j;
      int bb = n >> 3, c = n & 7;
      float v = x[((long)bb * LSEQ + j) * NCH + c];
      split_bf16(v, &XPh[idx], &XPl[idx]);
    }
    return;
  }
  b -= NXP;

  if (b < NWSQ) {                      // ---- k_wsq ----
    int p = b * 256 + tid;
    if (p < XPLEN) {
      int t0 = (p <= 511) ? 0 : (p - 352) / 160;
      int t1 = p / 160; if (t1 > 600) t1 = 600;
      float s = 0.f;
      for (int t = t0; t <= t1; t++) { float w = winval(p - t * HOP); s += w * w; }
      wsq[p] = s;
    }
    return;
  }
  b -= NWSQ;

  if (b < NBFF) {                      // ---- k_bff ----
    int idx = b * 256 + tid;
    if (idx < NFFT * DD) {
      int k = idx / DD, d = idx - k * DD;
      float w = winval(k);
      int f = (d < NF) ? d : d - NF;
      int m = (k * f) & 511;
      float th = (float)(M_PI / 256.0) * (float)m;
      BFf[idx] = ((d < NF) ? cosf(th) : -sinf(th)) * w;
    }
    return;
  }
  b -= NBFF;

  if (b < NWT) {                       // ---- k_wtsplit ----
    int idx = b * 256 + tid;
    if (idx < G4 * KPAD) {
      int n = idx / KPAD, k = idx - n * KPAD;
      float v = (k < DD) ? Wih[n * DD + k] : 0.f;
      split_bf16(v, &WTh[idx], &WTl[idx]);
    }
    return;
  }
  b -= NWT;

  if (b < NBI) {                       // ---- k_bisplit ----
    int idx = b * 256 + tid;
    if (idx < NFFT * KPAD) {
      int n = idx / KPAD, kk = idx - n * KPAD;
      float v = 0.f;
      if (kk < DD) {
        float w = winval(n);
        int f = (kk < NF) ? kk : kk - NF;
        int edge = (f == 0 || f == 256);
        float alpha = edge ? 1.f : 2.f;
        int m = (n * f) & 511;
        float th = (float)(M_PI / 256.0) * (float)m;
        float c;
        if (kk < NF) c = alpha * cosf(th);
        else         c = edge ? 0.f : -alpha * sinf(th);
        v = c * w * (1.f / 512.f);
      }
      split_bf16(v, &BIh[idx], &BIl[idx]);
    }
    return;
  }
  b -= NBI;

  if (b < NBS) {                       // ---- k_bsum ----
    int idx = b * 256 + tid;
    if (idx < G4) BSUM[idx] = bih[idx] + bhh[idx];
    return;
  }
  b -= NBS;

  if (b < NWM) {                       // ---- k_wmsplit ----
    int idx = b * 256 + tid;
    if (idx < 2 * 640 * HH) {
      int m = idx / (640 * HH);
      int rem = idx - m * 640 * HH;
      int np = rem / HH, k = rem - np * HH;
      int ri = np / 320, f = np - ri * 320;
      float v = 0.f;
      if (f < NF) {
        int fcol = (ri == 0) ? f : NF + f;
        v = (m == 0) ? W1[fcol * HH + k] : W2[fcol * HH + k];
      }
      unsigned short h, l;
      split_bf16(v, &h, &l);
      if (m == 0) { W1h[rem] = h; W1l[rem] = l; }
      else        { W2h[rem] = h; W2l[rem] = l; }
    }
    return;
  }
  b -= NWM;

  {                                    // ---- k_wpack ----
    int idx = b * 256 + tid;
    if (idx < G4 * 64) {
      int j = idx >> 6, k2 = idx & 63;
      _Float16 lo = (_Float16)Whh[j * HH + 2 * k2];
      _Float16 hi = (_Float16)Whh[j * HH + 2 * k2 + 1];
      unsigned int u = ((unsigned int)__builtin_bit_cast(unsigned short, hi) << 16)
                     |  (unsigned int)__builtin_bit_cast(unsigned short, lo);
      WhhP4[(k2 >> 2) * (G4 * 4) + j * 4 + (k2 & 3)] = u;
    }
  }
}

// Combined split B for the fused STFT+xW GEMM: BC[n][k], n in [0,1152)
__global__ void k_bcomb(const float* __restrict__ BWf, unsigned short* __restrict__ H,
                        unsigned short* __restrict__ L) {
  int idx = blockIdx.x * 256 + threadIdx.x;
  if (idx >= 1152 * KPAD) return;
  int n = idx / KPAD, k = idx - n * KPAD;
  float v = 0.f;
  if (k < NFFT) {
    if (n < DD) {
      float w = winval(k);
      int f = (n < NF) ? n : n - NF;
      int m = (k * f) & 511;
      float th = (float)(M_PI / 256.0) * (float)m;
      v = ((n < NF) ? cosf(th) : -sinf(th)) * w;
    } else if (n < NCOMB) {
      v = BWf[k * G4 + (n - 514)];
    }
  }
  split_bf16(v, &H[idx], &L[idx]);
}

// ---------------- split-bf16 MFMA GEMM (fp32 A): C[M,N] = A[M,K] * Bt^T (+bias) ----------------
template <int GATHER>
__launch_bounds__(256)
__global__ void k_gemm3(const float* __restrict__ A,
                        const unsigned short* __restrict__ Bth,
                        const unsigned short* __restrict__ Btl,
                        const float* __restrict__ bias, float* __restrict__ C,
                        int M, int N, int K, int lda, int ldc) {
  __shared__ __align__(16) unsigned short sAh[128 * 40];
  __shared__ __align__(16) unsigned short sAl[128 * 40];
  __shared__ __align__(16) unsigned short sBh[128 * 40];
  __shared__ __align__(16) unsigned short sBl[128 * 40];
  const int tid = threadIdx.x;
  const int row0 = blockIdx.y * 128, col0 = blockIdx.x * 128;
  const int sar = tid >> 1, sak = (tid & 1) * 16;
  const int arow = row0 + sar;
  long abase = (long)arow * lda;
  const bool arok = (arow < M);
  const int lane = tid & 63, w = tid >> 6;
  const int wm = (w >> 1) * 64, wn = (w & 1) * 64;
  const int l15 = lane & 15, quad = lane >> 4;
  f32x4 acc[4][4] = {};
  unsigned int* aH = (unsigned int*)sAh;
  unsigned int* aL = (unsigned int*)sAl;
  uint4* bH = (uint4*)sBh;
  uint4* bL = (uint4*)sBl;
  for (int k0 = 0; k0 < K; k0 += 32) {
#pragma unroll
    for (int i = 0; i < 8; i++) {
      int kk = k0 + sak + 2 * i;
      float v0 = 0.f, v1 = 0.f;
      if (arok) {
        if (kk + 1 < K) { float2 t2 = *(const float2*)(A + abase + kk); v0 = t2.x; v1 = t2.y; }
        else if (kk < K) { v0 = A[abase + kk]; }
      }
      unsigned int h0 = __float_as_uint(v0) >> 16, h1 = __float_as_uint(v1) >> 16;
      float r0 = v0 - __uint_as_float(h0 << 16), r1 = v1 - __uint_as_float(h1 << 16);
      unsigned int l0 = __float_as_uint(r0) >> 16, l1 = __float_as_uint(r1) >> 16;
      aH[sar * 20 + (sak >> 1) + i] = h0 | (h1 << 16);
      aL[sar * 20 + (sak >> 1) + i] = l0 | (l1 << 16);
    }
#pragma unroll
    for (int h = 0; h < 2; h++) {
      int idx = tid + h * 256;
      int r = idx >> 2, c = idx & 3;
      long go = (long)(col0 + r) * KPAD + k0 + c * 8;
      bH[r * 5 + c] = *(const uint4*)(Bth + go);
      bL[r * 5 + c] = *(const uint4*)(Btl + go);
    }
    __syncthreads();
    bf16x8 ah[4], al[4], bh[4], bl[4];
#pragma unroll
    for (int i = 0; i < 4; i++) {
      int off = (wm + i * 16 + l15) * 40 + quad * 8;
      ah[i] = *(const bf16x8*)(sAh + off);
      al[i] = *(const bf16x8*)(sAl + off);
      int boff = (wn + i * 16 + l15) * 40 + quad * 8;
      bh[i] = *(const bf16x8*)(sBh + boff);
      bl[i] = *(const bf16x8*)(sBl + boff);
    }
#pragma unroll
    for (int i = 0; i < 4; i++)
#pragma unroll
      for (int j = 0; j < 4; j++) {
        acc[i][j] = __builtin_amdgcn_mfma_f32_16x16x32_bf16(al[i], bh[j], acc[i][j], 0, 0, 0);
        acc[i][j] = __builtin_amdgcn_mfma_f32_16x16x32_bf16(ah[i], bl[j], acc[i][j], 0, 0, 0);
        acc[i][j] = __builtin_amdgcn_mfma_f32_16x16x32_bf16(ah[i], bh[j], acc[i][j], 0, 0, 0);
      }
    __syncthreads();
  }
#pragma unroll
  for (int i = 0; i < 4; i++)
#pragma unroll
    for (int j = 0; j < 4; j++) {
      int cc = col0 + wn + j * 16 + l15;
      if (cc >= N) continue;
      float bv = bias ? bias[cc] : 0.f;
#pragma unroll
      for (int rg = 0; rg < 4; rg++) {
        int rr = row0 + wm + i * 16 + quad * 4 + rg;
        if (rr < M) C[(long)rr * ldc + cc] = acc[i][j][rg] + bv;
      }
    }
}

// ---------------- fused STFT+xW GEMM: pre-split A (gathered XP), combined B ----------------
// C[38464, 1026]: cols <514 -> S; cols 514..1025 -> XW (+bsum). K=512, tile 128x128.
__launch_bounds__(256)
__global__ void k_gemm4(const unsigned short* __restrict__ Ah, const unsigned short* __restrict__ Al,
                        const unsigned short* __restrict__ Bh, const unsigned short* __restrict__ Bl,
                        const float* __restrict__ bsum, float* __restrict__ S,
                        float* __restrict__ XW) {
  __shared__ __align__(16) unsigned short sAh[128 * 40];
  __shared__ __align__(16) unsigned short sAl[128 * 40];
  __shared__ __align__(16) unsigned short sBh[128 * 40];
  __shared__ __align__(16) unsigned short sBl[128 * 40];
  const int tid = threadIdx.x;
  const int row0 = blockIdx.y * 128, col0 = blockIdx.x * 128;
  const int sr0 = tid >> 2, c4 = (tid & 3) * 8, cq = tid & 3;
  long ab0, ab1;
  { int rr = row0 + sr0;      int n = rr / TT, t = rr - n * TT; ab0 = (long)n * XPLEN + (long)t * HOP; }
  { int rr = row0 + sr0 + 64; int n = rr / TT, t = rr - n * TT; ab1 = (long)n * XPLEN + (long)t * HOP; }
  const int lane = tid & 63, w = tid >> 6;
  const int wm = (w >> 1) * 64, wn = (w & 1) * 64;
  const int l15 = lane & 15, quad = lane >> 4;
  f32x4 acc[4][4] = {};
  uint4* aH4 = (uint4*)sAh; uint4* aL4 = (uint4*)sAl;
  uint4* bH4 = (uint4*)sBh; uint4* bL4 = (uint4*)sBl;
  for (int k0 = 0; k0 < NFFT; k0 += 32) {
    aH4[sr0 * 5 + cq]        = *(const uint4*)(Ah + ab0 + k0 + c4);
    aL4[sr0 * 5 + cq]        = *(const uint4*)(Al + ab0 + k0 + c4);
    aH4[(sr0 + 64) * 5 + cq] = *(const uint4*)(Ah + ab1 + k0 + c4);
    aL4[(sr0 + 64) * 5 + cq] = *(const uint4*)(Al + ab1 + k0 + c4);
    {
      long go = (long)(col0 + sr0) * KPAD + k0 + c4;
      bH4[sr0 * 5 + cq] = *(const uint4*)(Bh + go);
      bL4[sr0 * 5 + cq] = *(const uint4*)(Bl + go);
      go = (long)(col0 + sr0 + 64) * KPAD + k0 + c4;
      bH4[(sr0 + 64) * 5 + cq] = *(const uint4*)(Bh + go);
      bL4[(sr0 + 64) * 5 + cq] = *(const uint4*)(Bl + go);
    }
    __syncthreads();
    bf16x8 ah[4], al[4], bh[4], bl[4];
#pragma unroll
    for (int i = 0; i < 4; i++) {
      int off = (wm + i * 16 + l15) * 40 + quad * 8;
      ah[i] = *(const bf16x8*)(sAh + off);
      al[i] = *(const bf16x8*)(sAl + off);
      int boff = (wn + i * 16 + l15) * 40 + quad * 8;
      bh[i] = *(const bf16x8*)(sBh + boff);
      bl[i] = *(const bf16x8*)(sBl + boff);
    }
#pragma unroll
    for (int i = 0; i < 4; i++)
#pragma unroll
      for (int j = 0; j < 4; j++) {
        acc[i][j] = __builtin_amdgcn_mfma_f32_16x16x32_bf16(al[i], bh[j], acc[i][j], 0, 0, 0);
        acc[i][j] = __builtin_amdgcn_mfma_f32_16x16x32_bf16(ah[i], bl[j], acc[i][j], 0, 0, 0);
        acc[i][j] = __builtin_amdgcn_mfma_f32_16x16x32_bf16(ah[i], bh[j], acc[i][j], 0, 0, 0);
      }
    __syncthreads();
  }
#pragma unroll
  for (int i = 0; i < 4; i++)
#pragma unroll
    for (int j = 0; j < 4; j++) {
      int cc = col0 + wn + j * 16 + l15;
      if (cc >= NCOMB) continue;
#pragma unroll
      for (int rg = 0; rg < 4; rg++) {
        int rr = row0 + wm + i * 16 + quad * 4 + rg;
        if (rr >= NROWS) continue;
        float v = acc[i][j][rg];
        if (cc < DD) S[(long)rr * DD + cc] = v;
        else         XW[(long)rr * G4 + (cc - 514)] = v + bsum[cc - 514];
      }
    }
}

// ---------------- iSTFT GEMM: pre-split A (pitch KPAD), B = BI split ----------------
__launch_bounds__(256)
__global__ void k_gemm5(const unsigned short* __restrict__ Ah, const unsigned short* __restrict__ Al,
                        const unsigned short* __restrict__ Bh, const unsigned short* __restrict__ Bl,
                        float* __restrict__ C, int M, int N, int ldc) {
  __shared__ __align__(16) unsigned short sAh[128 * 40];
  __shared__ __align__(16) unsigned short sAl[128 * 40];
  __shared__ __align__(16) unsigned short sBh[128 * 40];
  __shared__ __align__(16) unsigned short sBl[128 * 40];
  const int tid = threadIdx.x;
  const int row0 = blockIdx.y * 128, col0 = blockIdx.x * 128;
  const int sr0 = tid >> 2, c4 = (tid & 3) * 8, cq = tid & 3;
  const int lane = tid & 63, w = tid >> 6;
  const int wm = (w >> 1) * 64, wn = (w & 1) * 64;
  const int l15 = lane & 15, quad = lane >> 4;
  f32x4 acc[4][4] = {};
  uint4* aH4 = (uint4*)sAh; uint4* aL4 = (uint4*)sAl;
  uint4* bH4 = (uint4*)sBh; uint4* bL4 = (uint4*)sBl;
  for (int k0 = 0; k0 < KPAD; k0 += 32) {
    {
      long go = (long)(row0 + sr0) * KPAD + k0 + c4;
      aH4[sr0 * 5 + cq] = *(const uint4*)(Ah + go);
      aL4[sr0 * 5 + cq] = *(const uint4*)(Al + go);
      go = (long)(row0 + sr0 + 64) * KPAD + k0 + c4;
      aH4[(sr0 + 64) * 5 + cq] = *(const uint4*)(Ah + go);
      aL4[(sr0 + 64) * 5 + cq] = *(const uint4*)(Al + go);
    }
    {
      long go = (long)(col0 + sr0) * KPAD + k0 + c4;
      bH4[sr0 * 5 + cq] = *(const uint4*)(Bh + go);
      bL4[sr0 * 5 + cq] = *(const uint4*)(Bl + go);
      go = (long)(col0 + sr0 + 64) * KPAD + k0 + c4;
      bH4[(sr0 + 64) * 5 + cq] = *(const uint4*)(Bh + go);
      bL4[(sr0 + 64) * 5 + cq] = *(const uint4*)(Bl + go);
    }
    __syncthreads();
    bf16x8 ah[4], al[4], bh[4], bl[4];
#pragma unroll
    for (int i = 0; i < 4; i++) {
      int off = (wm + i * 16 + l15) * 40 + quad * 8;
      ah[i] = *(const bf16x8*)(sAh + off);
      al[i] = *(const bf16x8*)(sAl + off);
      int boff = (wn + i * 16 + l15) * 40 + quad * 8;
      bh[i] = *(const bf16x8*)(sBh + boff);
      bl[i] = *(const bf16x8*)(sBl + boff);
    }
#pragma unroll
    for (int i = 0; i < 4; i++)
#pragma unroll
      for (int j = 0; j < 4; j++) {
        acc[i][j] = __builtin_amdgcn_mfma_f32_16x16x32_bf16(al[i], bh[j], acc[i][j], 0, 0, 0);
        acc[i][j] = __builtin_amdgcn_mfma_f32_16x16x32_bf16(ah[i], bl[j], acc[i][j], 0, 0, 0);
        acc[i][j] = __builtin_amdgcn_mfma_f32_16x16x32_bf16(ah[i], bh[j], acc[i][j], 0, 0, 0);
      }
    __syncthreads();
  }
#pragma unroll
  for (int i = 0; i < 4; i++)
#pragma unroll
    for (int j = 0; j < 4; j++) {
      int cc = col0 + wn + j * 16 + l15;
      if (cc >= N) continue;
#pragma unroll
      for (int rg = 0; rg < 4; rg++) {
        int rr = row0 + wm + i * 16 + quad * 4 + rg;
        if (rr < M) C[(long)rr * ldc + cc] = acc[i][j][rg];
      }
    }
}

// ---------------- LSTM v11 (proven local optimum, 382us): v8 structure + 3 stall removals ----------------
// (a) raw s_barrier with lgkmcnt-only drain (no vmcnt(0) -> XW prefetch and Hout
//     stores stay in flight across barriers)
// (b) h broadcast via uniform ds_read_b128 (LDS pipe) instead of 64 v_readlane
// (c) distributed nonlinearity: each thread applies its own gate's sigma/tanh
// Restructures measured and rejected: 16-chain MFMA batch (v10, 2.6x worse),
// quad-shuffle exchange (v12, +23%), 4-rows/thread (v13, spilled, 2x worse),
// 2-deep prefetch (v14, flat).
__device__ __forceinline__ float tanh_fast(float x) {
  float e = __expf(2.f * x);
  return 1.f - 2.f / (e + 1.f);
}

__launch_bounds__(512, 2)
__global__ void k_lstm(const float* __restrict__ XW, const unsigned int* __restrict__ WhhP4,
                       float* __restrict__ Hout) {
  __shared__ __align__(16) unsigned int hl2[64];
  __shared__ float gl[G4];
  const int j = threadIdx.x;
  const int n = blockIdx.x;
  const uint4* W4 = (const uint4*)WhhP4;
  unsigned int wp[64];
#pragma unroll
  for (int i4 = 0; i4 < 16; i4++) {
    uint4 v = W4[i4 * G4 + j];
    wp[4 * i4]     = v.x;
    wp[4 * i4 + 1] = v.y;
    wp[4 * i4 + 2] = v.z;
    wp[4 * i4 + 3] = v.w;
  }
  float cst = 0.f;
  if (j < 64) hl2[j] = 0u;
  const float* xwrow = XW + (long)n * TT * G4 + j;
  float xnext = xwrow[0];
  const uint4* h4 = (const uint4*)hl2;
  const bool isg = (j >= 2 * HH) && (j < 3 * HH);   // 'g' gate rows -> tanh, else sigmoid
  __syncthreads();
  for (int t = 0; t < TT; t++) {
    float xv = xnext;
    if (t + 1 < TT) xnext = xwrow[(long)(t + 1) * G4];
    float a0 = 0.f, a1 = 0.f, a2 = 0.f, a3 = 0.f;
#pragma unroll
    for (int k = 0; k < 16; k++) {
      uint4 hv4 = h4[k];   // uniform address -> LDS broadcast, conflict-free
      a0 = __builtin_amdgcn_fdot2(__builtin_bit_cast(h2v, hv4.x), __builtin_bit_cast(h2v, wp[4 * k]),     a0, false);
      a1 = __builtin_amdgcn_fdot2(__builtin_bit_cast(h2v, hv4.y), __builtin_bit_cast(h2v, wp[4 * k + 1]), a1, false);
      a2 = __builtin_amdgcn_fdot2(__builtin_bit_cast(h2v, hv4.z), __builtin_bit_cast(h2v, wp[4 * k + 2]), a2, false);
      a3 = __builtin_amdgcn_fdot2(__builtin_bit_cast(h2v, hv4.w), __builtin_bit_cast(h2v, wp[4 * k + 3]), a3, false);
    }
    float a = ((a0 + a1) + (a2 + a3)) + xv;
    float nl;
    if (isg) nl = tanh_fast(a);
    else     nl = 1.f / (1.f + __expf(-a));
    gl[j] = nl;
    asm volatile("s_waitcnt lgkmcnt(0)" ::: "memory");
    __builtin_amdgcn_s_barrier();
    if (j < HH) {
      float ni = gl[j], nf = gl[HH + j], ng = gl[2 * HH + j], no = gl[3 * HH + j];
      cst = nf * cst + ni * ng;
      float hv = no * tanh_fast(cst);
      ((_Float16*)hl2)[j] = (_Float16)hv;
      Hout[((long)n * TT + t) * HH + j] = hv;
    }
    asm volatile("s_waitcnt lgkmcnt(0)" ::: "memory");
    __builtin_amdgcn_s_barrier();
  }
}

// ---------------- mask GEMM (split-bf16 MFMA) + mask apply + transpose ----------------
// MS layout: [b][f][c][t] complex-interleaved (re,im)
__launch_bounds__(256)
__global__ void k_maskms(const float* __restrict__ Hout,
                         const unsigned short* __restrict__ Wsh,
                         const unsigned short* __restrict__ Wsl,
                         const float* __restrict__ bias, const float* __restrict__ S,
                         float* __restrict__ MS) {
  __shared__ __align__(16) unsigned short sAh[64 * 40];
  __shared__ __align__(16) unsigned short sAl[64 * 40];
  __shared__ __align__(16) unsigned short sBh[64 * 40];
  __shared__ __align__(16) unsigned short sBl[64 * 40];
  __shared__ float Cs[64][68];
  __shared__ float SR[64][33];
  __shared__ float SI[64][33];
  const int tid = threadIdx.x;
  const int f0 = blockIdx.x * 32;
  const int row0 = blockIdx.y * 64;
  const int lane = tid & 63, w = tid >> 6;
  const int wm = w * 16;
  const int l15 = lane & 15, quad = lane >> 4;
  const int sar = tid >> 2;
  const int sak = (tid & 3) * 8;
  const int np = ((sar < 32) ? 0 : 320 - 32) + f0 + sar;
  unsigned int* aH = (unsigned int*)sAh;
  unsigned int* aL = (unsigned int*)sAl;
  f32x4 acc[4] = {};
  for (int k0 = 0; k0 < HH; k0 += 32) {
    {
      const float* ap = Hout + (long)(row0 + sar) * HH + k0 + sak;
      float4 v0 = *(const float4*)ap;
      float4 v1 = *(const float4*)(ap + 4);
      float vv[8] = {v0.x, v0.y, v0.z, v0.w, v1.x, v1.y, v1.z, v1.w};
#pragma unroll
      for (int i = 0; i < 4; i++) {
        unsigned int h0 = __float_as_uint(vv[2 * i]) >> 16, h1 = __float_as_uint(vv[2 * i + 1]) >> 16;
        float r0 = vv[2 * i] - __uint_as_float(h0 << 16), r1 = vv[2 * i + 1] - __uint_as_float(h1 << 16);
        unsigned int l0 = __float_as_uint(r0) >> 16, l1 = __float_as_uint(r1) >> 16;
        aH[sar * 20 + (sak >> 1) + i] = h0 | (h1 << 16);
        aL[sar * 20 + (sak >> 1) + i] = l0 | (l1 << 16);
      }
    }
    {
      long go = (long)np * HH + k0 + sak;
      *(uint4*)(sBh + sar * 40 + sak) = *(const uint4*)(Wsh + go);
      *(uint4*)(sBl + sar * 40 + sak) = *(const uint4*)(Wsl + go);
    }
    __syncthreads();
    bf16x8 ah = *(const bf16x8*)(sAh + (wm + l15) * 40 + quad * 8);
    bf16x8 al = *(const bf16x8*)(sAl + (wm + l15) * 40 + quad * 8);
#pragma unroll
    for (int ct = 0; ct < 4; ct++) {
      bf16x8 bh = *(const bf16x8*)(sBh + (ct * 16 + l15) * 40 + quad * 8);
      bf16x8 bl = *(const bf16x8*)(sBl + (ct * 16 + l15) * 40 + quad * 8);
      acc[ct] = __builtin_amdgcn_mfma_f32_16x16x32_bf16(al, bh, acc[ct], 0, 0, 0);
      acc[ct] = __builtin_amdgcn_mfma_f32_16x16x32_bf16(ah, bl, acc[ct], 0, 0, 0);
      acc[ct] = __builtin_amdgcn_mfma_f32_16x16x32_bf16(ah, bh, acc[ct], 0, 0, 0);
    }
    __syncthreads();
  }
#pragma unroll
  for (int ct = 0; ct < 4; ct++) {
    int col = ct * 16 + l15;
    int f = f0 + (col & 31);
    int fcol = (col < 32) ? f : NF + f;
    float bv = (f < NF) ? bias[fcol] : 0.f;
#pragma unroll
    for (int rg = 0; rg < 4; rg++) Cs[wm + quad * 4 + rg][col] = acc[ct][rg] + bv;
  }
  __syncthreads();
  {
    int fl = tid & 31, r8 = tid >> 5;
    int f = f0 + fl;
#pragma unroll
    for (int i = 0; i < 8; i++) {
      int rl = r8 * 8 + i;
      int rr = row0 + rl;
      float rm = Cs[rl][fl], im = Cs[rl][32 + fl];
      float sr = 0.f, si = 0.f;
      if (f < NF) { sr = S[(long)rr * DD + f]; si = S[(long)rr * DD + NF + f]; }
      SR[rl][fl] = rm * sr - im * si;
      SI[rl][fl] = rm * si + im * sr;
    }
  }
  __syncthreads();
  {
    int tl = tid & 63, fq = tid >> 6;
    int rr = row0 + tl;
    int n = rr / TT, t = rr - n * TT;
    int b = n >> 3, c = n & 7;
#pragma unroll
    for (int i = 0; i < 8; i++) {
      int fl = fq * 8 + i;
      int f = f0 + fl;
      if (f < NF) {
        long addr = ((((long)b * NF + f) * 8 + c) * (long)TT + t) * 2;
        *(float2*)&MS[addr] = make_float2(SR[tl][fl], SI[tl][fl]);
      }
    }
  }
}

// ---------------- PSD: one block per (b,f); complex-interleaved MS ----------------
__launch_bounds__(256)
__global__ void k_psd(const float* __restrict__ MS, float* __restrict__ PSD) {
  __shared__ float buf[9616];
  __shared__ float part[64][8];
  const int tid = threadIdx.x;
  const long base = (long)blockIdx.x * 9616;
  for (int i = tid; i < 9616; i += 256) buf[i] = MS[base + i];
  __syncthreads();
  int p = tid & 63, q = tid >> 6;
  int c = p >> 3, e = p & 7;
  const float2* xc = (const float2*)&buf[c * 1202];
  const float2* xe = (const float2*)&buf[e * 1202];
  int t0 = q * 150, t1 = (q == 3) ? TT : t0 + 150;
  float ar = 0.f, ai = 0.f;
  for (int t = t0; t < t1; t++) {
    float2 m = xc[t];
    float2 v = xe[t];
    ar += m.x * v.x + m.y * v.y;
    ai += m.y * v.x - m.x * v.y;
  }
  part[p][q * 2] = ar; part[p][q * 2 + 1] = ai;
  __syncthreads();
  if (tid < 64) {
    float sr = part[tid][0] + part[tid][2] + part[tid][4] + part[tid][6];
    float si = part[tid][1] + part[tid][3] + part[tid][5] + part[tid][7];
    PSD[((long)blockIdx.x * 64 + tid) * 2]     = sr * (1.f / 601.f);
    PSD[((long)blockIdx.x * 64 + tid) * 2 + 1] = si * (1.f / 601.f);
  }
}

// ---------------- 8x8 complex solve + MVDR weight ----------------
__launch_bounds__(64)
__global__ void k_solve(const float* __restrict__ PS, const float* __restrict__ PN,
                        float* __restrict__ WV) {
  int idx = blockIdx.x * 64 + threadIdx.x;
  if (idx >= NB * NF) return;
  float Ar[8][8], Ai[8][8], Br[8][8], Bi[8][8];
  const float* pn = PN + (long)idx * 128;
  const float* ps = PS + (long)idx * 128;
  for (int i = 0; i < 8; i++)
    for (int j = 0; j < 8; j++) {
      Ar[i][j] = pn[(i * 8 + j) * 2]; Ai[i][j] = pn[(i * 8 + j) * 2 + 1];
      Br[i][j] = ps[(i * 8 + j) * 2]; Bi[i][j] = ps[(i * 8 + j) * 2 + 1];
    }
  float tr = 0.f;
  for (int i = 0; i < 8; i++) tr += Ar[i][i];
  float load = 1e-6f * tr / 8.f + 1e-8f;
  for (int i = 0; i < 8; i++) Ar[i][i] += load;
  for (int k = 0; k < 8; k++) {
    int piv = k; float mx = Ar[k][k] * Ar[k][k] + Ai[k][k] * Ai[k][k];
    for (int i = k + 1; i < 8; i++) {
      float m2 = Ar[i][k] * Ar[i][k] + Ai[i][k] * Ai[i][k];
      if (m2 > mx) { mx = m2; piv = i; }
    }
    if (piv != k) {
      for (int j = 0; j < 8; j++) {
        float t0;
        t0 = Ar[k][j]; Ar[k][j] = Ar[piv][j]; Ar[piv][j] = t0;
        t0 = Ai[k][j]; Ai[k][j] = Ai[piv][j]; Ai[piv][j] = t0;
        t0 = Br[k][j]; Br[k][j] = Br[piv][j]; Br[piv][j] = t0;
        t0 = Bi[k][j]; Bi[k][j] = Bi[piv][j]; Bi[piv][j] = t0;
      }
    }
    float dr = Ar[k][k], di = Ai[k][k];
    float inv = 1.f / (dr * dr + di * di);
    float irr = dr * inv, iii = -di * inv;
    for (int j = 0; j < 8; j++) {
      float xr = Ar[k][j], xi = Ai[k][j];
      Ar[k][j] = xr * irr - xi * iii; Ai[k][j] = xr * iii + xi * irr;
      xr = Br[k][j]; xi = Bi[k][j];
      Br[k][j] = xr * irr - xi * iii; Bi[k][j] = xr * iii + xi * irr;
    }
    for (int i = 0; i < 8; i++) {
      if (i == k) continue;
      float fr = Ar[i][k], fi = Ai[i][k];
      for (int j = 0; j < 8; j++) {
        float kr = Ar[k][j], ki = Ai[k][j];
        Ar[i][j] -= fr * kr - fi * ki;
        Ai[i][j] -= fr * ki + fi * kr;
        kr = Br[k][j]; ki = Bi[k][j];
        Br[i][j] -= fr * kr - fi * ki;
        Bi[i][j] -= fr * ki + fi * kr;
      }
    }
  }
  float trr = 1e-8f, tri = 0.f;
  for (int i = 0; i < 8; i++) { trr += Br[i][i]; tri += Bi[i][i]; }
  float inv = 1.f / (trr * trr + tri * tri);
  for (int c = 0; c < 8; c++) {
    float xr = Br[c][0], xi = Bi[c][0];
    WV[((long)idx * 8 + c) * 2]     = (xr * trr + xi * tri) * inv;
    WV[((long)idx * 8 + c) * 2 + 1] = (xi * trr - xr * tri) * inv;
  }
}

// ---------------- beamform -> pre-split ENH (KPAD rows) ----------------
__launch_bounds__(320)
__global__ void k_beam(const float* __restrict__ S, const float* __restrict__ WV,
                       unsigned short* __restrict__ ENHh, unsigned short* __restrict__ ENHl) {
  __shared__ float WL[NF * 16];
  int bb = blockIdx.x / TT, t = blockIdx.x - bb * TT;
  for (int i = threadIdx.x; i < NF * 16; i += 320) WL[i] = WV[(long)bb * NF * 16 + i];
  __syncthreads();
  int f = threadIdx.x;
  long base = ((long)bb * TT + t) * KPAD;
  if (f < NF) {
    float er = 0.f, ei = 0.f;
#pragma unroll
    for (int c = 0; c < 8; c++) {
      float wr = WL[(f * 8 + c) * 2], wi = WL[(f * 8 + c) * 2 + 1];
      const float* srow = S + (((long)(bb * 8 + c) * TT) + t) * DD;
      float sr = srow[f], si = srow[NF + f];
      er += wr * sr + wi * si;
      ei += wr * si - wi * sr;
    }
    split_bf16(er, &ENHh[base + f], &ENHl[base + f]);
    split_bf16(ei, &ENHh[base + NF + f], &ENHl[base + NF + f]);
  }
  int z = threadIdx.x - 288;   // threads 288..317 zero the 30 K-pad cols
  if (z >= 0 && z < 30) { ENHh[base + DD + z] = 0; ENHl[base + DD + z] = 0; }
}

// ---------------- overlap-add + normalize + crop ----------------
__global__ void k_ola(const float* __restrict__ IFR, const float* __restrict__ WSQ,
                      float* __restrict__ out) {
  int idx = blockIdx.x * 256 + threadIdx.x;
  if (idx >= NB * LSEQ) return;
  int b = idx / LSEQ, l = idx - b * LSEQ;
  int p = l + FPAD;
  int t0 = (p <= 511) ? 0 : (p - 352) / 160;
  int t1 = p / 160; if (t1 > 600) t1 = 600;
  float s = 0.f;
  for (int t = t0; t <= t1; t++) s += IFR[((long)b * TT + t) * NFFT + (p - t * HOP)];
  out[idx] = s / fmaxf(WSQ[p], 1e-11f);
}

// ---------------- driver ----------------
extern "C" void kernel_launch(void* const* d_in, const int* in_sizes, int n_in,
                              void* d_out, int out_size, void* d_ws, size_t ws_size,
                              hipStream_t stream) {
  (void)in_sizes; (void)n_in; (void)out_size; (void)ws_size;
  const float* x   = (const float*)d_in[0];
  const float* Wih = (const float*)d_in[1];
  const float* Whh = (const float*)d_in[2];
  const float* bih = (const float*)d_in[3];
  const float* bhh = (const float*)d_in[4];
  const float* W1  = (const float*)d_in[5];
  const float* b1  = (const float*)d_in[6];
  const float* W2  = (const float*)d_in[7];
  const float* b2  = (const float*)d_in[8];
  float* ws = (float*)d_ws;

  // XP region: pre-split XPh/XPl (exactly fills old XP fp32 footprint); IFR aliases later.
  unsigned short* XPh = (unsigned short*)(ws + 0);            // 6,176,768 ush = 3,088,384 fl
  unsigned short* XPl = (unsigned short*)(ws + 3088384);      // -> region ends 6,176,768 fl
  float* S     = ws + 6176768;    // 19,774,496
  float* XWM   = ws + 25951264;   // 19,774,496 (XW then MS; WhhP4 in tail)
  float* HOUT  = ws + 45725760;   // 4,924,288 (pre-GEMM scratch + post-beam ENH split live here too)
  float* PSD_S = ws + 50650048;   // 263,168
  float* PSD_N = ws + 50913216;   // 263,168
  float* WV    = ws + 51176384;   // 32,896
  float* BSUM  = ws + 51209280;   // 512
  float* WSQ   = ws + 51209792;   // 96,512 -> 51,306,304
  unsigned short* W1sh = (unsigned short*)(ws + 51306304);
  unsigned short* W1sl = (unsigned short*)(ws + 51347264);
  unsigned short* W2sh = (unsigned short*)(ws + 51388224);
  unsigned short* W2sl = (unsigned short*)(ws + 51429184); // -> 51,470,144
  unsigned short* WTth = (unsigned short*)(ws + 51470144); // 139,264 fl
  unsigned short* WTtl = (unsigned short*)(ws + 51609408); // -> 51,748,672
  unsigned short* BIth = (unsigned short*)(ws + 51748672); // 139,264 fl
  unsigned short* BItl = (unsigned short*)(ws + 51887936); // -> end 52,027,200 (~208 MB)
  float* MS    = XWM;
  float* IFR   = ws + 0;          // aliases XP region after gemm4
  unsigned int* WhhP4 = (unsigned int*)(XWM + 19693568);   // after true end of XW
  // Pre-GEMM scratch inside HOUT (dead until k_lstm):
  float* BFf = HOUT;                                        // 263,168 fl
  float* BWf = HOUT + 263168;                               // 262,144 fl
  unsigned short* BCh = (unsigned short*)(HOUT + 525312);   // 1152*544 ush = 313,344 fl
  unsigned short* BCl = (unsigned short*)(HOUT + 838656);   // -> 1,152,000 fl < 4,924,288
  // Post-beam ENH split in HOUT (Hout consumed by maskms before k_beam):
  unsigned short* ENHh = (unsigned short*)HOUT;             // 4808*544 ush = 1,307,776 fl
  unsigned short* ENHl = (unsigned short*)(HOUT + 1307776);

  // fused init: xp + wsq + bff + wtsplit + bisplit + bsum + wmsplit + wpack
  k_init<<<NINIT, 256, 0, stream>>>(x, Wih, Whh, bih, bhh, W1, W2,
                                    XPh, XPl, WSQ, BFf, WTth, WTtl, BIth, BItl,
                                    BSUM, W1sh, W1sl, W2sh, W2sl, WhhP4);

  // BW = BF @ Wih^T  (512x512, K=514) — small gemm3
  {
    dim3 g(4, 4);
    k_gemm3<0><<<g, 256, 0, stream>>>(BFf, WTth, WTtl, nullptr, BWf, 512, 512, DD, DD, G4);
  }
  // combined split B = [BF | BW]
  k_bcomb<<<(1152 * KPAD + 255) / 256, 256, 0, stream>>>(BWf, BCh, BCl);

  // fused STFT + xW: S[38464,514] and XW[38464,512] in one gather-GEMM
  {
    dim3 g(9, 301);
    k_gemm4<<<g, 256, 0, stream>>>(XPh, XPl, BCh, BCl, BSUM, S, XWM);
  }

  k_lstm<<<64, 512, 0, stream>>>(XWM, WhhP4, HOUT);

  dim3 gm(9, 601);
  k_maskms<<<gm, 256, 0, stream>>>(HOUT, W1sh, W1sl, b1, S, MS);
  k_psd<<<NB * NF, 256, 0, stream>>>(MS, PSD_S);
  k_maskms<<<gm, 256, 0, stream>>>(HOUT, W2sh, W2sl, b2, S, MS);
  k_psd<<<NB * NF, 256, 0, stream>>>(MS, PSD_N);

  k_solve<<<(NB * NF + 63) / 64, 64, 0, stream>>>(PSD_S, PSD_N, WV);
  k_beam<<<NB * TT, 320, 0, stream>>>(S, WV, ENHh, ENHl);

  // iSTFT: IFR[4808,512] = ENH @ BI (pre-split A)
  {
    dim3 g(4, 38);
    k_gemm5<<<g, 256, 0, stream>>>(ENHh, ENHl, BIth, BItl, IFR, NB * TT, NFFT, NFFT);
  }

  k_ola<<<(NB * LSEQ + 255) / 256, 256, 0, stream>>>(IFR, WSQ, (float*)d_out);
}

// Round 8
// 1148.430 us; speedup vs baseline: 1.3445x; 1.0016x over previous
//
#include <hip/hip_runtime.h>
#include <math.h>

#define NFFT  512
#define WINL  320
#define HOP   160
#define FPAD  256
#define NF    257
#define TT    601
#define LSEQ  96000
#define XPLEN 96512
#define NCH   8
#define NB    8
#define NSEQ  64
#define NROWS 38464   // NSEQ*TT
#define DD    514
#define HH    128
#define G4    512
#define KPAD  544     // 17*32, zero-padded K for split-B arrays
#define NCOMB 1026    // 514 (S cols) + 512 (XW cols)

// fused-init block ranges (all exact multiples of 256 threads)
#define NXP   24128   // NSEQ*XPLEN/256
#define NWSQ  377     // XPLEN/256
#define NBFF  1028    // NFFT*DD/256
#define NWT   1088    // G4*KPAD/256
#define NBI   1088    // NFFT*KPAD/256
#define NBS   2       // G4/256
#define NWM   640     // 2*640*HH/256
#define NWP   128     // G4*64/256
#define NINIT (NXP + NWSQ + NBFF + NWT + NBI + NBS + NWM + NWP)   // 28479

typedef _Float16 h2v __attribute__((ext_vector_type(2)));
typedef short bf16x8 __attribute__((ext_vector_type(8)));
typedef float f32x4 __attribute__((ext_vector_type(4)));

// ---------------- init helpers ----------------
__device__ __forceinline__ float winval(int k) {
  if (k < 96 || k >= 416) return 0.f;
  return 0.5f - 0.5f * cosf((float)(2.0 * M_PI / 320.0) * (float)(k - 96));
}

__device__ __forceinline__ void split_bf16(float v, unsigned short* h, unsigned short* l) {
  unsigned int hb = __float_as_uint(v) >> 16;
  float r = v - __uint_as_float(hb << 16);
  *h = (unsigned short)hb;
  *l = (unsigned short)(__float_as_uint(r) >> 16);
}

// async global->LDS, 16B per lane; dest is wave-uniform base + lane*16
__device__ __forceinline__ void glds16(const unsigned short* g, unsigned short* l) {
  __builtin_amdgcn_global_load_lds(
      (const __attribute__((address_space(1))) void*)g,
      (__attribute__((address_space(3))) void*)l,
      16, 0, 0);
}

// ---------------- fused init: 8 independent prep kernels in one launch ----------------
__global__ void k_init(const float* __restrict__ x, const float* __restrict__ Wih,
                       const float* __restrict__ Whh, const float* __restrict__ bih,
                       const float* __restrict__ bhh, const float* __restrict__ W1,
                       const float* __restrict__ W2,
                       unsigned short* __restrict__ XPh, unsigned short* __restrict__ XPl,
                       float* __restrict__ wsq, float* __restrict__ BFf,
                       unsigned short* __restrict__ WTh, unsigned short* __restrict__ WTl,
                       unsigned short* __restrict__ BIh, unsigned short* __restrict__ BIl,
                       float* __restrict__ BSUM,
                       unsigned short* __restrict__ W1h, unsigned short* __restrict__ W1l,
                       unsigned short* __restrict__ W2h, unsigned short* __restrict__ W2l,
                       unsigned int* __restrict__ WhhP4) {
  int b = blockIdx.x;
  const int tid = threadIdx.x;

  if (b < NXP) {                       // ---- k_xp ----
    int idx = b * 256 + tid;
    if (idx < NSEQ * XPLEN) {
      int n = idx / XPLEN, i = idx - n * XPLEN;
      int j = i - FPAD;
      if (j < 0) j = -j;
      else if (j >= LSEQ) j = 2 * LSEQ - 2 - j;
      int bb = n >> 3, c = n & 7;
      float v = x[((long)bb * LSEQ + j) * NCH + c];
      split_bf16(v, &XPh[idx], &XPl[idx]);
    }
    return;
  }
  b -= NXP;

  if (b < NWSQ) {                      // ---- k_wsq ----
    int p = b * 256 + tid;
    if (p < XPLEN) {
      int t0 = (p <= 511) ? 0 : (p - 352) / 160;
      int t1 = p / 160; if (t1 > 600) t1 = 600;
      float s = 0.f;
      for (int t = t0; t <= t1; t++) { float w = winval(p - t * HOP); s += w * w; }
      wsq[p] = s;
    }
    return;
  }
  b -= NWSQ;

  if (b < NBFF) {                      // ---- k_bff ----
    int idx = b * 256 + tid;
    if (idx < NFFT * DD) {
      int k = idx / DD, d = idx - k * DD;
      float w = winval(k);
      int f = (d < NF) ? d : d - NF;
      int m = (k * f) & 511;
      float th = (float)(M_PI / 256.0) * (float)m;
      BFf[idx] = ((d < NF) ? cosf(th) : -sinf(th)) * w;
    }
    return;
  }
  b -= NBFF;

  if (b < NWT) {                       // ---- k_wtsplit ----
    int idx = b * 256 + tid;
    if (idx < G4 * KPAD) {
      int n = idx / KPAD, k = idx - n * KPAD;
      float v = (k < DD) ? Wih[n * DD + k] : 0.f;
      split_bf16(v, &WTh[idx], &WTl[idx]);
    }
    return;
  }
  b -= NWT;

  if (b < NBI) {                       // ---- k_bisplit ----
    int idx = b * 256 + tid;
    if (idx < NFFT * KPAD) {
      int n = idx / KPAD, kk = idx - n * KPAD;
      float v = 0.f;
      if (kk < DD) {
        float w = winval(n);
        int f = (kk < NF) ? kk : kk - NF;
        int edge = (f == 0 || f == 256);
        float alpha = edge ? 1.f : 2.f;
        int m = (n * f) & 511;
        float th = (float)(M_PI / 256.0) * (float)m;
        float c;
        if (kk < NF) c = alpha * cosf(th);
        else         c = edge ? 0.f : -alpha * sinf(th);
        v = c * w * (1.f / 512.f);
      }
      split_bf16(v, &BIh[idx], &BIl[idx]);
    }
    return;
  }
  b -= NBI;

  if (b < NBS) {                       // ---- k_bsum ----
    int idx = b * 256 + tid;
    if (idx < G4) BSUM[idx] = bih[idx] + bhh[idx];
    return;
  }
  b -= NBS;

  if (b < NWM) {                       // ---- k_wmsplit ----
    int idx = b * 256 + tid;
    if (idx < 2 * 640 * HH) {
      int m = idx / (640 * HH);
      int rem = idx - m * 640 * HH;
      int np = rem / HH, k = rem - np * HH;
      int ri = np / 320, f = np - ri * 320;
      float v = 0.f;
      if (f < NF) {
        int fcol = (ri == 0) ? f : NF + f;
        v = (m == 0) ? W1[fcol * HH + k] : W2[fcol * HH + k];
      }
      unsigned short h, l;
      split_bf16(v, &h, &l);
      if (m == 0) { W1h[rem] = h; W1l[rem] = l; }
      else        { W2h[rem] = h; W2l[rem] = l; }
    }
    return;
  }
  b -= NWM;

  {                                    // ---- k_wpack ----
    int idx = b * 256 + tid;
    if (idx < G4 * 64) {
      int j = idx >> 6, k2 = idx & 63;
      _Float16 lo = (_Float16)Whh[j * HH + 2 * k2];
      _Float16 hi = (_Float16)Whh[j * HH + 2 * k2 + 1];
      unsigned int u = ((unsigned int)__builtin_bit_cast(unsigned short, hi) << 16)
                     |  (unsigned int)__builtin_bit_cast(unsigned short, lo);
      WhhP4[(k2 >> 2) * (G4 * 4) + j * 4 + (k2 & 3)] = u;
    }
  }
}

// Combined split B for the fused STFT+xW GEMM: BC[n][k], n in [0,1152)
__global__ void k_bcomb(const float* __restrict__ BWf, unsigned short* __restrict__ H,
                        unsigned short* __restrict__ L) {
  int idx = blockIdx.x * 256 + threadIdx.x;
  if (idx >= 1152 * KPAD) return;
  int n = idx / KPAD, k = idx - n * KPAD;
  float v = 0.f;
  if (k < NFFT) {
    if (n < DD) {
      float w = winval(k);
      int f = (n < NF) ? n : n - NF;
      int m = (k * f) & 511;
      float th = (float)(M_PI / 256.0) * (float)m;
      v = ((n < NF) ? cosf(th) : -sinf(th)) * w;
    } else if (n < NCOMB) {
      v = BWf[k * G4 + (n - 514)];
    }
  }
  split_bf16(v, &H[idx], &L[idx]);
}

// ---------------- split-bf16 MFMA GEMM (fp32 A): C[M,N] = A[M,K] * Bt^T (+bias) ----------------
template <int GATHER>
__launch_bounds__(256)
__global__ void k_gemm3(const float* __restrict__ A,
                        const unsigned short* __restrict__ Bth,
                        const unsigned short* __restrict__ Btl,
                        const float* __restrict__ bias, float* __restrict__ C,
                        int M, int N, int K, int lda, int ldc) {
  __shared__ __align__(16) unsigned short sAh[128 * 40];
  __shared__ __align__(16) unsigned short sAl[128 * 40];
  __shared__ __align__(16) unsigned short sBh[128 * 40];
  __shared__ __align__(16) unsigned short sBl[128 * 40];
  const int tid = threadIdx.x;
  const int row0 = blockIdx.y * 128, col0 = blockIdx.x * 128;
  const int sar = tid >> 1, sak = (tid & 1) * 16;
  const int arow = row0 + sar;
  long abase = (long)arow * lda;
  const bool arok = (arow < M);
  const int lane = tid & 63, w = tid >> 6;
  const int wm = (w >> 1) * 64, wn = (w & 1) * 64;
  const int l15 = lane & 15, quad = lane >> 4;
  f32x4 acc[4][4] = {};
  unsigned int* aH = (unsigned int*)sAh;
  unsigned int* aL = (unsigned int*)sAl;
  uint4* bH = (uint4*)sBh;
  uint4* bL = (uint4*)sBl;
  for (int k0 = 0; k0 < K; k0 += 32) {
#pragma unroll
    for (int i = 0; i < 8; i++) {
      int kk = k0 + sak + 2 * i;
      float v0 = 0.f, v1 = 0.f;
      if (arok) {
        if (kk + 1 < K) { float2 t2 = *(const float2*)(A + abase + kk); v0 = t2.x; v1 = t2.y; }
        else if (kk < K) { v0 = A[abase + kk]; }
      }
      unsigned int h0 = __float_as_uint(v0) >> 16, h1 = __float_as_uint(v1) >> 16;
      float r0 = v0 - __uint_as_float(h0 << 16), r1 = v1 - __uint_as_float(h1 << 16);
      unsigned int l0 = __float_as_uint(r0) >> 16, l1 = __float_as_uint(r1) >> 16;
      aH[sar * 20 + (sak >> 1) + i] = h0 | (h1 << 16);
      aL[sar * 20 + (sak >> 1) + i] = l0 | (l1 << 16);
    }
#pragma unroll
    for (int h = 0; h < 2; h++) {
      int idx = tid + h * 256;
      int r = idx >> 2, c = idx & 3;
      long go = (long)(col0 + r) * KPAD + k0 + c * 8;
      bH[r * 5 + c] = *(const uint4*)(Bth + go);
      bL[r * 5 + c] = *(const uint4*)(Btl + go);
    }
    __syncthreads();
    bf16x8 ah[4], al[4], bh[4], bl[4];
#pragma unroll
    for (int i = 0; i < 4; i++) {
      int off = (wm + i * 16 + l15) * 40 + quad * 8;
      ah[i] = *(const bf16x8*)(sAh + off);
      al[i] = *(const bf16x8*)(sAl + off);
      int boff = (wn + i * 16 + l15) * 40 + quad * 8;
      bh[i] = *(const bf16x8*)(sBh + boff);
      bl[i] = *(const bf16x8*)(sBl + boff);
    }
#pragma unroll
    for (int i = 0; i < 4; i++)
#pragma unroll
      for (int j = 0; j < 4; j++) {
        acc[i][j] = __builtin_amdgcn_mfma_f32_16x16x32_bf16(al[i], bh[j], acc[i][j], 0, 0, 0);
        acc[i][j] = __builtin_amdgcn_mfma_f32_16x16x32_bf16(ah[i], bl[j], acc[i][j], 0, 0, 0);
        acc[i][j] = __builtin_amdgcn_mfma_f32_16x16x32_bf16(ah[i], bh[j], acc[i][j], 0, 0, 0);
      }
    __syncthreads();
  }
#pragma unroll
  for (int i = 0; i < 4; i++)
#pragma unroll
    for (int j = 0; j < 4; j++) {
      int cc = col0 + wn + j * 16 + l15;
      if (cc >= N) continue;
      float bv = bias ? bias[cc] : 0.f;
#pragma unroll
      for (int rg = 0; rg < 4; rg++) {
        int rr = row0 + wm + i * 16 + quad * 4 + rg;
        if (rr < M) C[(long)rr * ldc + cc] = acc[i][j][rg] + bv;
      }
    }
}

// ---------------- fused STFT+xW GEMM v16: global_load_lds staging ----------------
// C[38464, 1026]: cols <514 -> S; cols 514..1025 -> XW (+bsum). K=512, tile 128x128.
// Staging via __builtin_amdgcn_global_load_lds width=16 (m97 pattern): LDS pitch
// 32 ush (linear, no pad - gload_lds requires contiguous dest); wave w stages
// rows [32w,32w+32) of each buffer, lane l covers row 32w+q*16+(l>>2), chunk
// l&3; the per-lane GLOBAL address carries the A-row gather. Chunk<->offset
// mapping identical to the reg-staged version (pitch change only) -> MFMA
// inputs bit-identical.
__launch_bounds__(256)
__global__ void k_gemm4(const unsigned short* __restrict__ Ah, const unsigned short* __restrict__ Al,
                        const unsigned short* __restrict__ Bh, const unsigned short* __restrict__ Bl,
                        const float* __restrict__ bsum, float* __restrict__ S,
                        float* __restrict__ XW) {
  __shared__ __align__(16) unsigned short sAh[128 * 32];
  __shared__ __align__(16) unsigned short sAl[128 * 32];
  __shared__ __align__(16) unsigned short sBh[128 * 32];
  __shared__ __align__(16) unsigned short sBl[128 * 32];
  const int tid = threadIdx.x;
  const int row0 = blockIdx.y * 128, col0 = blockIdx.x * 128;
  const int lane = tid & 63, w = tid >> 6;
  const int wm = (w >> 1) * 64, wn = (w & 1) * 64;
  const int l15 = lane & 15, quad = lane >> 4;
  // staging geometry
  const int sr0 = w * 32 + (lane >> 2);   // q=0 row (block-local)
  const int sr1 = sr0 + 16;               // q=1 row
  const int c8 = (lane & 3) * 8;          // 8-ush chunk offset
  long ab0, ab1;
  { int rr = row0 + sr0; int n = rr / TT, t = rr - n * TT; ab0 = (long)n * XPLEN + (long)t * HOP + c8; }
  { int rr = row0 + sr1; int n = rr / TT, t = rr - n * TT; ab1 = (long)n * XPLEN + (long)t * HOP + c8; }
  const long bb0 = (long)(col0 + sr0) * KPAD + c8;
  const long bb1 = (long)(col0 + sr1) * KPAD + c8;
  const int d0 = w * 1024;                // LDS dest base (ush), q=0
  const int d1 = d0 + 512;                // q=1
  f32x4 acc[4][4] = {};
  for (int k0 = 0; k0 < NFFT; k0 += 32) {
    glds16(Ah + ab0 + k0, sAh + d0);
    glds16(Ah + ab1 + k0, sAh + d1);
    glds16(Al + ab0 + k0, sAl + d0);
    glds16(Al + ab1 + k0, sAl + d1);
    glds16(Bh + bb0 + k0, sBh + d0);
    glds16(Bh + bb1 + k0, sBh + d1);
    glds16(Bl + bb0 + k0, sBl + d0);
    glds16(Bl + bb1 + k0, sBl + d1);
    __syncthreads();
    bf16x8 ah[4], al[4], bh[4], bl[4];
#pragma unroll
    for (int i = 0; i < 4; i++) {
      int off = (wm + i * 16 + l15) * 32 + quad * 8;
      ah[i] = *(const bf16x8*)(sAh + off);
      al[i] = *(const bf16x8*)(sAl + off);
      int boff = (wn + i * 16 + l15) * 32 + quad * 8;
      bh[i] = *(const bf16x8*)(sBh + boff);
      bl[i] = *(const bf16x8*)(sBl + boff);
    }
#pragma unroll
    for (int i = 0; i < 4; i++)
#pragma unroll
      for (int j = 0; j < 4; j++) {
        acc[i][j] = __builtin_amdgcn_mfma_f32_16x16x32_bf16(al[i], bh[j], acc[i][j], 0, 0, 0);
        acc[i][j] = __builtin_amdgcn_mfma_f32_16x16x32_bf16(ah[i], bl[j], acc[i][j], 0, 0, 0);
        acc[i][j] = __builtin_amdgcn_mfma_f32_16x16x32_bf16(ah[i], bh[j], acc[i][j], 0, 0, 0);
      }
    __syncthreads();
  }
#pragma unroll
  for (int i = 0; i < 4; i++)
#pragma unroll
    for (int j = 0; j < 4; j++) {
      int cc = col0 + wn + j * 16 + l15;
      if (cc >= NCOMB) continue;
#pragma unroll
      for (int rg = 0; rg < 4; rg++) {
        int rr = row0 + wm + i * 16 + quad * 4 + rg;
        if (rr >= NROWS) continue;
        float v = acc[i][j][rg];
        if (cc < DD) S[(long)rr * DD + cc] = v;
        else         XW[(long)rr * G4 + (cc - 514)] = v + bsum[cc - 514];
      }
    }
}

// ---------------- iSTFT GEMM: pre-split A (pitch KPAD), B = BI split ----------------
__launch_bounds__(256)
__global__ void k_gemm5(const unsigned short* __restrict__ Ah, const unsigned short* __restrict__ Al,
                        const unsigned short* __restrict__ Bh, const unsigned short* __restrict__ Bl,
                        float* __restrict__ C, int M, int N, int ldc) {
  __shared__ __align__(16) unsigned short sAh[128 * 40];
  __shared__ __align__(16) unsigned short sAl[128 * 40];
  __shared__ __align__(16) unsigned short sBh[128 * 40];
  __shared__ __align__(16) unsigned short sBl[128 * 40];
  const int tid = threadIdx.x;
  const int row0 = blockIdx.y * 128, col0 = blockIdx.x * 128;
  const int sr0 = tid >> 2, c4 = (tid & 3) * 8, cq = tid & 3;
  const int lane = tid & 63, w = tid >> 6;
  const int wm = (w >> 1) * 64, wn = (w & 1) * 64;
  const int l15 = lane & 15, quad = lane >> 4;
  f32x4 acc[4][4] = {};
  uint4* aH4 = (uint4*)sAh; uint4* aL4 = (uint4*)sAl;
  uint4* bH4 = (uint4*)sBh; uint4* bL4 = (uint4*)sBl;
  for (int k0 = 0; k0 < KPAD; k0 += 32) {
    {
      long go = (long)(row0 + sr0) * KPAD + k0 + c4;
      aH4[sr0 * 5 + cq] = *(const uint4*)(Ah + go);
      aL4[sr0 * 5 + cq] = *(const uint4*)(Al + go);
      go = (long)(row0 + sr0 + 64) * KPAD + k0 + c4;
      aH4[(sr0 + 64) * 5 + cq] = *(const uint4*)(Ah + go);
      aL4[(sr0 + 64) * 5 + cq] = *(const uint4*)(Al + go);
    }
    {
      long go = (long)(col0 + sr0) * KPAD + k0 + c4;
      bH4[sr0 * 5 + cq] = *(const uint4*)(Bh + go);
      bL4[sr0 * 5 + cq] = *(const uint4*)(Bl + go);
      go = (long)(col0 + sr0 + 64) * KPAD + k0 + c4;
      bH4[(sr0 + 64) * 5 + cq] = *(const uint4*)(Bh + go);
      bL4[(sr0 + 64) * 5 + cq] = *(const uint4*)(Bl + go);
    }
    __syncthreads();
    bf16x8 ah[4], al[4], bh[4], bl[4];
#pragma unroll
    for (int i = 0; i < 4; i++) {
      int off = (wm + i * 16 + l15) * 40 + quad * 8;
      ah[i] = *(const bf16x8*)(sAh + off);
      al[i] = *(const bf16x8*)(sAl + off);
      int boff = (wn + i * 16 + l15) * 40 + quad * 8;
      bh[i] = *(const bf16x8*)(sBh + boff);
      bl[i] = *(const bf16x8*)(sBl + boff);
    }
#pragma unroll
    for (int i = 0; i < 4; i++)
#pragma unroll
      for (int j = 0; j < 4; j++) {
        acc[i][j] = __builtin_amdgcn_mfma_f32_16x16x32_bf16(al[i], bh[j], acc[i][j], 0, 0, 0);
        acc[i][j] = __builtin_amdgcn_mfma_f32_16x16x32_bf16(ah[i], bl[j], acc[i][j], 0, 0, 0);
        acc[i][j] = __builtin_amdgcn_mfma_f32_16x16x32_bf16(ah[i], bh[j], acc[i][j], 0, 0, 0);
      }
    __syncthreads();
  }
#pragma unroll
  for (int i = 0; i < 4; i++)
#pragma unroll
    for (int j = 0; j < 4; j++) {
      int cc = col0 + wn + j * 16 + l15;
      if (cc >= N) continue;
#pragma unroll
      for (int rg = 0; rg < 4; rg++) {
        int rr = row0 + wm + i * 16 + quad * 4 + rg;
        if (rr < M) C[(long)rr * ldc + cc] = acc[i][j][rg];
      }
    }
}

// ---------------- LSTM v11 (proven local optimum, 382us): v8 structure + 3 stall removals ----------------
__device__ __forceinline__ float tanh_fast(float x) {
  float e = __expf(2.f * x);
  return 1.f - 2.f / (e + 1.f);
}

__launch_bounds__(512, 2)
__global__ void k_lstm(const float* __restrict__ XW, const unsigned int* __restrict__ WhhP4,
                       float* __restrict__ Hout) {
  __shared__ __align__(16) unsigned int hl2[64];
  __shared__ float gl[G4];
  const int j = threadIdx.x;
  const int n = blockIdx.x;
  const uint4* W4 = (const uint4*)WhhP4;
  unsigned int wp[64];
#pragma unroll
  for (int i4 = 0; i4 < 16; i4++) {
    uint4 v = W4[i4 * G4 + j];
    wp[4 * i4]     = v.x;
    wp[4 * i4 + 1] = v.y;
    wp[4 * i4 + 2] = v.z;
    wp[4 * i4 + 3] = v.w;
  }
  float cst = 0.f;
  if (j < 64) hl2[j] = 0u;
  const float* xwrow = XW + (long)n * TT * G4 + j;
  float xnext = xwrow[0];
  const uint4* h4 = (const uint4*)hl2;
  const bool isg = (j >= 2 * HH) && (j < 3 * HH);   // 'g' gate rows -> tanh, else sigmoid
  __syncthreads();
  for (int t = 0; t < TT; t++) {
    float xv = xnext;
    if (t + 1 < TT) xnext = xwrow[(long)(t + 1) * G4];
    float a0 = 0.f, a1 = 0.f, a2 = 0.f, a3 = 0.f;
#pragma unroll
    for (int k = 0; k < 16; k++) {
      uint4 hv4 = h4[k];   // uniform address -> LDS broadcast, conflict-free
      a0 = __builtin_amdgcn_fdot2(__builtin_bit_cast(h2v, hv4.x), __builtin_bit_cast(h2v, wp[4 * k]),     a0, false);
      a1 = __builtin_amdgcn_fdot2(__builtin_bit_cast(h2v, hv4.y), __builtin_bit_cast(h2v, wp[4 * k + 1]), a1, false);
      a2 = __builtin_amdgcn_fdot2(__builtin_bit_cast(h2v, hv4.z), __builtin_bit_cast(h2v, wp[4 * k + 2]), a2, false);
      a3 = __builtin_amdgcn_fdot2(__builtin_bit_cast(h2v, hv4.w), __builtin_bit_cast(h2v, wp[4 * k + 3]), a3, false);
    }
    float a = ((a0 + a1) + (a2 + a3)) + xv;
    float nl;
    if (isg) nl = tanh_fast(a);
    else     nl = 1.f / (1.f + __expf(-a));
    gl[j] = nl;
    asm volatile("s_waitcnt lgkmcnt(0)" ::: "memory");
    __builtin_amdgcn_s_barrier();
    if (j < HH) {
      float ni = gl[j], nf = gl[HH + j], ng = gl[2 * HH + j], no = gl[3 * HH + j];
      cst = nf * cst + ni * ng;
      float hv = no * tanh_fast(cst);
      ((_Float16*)hl2)[j] = (_Float16)hv;
      Hout[((long)n * TT + t) * HH + j] = hv;
    }
    asm volatile("s_waitcnt lgkmcnt(0)" ::: "memory");
    __builtin_amdgcn_s_barrier();
  }
}

// ---------------- mask GEMM (split-bf16 MFMA) + mask apply + transpose ----------------
// MS layout: [b][f][c][t] complex-interleaved (re,im)
__launch_bounds__(256)
__global__ void k_maskms(const float* __restrict__ Hout,
                         const unsigned short* __restrict__ Wsh,
                         const unsigned short* __restrict__ Wsl,
                         const float* __restrict__ bias, const float* __restrict__ S,
                         float* __restrict__ MS) {
  __shared__ __align__(16) unsigned short sAh[64 * 40];
  __shared__ __align__(16) unsigned short sAl[64 * 40];
  __shared__ __align__(16) unsigned short sBh[64 * 40];
  __shared__ __align__(16) unsigned short sBl[64 * 40];
  __shared__ float Cs[64][68];
  __shared__ float SR[64][33];
  __shared__ float SI[64][33];
  const int tid = threadIdx.x;
  const int f0 = blockIdx.x * 32;
  const int row0 = blockIdx.y * 64;
  const int lane = tid & 63, w = tid >> 6;
  const int wm = w * 16;
  const int l15 = lane & 15, quad = lane >> 4;
  const int sar = tid >> 2;
  const int sak = (tid & 3) * 8;
  const int np = ((sar < 32) ? 0 : 320 - 32) + f0 + sar;
  unsigned int* aH = (unsigned int*)sAh;
  unsigned int* aL = (unsigned int*)sAl;
  f32x4 acc[4] = {};
  for (int k0 = 0; k0 < HH; k0 += 32) {
    {
      const float* ap = Hout + (long)(row0 + sar) * HH + k0 + sak;
      float4 v0 = *(const float4*)ap;
      float4 v1 = *(const float4*)(ap + 4);
      float vv[8] = {v0.x, v0.y, v0.z, v0.w, v1.x, v1.y, v1.z, v1.w};
#pragma unroll
      for (int i = 0; i < 4; i++) {
        unsigned int h0 = __float_as_uint(vv[2 * i]) >> 16, h1 = __float_as_uint(vv[2 * i + 1]) >> 16;
        float r0 = vv[2 * i] - __uint_as_float(h0 << 16), r1 = vv[2 * i + 1] - __uint_as_float(h1 << 16);
        unsigned int l0 = __float_as_uint(r0) >> 16, l1 = __float_as_uint(r1) >> 16;
        aH[sar * 20 + (sak >> 1) + i] = h0 | (h1 << 16);
        aL[sar * 20 + (sak >> 1) + i] = l0 | (l1 << 16);
      }
    }
    {
      long go = (long)np * HH + k0 + sak;
      *(uint4*)(sBh + sar * 40 + sak) = *(const uint4*)(Wsh + go);
      *(uint4*)(sBl + sar * 40 + sak) = *(const uint4*)(Wsl + go);
    }
    __syncthreads();
    bf16x8 ah = *(const bf16x8*)(sAh + (wm + l15) * 40 + quad * 8);
    bf16x8 al = *(const bf16x8*)(sAl + (wm + l15) * 40 + quad * 8);
#pragma unroll
    for (int ct = 0; ct < 4; ct++) {
      bf16x8 bh = *(const bf16x8*)(sBh + (ct * 16 + l15) * 40 + quad * 8);
      bf16x8 bl = *(const bf16x8*)(sBl + (ct * 16 + l15) * 40 + quad * 8);
      acc[ct] = __builtin_amdgcn_mfma_f32_16x16x32_bf16(al, bh, acc[ct], 0, 0, 0);
      acc[ct] = __builtin_amdgcn_mfma_f32_16x16x32_bf16(ah, bl, acc[ct], 0, 0, 0);
      acc[ct] = __builtin_amdgcn_mfma_f32_16x16x32_bf16(ah, bh, acc[ct], 0, 0, 0);
    }
    __syncthreads();
  }
#pragma unroll
  for (int ct = 0; ct < 4; ct++) {
    int col = ct * 16 + l15;
    int f = f0 + (col & 31);
    int fcol = (col < 32) ? f : NF + f;
    float bv = (f < NF) ? bias[fcol] : 0.f;
#pragma unroll
    for (int rg = 0; rg < 4; rg++) Cs[wm + quad * 4 + rg][col] = acc[ct][rg] + bv;
  }
  __syncthreads();
  {
    int fl = tid & 31, r8 = tid >> 5;
    int f = f0 + fl;
#pragma unroll
    for (int i = 0; i < 8; i++) {
      int rl = r8 * 8 + i;
      int rr = row0 + rl;
      float rm = Cs[rl][fl], im = Cs[rl][32 + fl];
      float sr = 0.f, si = 0.f;
      if (f < NF) { sr = S[(long)rr * DD + f]; si = S[(long)rr * DD + NF + f]; }
      SR[rl][fl] = rm * sr - im * si;
      SI[rl][fl] = rm * si + im * sr;
    }
  }
  __syncthreads();
  {
    int tl = tid & 63, fq = tid >> 6;
    int rr = row0 + tl;
    int n = rr / TT, t = rr - n * TT;
    int b = n >> 3, c = n & 7;
#pragma unroll
    for (int i = 0; i < 8; i++) {
      int fl = fq * 8 + i;
      int f = f0 + fl;
      if (f < NF) {
        long addr = ((((long)b * NF + f) * 8 + c) * (long)TT + t) * 2;
        *(float2*)&MS[addr] = make_float2(SR[tl][fl], SI[tl][fl]);
      }
    }
  }
}

// ---------------- PSD: one block per (b,f); complex-interleaved MS ----------------
__launch_bounds__(256)
__global__ void k_psd(const float* __restrict__ MS, float* __restrict__ PSD) {
  __shared__ float buf[9616];
  __shared__ float part[64][8];
  const int tid = threadIdx.x;
  const long base = (long)blockIdx.x * 9616;
  for (int i = tid; i < 9616; i += 256) buf[i] = MS[base + i];
  __syncthreads();
  int p = tid & 63, q = tid >> 6;
  int c = p >> 3, e = p & 7;
  const float2* xc = (const float2*)&buf[c * 1202];
  const float2* xe = (const float2*)&buf[e * 1202];
  int t0 = q * 150, t1 = (q == 3) ? TT : t0 + 150;
  float ar = 0.f, ai = 0.f;
  for (int t = t0; t < t1; t++) {
    float2 m = xc[t];
    float2 v = xe[t];
    ar += m.x * v.x + m.y * v.y;
    ai += m.y * v.x - m.x * v.y;
  }
  part[p][q * 2] = ar; part[p][q * 2 + 1] = ai;
  __syncthreads();
  if (tid < 64) {
    float sr = part[tid][0] + part[tid][2] + part[tid][4] + part[tid][6];
    float si = part[tid][1] + part[tid][3] + part[tid][5] + part[tid][7];
    PSD[((long)blockIdx.x * 64 + tid) * 2]     = sr * (1.f / 601.f);
    PSD[((long)blockIdx.x * 64 + tid) * 2 + 1] = si * (1.f / 601.f);
  }
}

// ---------------- 8x8 complex solve + MVDR weight ----------------
__launch_bounds__(64)
__global__ void k_solve(const float* __restrict__ PS, const float* __restrict__ PN,
                        float* __restrict__ WV) {
  int idx = blockIdx.x * 64 + threadIdx.x;
  if (idx >= NB * NF) return;
  float Ar[8][8], Ai[8][8], Br[8][8], Bi[8][8];
  const float* pn = PN + (long)idx * 128;
  const float* ps = PS + (long)idx * 128;
  for (int i = 0; i < 8; i++)
    for (int j = 0; j < 8; j++) {
      Ar[i][j] = pn[(i * 8 + j) * 2]; Ai[i][j] = pn[(i * 8 + j) * 2 + 1];
      Br[i][j] = ps[(i * 8 + j) * 2]; Bi[i][j] = ps[(i * 8 + j) * 2 + 1];
    }
  float tr = 0.f;
  for (int i = 0; i < 8; i++) tr += Ar[i][i];
  float load = 1e-6f * tr / 8.f + 1e-8f;
  for (int i = 0; i < 8; i++) Ar[i][i] += load;
  for (int k = 0; k < 8; k++) {
    int piv = k; float mx = Ar[k][k] * Ar[k][k] + Ai[k][k] * Ai[k][k];
    for (int i = k + 1; i < 8; i++) {
      float m2 = Ar[i][k] * Ar[i][k] + Ai[i][k] * Ai[i][k];
      if (m2 > mx) { mx = m2; piv = i; }
    }
    if (piv != k) {
      for (int j = 0; j < 8; j++) {
        float t0;
        t0 = Ar[k][j]; Ar[k][j] = Ar[piv][j]; Ar[piv][j] = t0;
        t0 = Ai[k][j]; Ai[k][j] = Ai[piv][j]; Ai[piv][j] = t0;
        t0 = Br[k][j]; Br[k][j] = Br[piv][j]; Br[piv][j] = t0;
        t0 = Bi[k][j]; Bi[k][j] = Bi[piv][j]; Bi[piv][j] = t0;
      }
    }
    float dr = Ar[k][k], di = Ai[k][k];
    float inv = 1.f / (dr * dr + di * di);
    float irr = dr * inv, iii = -di * inv;
    for (int j = 0; j < 8; j++) {
      float xr = Ar[k][j], xi = Ai[k][j];
      Ar[k][j] = xr * irr - xi * iii; Ai[k][j] = xr * iii + xi * irr;
      xr = Br[k][j]; xi = Bi[k][j];
      Br[k][j] = xr * irr - xi * iii; Bi[k][j] = xr * iii + xi * irr;
    }
    for (int i = 0; i < 8; i++) {
      if (i == k) continue;
      float fr = Ar[i][k], fi = Ai[i][k];
      for (int j = 0; j < 8; j++) {
        float kr = Ar[k][j], ki = Ai[k][j];
        Ar[i][j] -= fr * kr - fi * ki;
        Ai[i][j] -= fr * ki + fi * kr;
        kr = Br[k][j]; ki = Bi[k][j];
        Br[i][j] -= fr * kr - fi * ki;
        Bi[i][j] -= fr * ki + fi * kr;
      }
    }
  }
  float trr = 1e-8f, tri = 0.f;
  for (int i = 0; i < 8; i++) { trr += Br[i][i]; tri += Bi[i][i]; }
  float inv = 1.f / (trr * trr + tri * tri);
  for (int c = 0; c < 8; c++) {
    float xr = Br[c][0], xi = Bi[c][0];
    WV[((long)idx * 8 + c) * 2]     = (xr * trr + xi * tri) * inv;
    WV[((long)idx * 8 + c) * 2 + 1] = (xi * trr - xr * tri) * inv;
  }
}

// ---------------- beamform -> pre-split ENH (KPAD rows) ----------------
__launch_bounds__(320)
__global__ void k_beam(const float* __restrict__ S, const float* __restrict__ WV,
                       unsigned short* __restrict__ ENHh, unsigned short* __restrict__ ENHl) {
  __shared__ float WL[NF * 16];
  int bb = blockIdx.x / TT, t = blockIdx.x - bb * TT;
  for (int i = threadIdx.x; i < NF * 16; i += 320) WL[i] = WV[(long)bb * NF * 16 + i];
  __syncthreads();
  int f = threadIdx.x;
  long base = ((long)bb * TT + t) * KPAD;
  if (f < NF) {
    float er = 0.f, ei = 0.f;
#pragma unroll
    for (int c = 0; c < 8; c++) {
      float wr = WL[(f * 8 + c) * 2], wi = WL[(f * 8 + c) * 2 + 1];
      const float* srow = S + (((long)(bb * 8 + c) * TT) + t) * DD;
      float sr = srow[f], si = srow[NF + f];
      er += wr * sr + wi * si;
      ei += wr * si - wi * sr;
    }
    split_bf16(er, &ENHh[base + f], &ENHl[base + f]);
    split_bf16(ei, &ENHh[base + NF + f], &ENHl[base + NF + f]);
  }
  int z = threadIdx.x - 288;   // threads 288..317 zero the 30 K-pad cols
  if (z >= 0 && z < 30) { ENHh[base + DD + z] = 0; ENHl[base + DD + z] = 0; }
}

// ---------------- overlap-add + normalize + crop ----------------
__global__ void k_ola(const float* __restrict__ IFR, const float* __restrict__ WSQ,
                      float* __restrict__ out) {
  int idx = blockIdx.x * 256 + threadIdx.x;
  if (idx >= NB * LSEQ) return;
  int b = idx / LSEQ, l = idx - b * LSEQ;
  int p = l + FPAD;
  int t0 = (p <= 511) ? 0 : (p - 352) / 160;
  int t1 = p / 160; if (t1 > 600) t1 = 600;
  float s = 0.f;
  for (int t = t0; t <= t1; t++) s += IFR[((long)b * TT + t) * NFFT + (p - t * HOP)];
  out[idx] = s / fmaxf(WSQ[p], 1e-11f);
}

// ---------------- driver ----------------
extern "C" void kernel_launch(void* const* d_in, const int* in_sizes, int n_in,
                              void* d_out, int out_size, void* d_ws, size_t ws_size,
                              hipStream_t stream) {
  (void)in_sizes; (void)n_in; (void)out_size; (void)ws_size;
  const float* x   = (const float*)d_in[0];
  const float* Wih = (const float*)d_in[1];
  const float* Whh = (const float*)d_in[2];
  const float* bih = (const float*)d_in[3];
  const float* bhh = (const float*)d_in[4];
  const float* W1  = (const float*)d_in[5];
  const float* b1  = (const float*)d_in[6];
  const float* W2  = (const float*)d_in[7];
  const float* b2  = (const float*)d_in[8];
  float* ws = (float*)d_ws;

  // XP region: pre-split XPh/XPl (exactly fills old XP fp32 footprint); IFR aliases later.
  unsigned short* XPh = (unsigned short*)(ws + 0);            // 6,176,768 ush = 3,088,384 fl
  unsigned short* XPl = (unsigned short*)(ws + 3088384);      // -> region ends 6,176,768 fl
  float* S     = ws + 6176768;    // 19,774,496
  float* XWM   = ws + 25951264;   // 19,774,496 (XW then MS; WhhP4 in tail)
  float* HOUT  = ws + 45725760;   // 4,924,288 (pre-GEMM scratch + post-beam ENH split live here too)
  float* PSD_S = ws + 50650048;   // 263,168
  float* PSD_N = ws + 50913216;   // 263,168
  float* WV    = ws + 51176384;   // 32,896
  float* BSUM  = ws + 51209280;   // 512
  float* WSQ   = ws + 51209792;   // 96,512 -> 51,306,304
  unsigned short* W1sh = (unsigned short*)(ws + 51306304);
  unsigned short* W1sl = (unsigned short*)(ws + 51347264);
  unsigned short* W2sh = (unsigned short*)(ws + 51388224);
  unsigned short* W2sl = (unsigned short*)(ws + 51429184); // -> 51,470,144
  unsigned short* WTth = (unsigned short*)(ws + 51470144); // 139,264 fl
  unsigned short* WTtl = (unsigned short*)(ws + 51609408); // -> 51,748,672
  unsigned short* BIth = (unsigned short*)(ws + 51748672); // 139,264 fl
  unsigned short* BItl = (unsigned short*)(ws + 51887936); // -> end 52,027,200 (~208 MB)
  float* MS    = XWM;
  float* IFR   = ws + 0;          // aliases XP region after gemm4
  unsigned int* WhhP4 = (unsigned int*)(XWM + 19693568);   // after true end of XW
  // Pre-GEMM scratch inside HOUT (dead until k_lstm):
  float* BFf = HOUT;                                        // 263,168 fl
  float* BWf = HOUT + 263168;                               // 262,144 fl
  unsigned short* BCh = (unsigned short*)(HOUT + 525312);   // 1152*544 ush = 313,344 fl
  unsigned short* BCl = (unsigned short*)(HOUT + 838656);   // -> 1,152,000 fl < 4,924,288
  // Post-beam ENH split in HOUT (Hout consumed by maskms before k_beam):
  unsigned short* ENHh = (unsigned short*)HOUT;             // 4808*544 ush = 1,307,776 fl
  unsigned short* ENHl = (unsigned short*)(HOUT + 1307776);

  // fused init: xp + wsq + bff + wtsplit + bisplit + bsum + wmsplit + wpack
  k_init<<<NINIT, 256, 0, stream>>>(x, Wih, Whh, bih, bhh, W1, W2,
                                    XPh, XPl, WSQ, BFf, WTth, WTtl, BIth, BItl,
                                    BSUM, W1sh, W1sl, W2sh, W2sl, WhhP4);

  // BW = BF @ Wih^T  (512x512, K=514) — small gemm3
  {
    dim3 g(4, 4);
    k_gemm3<0><<<g, 256, 0, stream>>>(BFf, WTth, WTtl, nullptr, BWf, 512, 512, DD, DD, G4);
  }
  // combined split B = [BF | BW]
  k_bcomb<<<(1152 * KPAD + 255) / 256, 256, 0, stream>>>(BWf, BCh, BCl);

  // fused STFT + xW: S[38464,514] and XW[38464,512] in one gather-GEMM
  {
    dim3 g(9, 301);
    k_gemm4<<<g, 256, 0, stream>>>(XPh, XPl, BCh, BCl, BSUM, S, XWM);
  }

  k_lstm<<<64, 512, 0, stream>>>(XWM, WhhP4, HOUT);

  dim3 gm(9, 601);
  k_maskms<<<gm, 256, 0, stream>>>(HOUT, W1sh, W1sl, b1, S, MS);
  k_psd<<<NB * NF, 256, 0, stream>>>(MS, PSD_S);
  k_maskms<<<gm, 256, 0, stream>>>(HOUT, W2sh, W2sl, b2, S, MS);
  k_psd<<<NB * NF, 256, 0, stream>>>(MS, PSD_N);

  k_solve<<<(NB * NF + 63) / 64, 64, 0, stream>>>(PSD_S, PSD_N, WV);
  k_beam<<<NB * TT, 320, 0, stream>>>(S, WV, ENHh, ENHl);

  // iSTFT: IFR[4808,512] = ENH @ BI (pre-split A)
  {
    dim3 g(4, 38);
    k_gemm5<<<g, 256, 0, stream>>>(ENHh, ENHl, BIth, BItl, IFR, NB * TT, NFFT, NFFT);
  }

  k_ola<<<(NB * LSEQ + 255) / 256, 256, 0, stream>>>(IFR, WSQ, (float*)d_out);
}

// Round 9
// 1087.588 us; speedup vs baseline: 1.4197x; 1.0559x over previous
//
#include <hip/hip_runtime.h>
#include <math.h>

#define NFFT  512
#define WINL  320
#define HOP   160
#define FPAD  256
#define NF    257
#define TT    601
#define LSEQ  96000
#define XPLEN 96512
#define NCH   8
#define NB    8
#define NSEQ  64
#define NROWS 38464   // NSEQ*TT
#define DD    514
#define HH    128
#define G4    512
#define KPAD  544     // 17*32, zero-padded K for split-B arrays
#define NCOMB 1026    // 514 (S cols) + 512 (XW cols)

// fused-init block ranges (all exact multiples of 256 threads)
#define NXP   24128   // NSEQ*XPLEN/256
#define NWSQ  377     // XPLEN/256
#define NBFF  1028    // NFFT*DD/256
#define NWT   1088    // G4*KPAD/256
#define NBI   1088    // NFFT*KPAD/256
#define NBS   2       // G4/256
#define NWM   640     // 2*640*HH/256
#define NWP   128     // G4*64/256
#define NINIT (NXP + NWSQ + NBFF + NWT + NBI + NBS + NWM + NWP)   // 28479

typedef _Float16 h2v __attribute__((ext_vector_type(2)));
typedef short bf16x8 __attribute__((ext_vector_type(8)));
typedef float f32x4 __attribute__((ext_vector_type(4)));

// ---------------- init helpers ----------------
__device__ __forceinline__ float winval(int k) {
  if (k < 96 || k >= 416) return 0.f;
  return 0.5f - 0.5f * cosf((float)(2.0 * M_PI / 320.0) * (float)(k - 96));
}

__device__ __forceinline__ void split_bf16(float v, unsigned short* h, unsigned short* l) {
  unsigned int hb = __float_as_uint(v) >> 16;
  float r = v - __uint_as_float(hb << 16);
  *h = (unsigned short)hb;
  *l = (unsigned short)(__float_as_uint(r) >> 16);
}

// async global->LDS, 16B per lane; dest is wave-uniform base + lane*16
__device__ __forceinline__ void glds16(const unsigned short* g, unsigned short* l) {
  __builtin_amdgcn_global_load_lds(
      (const __attribute__((address_space(1))) void*)g,
      (__attribute__((address_space(3))) void*)l,
      16, 0, 0);
}

// bijective XCD-chunk swizzle (m204 variant; works for nwg%8 != 0):
// HW dispatches blockIdx round-robin across 8 XCDs; this remap gives each XCD a
// CONTIGUOUS logical range, so blocks sharing an A-panel (consecutive logical
// ids) stay on one XCD's L2.
__device__ __forceinline__ int xcd_swz(int orig, int nwg) {
  int q = nwg >> 3, r = nwg & 7;
  int xcd = orig & 7, slot = orig >> 3;
  return (xcd < r ? xcd * (q + 1) : r * (q + 1) + (xcd - r) * q) + slot;
}

// ---------------- fused init: 8 independent prep kernels in one launch ----------------
__global__ void k_init(const float* __restrict__ x, const float* __restrict__ Wih,
                       const float* __restrict__ Whh, const float* __restrict__ bih,
                       const float* __restrict__ bhh, const float* __restrict__ W1,
                       const float* __restrict__ W2,
                       unsigned short* __restrict__ XPh, unsigned short* __restrict__ XPl,
                       float* __restrict__ wsq, float* __restrict__ BFf,
                       unsigned short* __restrict__ WTh, unsigned short* __restrict__ WTl,
                       unsigned short* __restrict__ BIh, unsigned short* __restrict__ BIl,
                       float* __restrict__ BSUM,
                       unsigned short* __restrict__ W1h, unsigned short* __restrict__ W1l,
                       unsigned short* __restrict__ W2h, unsigned short* __restrict__ W2l,
                       unsigned int* __restrict__ WhhP4) {
  int b = blockIdx.x;
  const int tid = threadIdx.x;

  if (b < NXP) {                       // ---- k_xp ----
    int idx = b * 256 + tid;
    if (idx < NSEQ * XPLEN) {
      int n = idx / XPLEN, i = idx - n * XPLEN;
      int j = i - FPAD;
      if (j < 0) j = -j;
      else if (j >= LSEQ) j = 2 * LSEQ - 2 - j;
      int bb = n >> 3, c = n & 7;
      float v = x[((long)bb * LSEQ + j) * NCH + c];
      split_bf16(v, &XPh[idx], &XPl[idx]);
    }
    return;
  }
  b -= NXP;

  if (b < NWSQ) {                      // ---- k_wsq ----
    int p = b * 256 + tid;
    if (p < XPLEN) {
      int t0 = (p <= 511) ? 0 : (p - 352) / 160;
      int t1 = p / 160; if (t1 > 600) t1 = 600;
      float s = 0.f;
      for (int t = t0; t <= t1; t++) { float w = winval(p - t * HOP); s += w * w; }
      wsq[p] = s;
    }
    return;
  }
  b -= NWSQ;

  if (b < NBFF) {                      // ---- k_bff ----
    int idx = b * 256 + tid;
    if (idx < NFFT * DD) {
      int k = idx / DD, d = idx - k * DD;
      float w = winval(k);
      int f = (d < NF) ? d : d - NF;
      int m = (k * f) & 511;
      float th = (float)(M_PI / 256.0) * (float)m;
      BFf[idx] = ((d < NF) ? cosf(th) : -sinf(th)) * w;
    }
    return;
  }
  b -= NBFF;

  if (b < NWT) {                       // ---- k_wtsplit ----
    int idx = b * 256 + tid;
    if (idx < G4 * KPAD) {
      int n = idx / KPAD, k = idx - n * KPAD;
      float v = (k < DD) ? Wih[n * DD + k] : 0.f;
      split_bf16(v, &WTh[idx], &WTl[idx]);
    }
    return;
  }
  b -= NWT;

  if (b < NBI) {                       // ---- k_bisplit ----
    int idx = b * 256 + tid;
    if (idx < NFFT * KPAD) {
      int n = idx / KPAD, kk = idx - n * KPAD;
      float v = 0.f;
      if (kk < DD) {
        float w = winval(n);
        int f = (kk < NF) ? kk : kk - NF;
        int edge = (f == 0 || f == 256);
        float alpha = edge ? 1.f : 2.f;
        int m = (n * f) & 511;
        float th = (float)(M_PI / 256.0) * (float)m;
        float c;
        if (kk < NF) c = alpha * cosf(th);
        else         c = edge ? 0.f : -alpha * sinf(th);
        v = c * w * (1.f / 512.f);
      }
      split_bf16(v, &BIh[idx], &BIl[idx]);
    }
    return;
  }
  b -= NBI;

  if (b < NBS) {                       // ---- k_bsum ----
    int idx = b * 256 + tid;
    if (idx < G4) BSUM[idx] = bih[idx] + bhh[idx];
    return;
  }
  b -= NBS;

  if (b < NWM) {                       // ---- k_wmsplit ----
    int idx = b * 256 + tid;
    if (idx < 2 * 640 * HH) {
      int m = idx / (640 * HH);
      int rem = idx - m * 640 * HH;
      int np = rem / HH, k = rem - np * HH;
      int ri = np / 320, f = np - ri * 320;
      float v = 0.f;
      if (f < NF) {
        int fcol = (ri == 0) ? f : NF + f;
        v = (m == 0) ? W1[fcol * HH + k] : W2[fcol * HH + k];
      }
      unsigned short h, l;
      split_bf16(v, &h, &l);
      if (m == 0) { W1h[rem] = h; W1l[rem] = l; }
      else        { W2h[rem] = h; W2l[rem] = l; }
    }
    return;
  }
  b -= NWM;

  {                                    // ---- k_wpack ----
    int idx = b * 256 + tid;
    if (idx < G4 * 64) {
      int j = idx >> 6, k2 = idx & 63;
      _Float16 lo = (_Float16)Whh[j * HH + 2 * k2];
      _Float16 hi = (_Float16)Whh[j * HH + 2 * k2 + 1];
      unsigned int u = ((unsigned int)__builtin_bit_cast(unsigned short, hi) << 16)
                     |  (unsigned int)__builtin_bit_cast(unsigned short, lo);
      WhhP4[(k2 >> 2) * (G4 * 4) + j * 4 + (k2 & 3)] = u;
    }
  }
}

// Combined split B for the fused STFT+xW GEMM: BC[n][k], n in [0,1152)
__global__ void k_bcomb(const float* __restrict__ BWf, unsigned short* __restrict__ H,
                        unsigned short* __restrict__ L) {
  int idx = blockIdx.x * 256 + threadIdx.x;
  if (idx >= 1152 * KPAD) return;
  int n = idx / KPAD, k = idx - n * KPAD;
  float v = 0.f;
  if (k < NFFT) {
    if (n < DD) {
      float w = winval(k);
      int f = (n < NF) ? n : n - NF;
      int m = (k * f) & 511;
      float th = (float)(M_PI / 256.0) * (float)m;
      v = ((n < NF) ? cosf(th) : -sinf(th)) * w;
    } else if (n < NCOMB) {
      v = BWf[k * G4 + (n - 514)];
    }
  }
  split_bf16(v, &H[idx], &L[idx]);
}

// ---------------- split-bf16 MFMA GEMM (fp32 A): C[M,N] = A[M,K] * Bt^T (+bias) ----------------
template <int GATHER>
__launch_bounds__(256)
__global__ void k_gemm3(const float* __restrict__ A,
                        const unsigned short* __restrict__ Bth,
                        const unsigned short* __restrict__ Btl,
                        const float* __restrict__ bias, float* __restrict__ C,
                        int M, int N, int K, int lda, int ldc) {
  __shared__ __align__(16) unsigned short sAh[128 * 40];
  __shared__ __align__(16) unsigned short sAl[128 * 40];
  __shared__ __align__(16) unsigned short sBh[128 * 40];
  __shared__ __align__(16) unsigned short sBl[128 * 40];
  const int tid = threadIdx.x;
  const int row0 = blockIdx.y * 128, col0 = blockIdx.x * 128;
  const int sar = tid >> 1, sak = (tid & 1) * 16;
  const int arow = row0 + sar;
  long abase = (long)arow * lda;
  const bool arok = (arow < M);
  const int lane = tid & 63, w = tid >> 6;
  const int wm = (w >> 1) * 64, wn = (w & 1) * 64;
  const int l15 = lane & 15, quad = lane >> 4;
  f32x4 acc[4][4] = {};
  unsigned int* aH = (unsigned int*)sAh;
  unsigned int* aL = (unsigned int*)sAl;
  uint4* bH = (uint4*)sBh;
  uint4* bL = (uint4*)sBl;
  for (int k0 = 0; k0 < K; k0 += 32) {
#pragma unroll
    for (int i = 0; i < 8; i++) {
      int kk = k0 + sak + 2 * i;
      float v0 = 0.f, v1 = 0.f;
      if (arok) {
        if (kk + 1 < K) { float2 t2 = *(const float2*)(A + abase + kk); v0 = t2.x; v1 = t2.y; }
        else if (kk < K) { v0 = A[abase + kk]; }
      }
      unsigned int h0 = __float_as_uint(v0) >> 16, h1 = __float_as_uint(v1) >> 16;
      float r0 = v0 - __uint_as_float(h0 << 16), r1 = v1 - __uint_as_float(h1 << 16);
      unsigned int l0 = __float_as_uint(r0) >> 16, l1 = __float_as_uint(r1) >> 16;
      aH[sar * 20 + (sak >> 1) + i] = h0 | (h1 << 16);
      aL[sar * 20 + (sak >> 1) + i] = l0 | (l1 << 16);
    }
#pragma unroll
    for (int h = 0; h < 2; h++) {
      int idx = tid + h * 256;
      int r = idx >> 2, c = idx & 3;
      long go = (long)(col0 + r) * KPAD + k0 + c * 8;
      bH[r * 5 + c] = *(const uint4*)(Bth + go);
      bL[r * 5 + c] = *(const uint4*)(Btl + go);
    }
    __syncthreads();
    bf16x8 ah[4], al[4], bh[4], bl[4];
#pragma unroll
    for (int i = 0; i < 4; i++) {
      int off = (wm + i * 16 + l15) * 40 + quad * 8;
      ah[i] = *(const bf16x8*)(sAh + off);
      al[i] = *(const bf16x8*)(sAl + off);
      int boff = (wn + i * 16 + l15) * 40 + quad * 8;
      bh[i] = *(const bf16x8*)(sBh + boff);
      bl[i] = *(const bf16x8*)(sBl + boff);
    }
#pragma unroll
    for (int i = 0; i < 4; i++)
#pragma unroll
      for (int j = 0; j < 4; j++) {
        acc[i][j] = __builtin_amdgcn_mfma_f32_16x16x32_bf16(al[i], bh[j], acc[i][j], 0, 0, 0);
        acc[i][j] = __builtin_amdgcn_mfma_f32_16x16x32_bf16(ah[i], bl[j], acc[i][j], 0, 0, 0);
        acc[i][j] = __builtin_amdgcn_mfma_f32_16x16x32_bf16(ah[i], bh[j], acc[i][j], 0, 0, 0);
      }
    __syncthreads();
  }
#pragma unroll
  for (int i = 0; i < 4; i++)
#pragma unroll
    for (int j = 0; j < 4; j++) {
      int cc = col0 + wn + j * 16 + l15;
      if (cc >= N) continue;
      float bv = bias ? bias[cc] : 0.f;
#pragma unroll
      for (int rg = 0; rg < 4; rg++) {
        int rr = row0 + wm + i * 16 + quad * 4 + rg;
        if (rr < M) C[(long)rr * ldc + cc] = acc[i][j][rg] + bv;
      }
    }
}

// ---------------- fused STFT+xW GEMM v17: gload_lds staging + XCD-chunk swizzle ----------------
// C[38464, 1026]: cols <514 -> S; cols 514..1025 -> XW (+bsum). K=512, tile 128x128.
// 1-D grid of 9*301 blocks, remapped via xcd_swz so the 9 blocks sharing an
// A-row-panel (and the B-panel re-hits every 9 blocks) stay on one XCD's L2.
__launch_bounds__(256)
__global__ void k_gemm4(const unsigned short* __restrict__ Ah, const unsigned short* __restrict__ Al,
                        const unsigned short* __restrict__ Bh, const unsigned short* __restrict__ Bl,
                        const float* __restrict__ bsum, float* __restrict__ S,
                        float* __restrict__ XW) {
  __shared__ __align__(16) unsigned short sAh[128 * 32];
  __shared__ __align__(16) unsigned short sAl[128 * 32];
  __shared__ __align__(16) unsigned short sBh[128 * 32];
  __shared__ __align__(16) unsigned short sBl[128 * 32];
  const int tid = threadIdx.x;
  const int wg = xcd_swz(blockIdx.x, 9 * 301);
  const int row0 = (wg / 9) * 128, col0 = (wg % 9) * 128;
  const int lane = tid & 63, w = tid >> 6;
  const int wm = (w >> 1) * 64, wn = (w & 1) * 64;
  const int l15 = lane & 15, quad = lane >> 4;
  // staging geometry
  const int sr0 = w * 32 + (lane >> 2);   // q=0 row (block-local)
  const int sr1 = sr0 + 16;               // q=1 row
  const int c8 = (lane & 3) * 8;          // 8-ush chunk offset
  long ab0, ab1;
  { int rr = row0 + sr0; int n = rr / TT, t = rr - n * TT; ab0 = (long)n * XPLEN + (long)t * HOP + c8; }
  { int rr = row0 + sr1; int n = rr / TT, t = rr - n * TT; ab1 = (long)n * XPLEN + (long)t * HOP + c8; }
  const long bb0 = (long)(col0 + sr0) * KPAD + c8;
  const long bb1 = (long)(col0 + sr1) * KPAD + c8;
  const int d0 = w * 1024;                // LDS dest base (ush), q=0
  const int d1 = d0 + 512;                // q=1
  f32x4 acc[4][4] = {};
  for (int k0 = 0; k0 < NFFT; k0 += 32) {
    glds16(Ah + ab0 + k0, sAh + d0);
    glds16(Ah + ab1 + k0, sAh + d1);
    glds16(Al + ab0 + k0, sAl + d0);
    glds16(Al + ab1 + k0, sAl + d1);
    glds16(Bh + bb0 + k0, sBh + d0);
    glds16(Bh + bb1 + k0, sBh + d1);
    glds16(Bl + bb0 + k0, sBl + d0);
    glds16(Bl + bb1 + k0, sBl + d1);
    __syncthreads();
    bf16x8 ah[4], al[4], bh[4], bl[4];
#pragma unroll
    for (int i = 0; i < 4; i++) {
      int off = (wm + i * 16 + l15) * 32 + quad * 8;
      ah[i] = *(const bf16x8*)(sAh + off);
      al[i] = *(const bf16x8*)(sAl + off);
      int boff = (wn + i * 16 + l15) * 32 + quad * 8;
      bh[i] = *(const bf16x8*)(sBh + boff);
      bl[i] = *(const bf16x8*)(sBl + boff);
    }
#pragma unroll
    for (int i = 0; i < 4; i++)
#pragma unroll
      for (int j = 0; j < 4; j++) {
        acc[i][j] = __builtin_amdgcn_mfma_f32_16x16x32_bf16(al[i], bh[j], acc[i][j], 0, 0, 0);
        acc[i][j] = __builtin_amdgcn_mfma_f32_16x16x32_bf16(ah[i], bl[j], acc[i][j], 0, 0, 0);
        acc[i][j] = __builtin_amdgcn_mfma_f32_16x16x32_bf16(ah[i], bh[j], acc[i][j], 0, 0, 0);
      }
    __syncthreads();
  }
#pragma unroll
  for (int i = 0; i < 4; i++)
#pragma unroll
    for (int j = 0; j < 4; j++) {
      int cc = col0 + wn + j * 16 + l15;
      if (cc >= NCOMB) continue;
#pragma unroll
      for (int rg = 0; rg < 4; rg++) {
        int rr = row0 + wm + i * 16 + quad * 4 + rg;
        if (rr >= NROWS) continue;
        float v = acc[i][j][rg];
        if (cc < DD) S[(long)rr * DD + cc] = v;
        else         XW[(long)rr * G4 + (cc - 514)] = v + bsum[cc - 514];
      }
    }
}

// ---------------- iSTFT GEMM: pre-split A (pitch KPAD), B = BI split ----------------
__launch_bounds__(256)
__global__ void k_gemm5(const unsigned short* __restrict__ Ah, const unsigned short* __restrict__ Al,
                        const unsigned short* __restrict__ Bh, const unsigned short* __restrict__ Bl,
                        float* __restrict__ C, int M, int N, int ldc) {
  __shared__ __align__(16) unsigned short sAh[128 * 40];
  __shared__ __align__(16) unsigned short sAl[128 * 40];
  __shared__ __align__(16) unsigned short sBh[128 * 40];
  __shared__ __align__(16) unsigned short sBl[128 * 40];
  const int tid = threadIdx.x;
  const int row0 = blockIdx.y * 128, col0 = blockIdx.x * 128;
  const int sr0 = tid >> 2, c4 = (tid & 3) * 8, cq = tid & 3;
  const int lane = tid & 63, w = tid >> 6;
  const int wm = (w >> 1) * 64, wn = (w & 1) * 64;
  const int l15 = lane & 15, quad = lane >> 4;
  f32x4 acc[4][4] = {};
  uint4* aH4 = (uint4*)sAh; uint4* aL4 = (uint4*)sAl;
  uint4* bH4 = (uint4*)sBh; uint4* bL4 = (uint4*)sBl;
  for (int k0 = 0; k0 < KPAD; k0 += 32) {
    {
      long go = (long)(row0 + sr0) * KPAD + k0 + c4;
      aH4[sr0 * 5 + cq] = *(const uint4*)(Ah + go);
      aL4[sr0 * 5 + cq] = *(const uint4*)(Al + go);
      go = (long)(row0 + sr0 + 64) * KPAD + k0 + c4;
      aH4[(sr0 + 64) * 5 + cq] = *(const uint4*)(Ah + go);
      aL4[(sr0 + 64) * 5 + cq] = *(const uint4*)(Al + go);
    }
    {
      long go = (long)(col0 + sr0) * KPAD + k0 + c4;
      bH4[sr0 * 5 + cq] = *(const uint4*)(Bh + go);
      bL4[sr0 * 5 + cq] = *(const uint4*)(Bl + go);
      go = (long)(col0 + sr0 + 64) * KPAD + k0 + c4;
      bH4[(sr0 + 64) * 5 + cq] = *(const uint4*)(Bh + go);
      bL4[(sr0 + 64) * 5 + cq] = *(const uint4*)(Bl + go);
    }
    __syncthreads();
    bf16x8 ah[4], al[4], bh[4], bl[4];
#pragma unroll
    for (int i = 0; i < 4; i++) {
      int off = (wm + i * 16 + l15) * 40 + quad * 8;
      ah[i] = *(const bf16x8*)(sAh + off);
      al[i] = *(const bf16x8*)(sAl + off);
      int boff = (wn + i * 16 + l15) * 40 + quad * 8;
      bh[i] = *(const bf16x8*)(sBh + boff);
      bl[i] = *(const bf16x8*)(sBl + boff);
    }
#pragma unroll
    for (int i = 0; i < 4; i++)
#pragma unroll
      for (int j = 0; j < 4; j++) {
        acc[i][j] = __builtin_amdgcn_mfma_f32_16x16x32_bf16(al[i], bh[j], acc[i][j], 0, 0, 0);
        acc[i][j] = __builtin_amdgcn_mfma_f32_16x16x32_bf16(ah[i], bl[j], acc[i][j], 0, 0, 0);
        acc[i][j] = __builtin_amdgcn_mfma_f32_16x16x32_bf16(ah[i], bh[j], acc[i][j], 0, 0, 0);
      }
    __syncthreads();
  }
#pragma unroll
  for (int i = 0; i < 4; i++)
#pragma unroll
    for (int j = 0; j < 4; j++) {
      int cc = col0 + wn + j * 16 + l15;
      if (cc >= N) continue;
#pragma unroll
      for (int rg = 0; rg < 4; rg++) {
        int rr = row0 + wm + i * 16 + quad * 4 + rg;
        if (rr < M) C[(long)rr * ldc + cc] = acc[i][j][rg];
      }
    }
}

// ---------------- LSTM v11 (proven local optimum, 382us): v8 structure + 3 stall removals ----------------
__device__ __forceinline__ float tanh_fast(float x) {
  float e = __expf(2.f * x);
  return 1.f - 2.f / (e + 1.f);
}

__launch_bounds__(512, 2)
__global__ void k_lstm(const float* __restrict__ XW, const unsigned int* __restrict__ WhhP4,
                       float* __restrict__ Hout) {
  __shared__ __align__(16) unsigned int hl2[64];
  __shared__ float gl[G4];
  const int j = threadIdx.x;
  const int n = blockIdx.x;
  const uint4* W4 = (const uint4*)WhhP4;
  unsigned int wp[64];
#pragma unroll
  for (int i4 = 0; i4 < 16; i4++) {
    uint4 v = W4[i4 * G4 + j];
    wp[4 * i4]     = v.x;
    wp[4 * i4 + 1] = v.y;
    wp[4 * i4 + 2] = v.z;
    wp[4 * i4 + 3] = v.w;
  }
  float cst = 0.f;
  if (j < 64) hl2[j] = 0u;
  const float* xwrow = XW + (long)n * TT * G4 + j;
  float xnext = xwrow[0];
  const uint4* h4 = (const uint4*)hl2;
  const bool isg = (j >= 2 * HH) && (j < 3 * HH);   // 'g' gate rows -> tanh, else sigmoid
  __syncthreads();
  for (int t = 0; t < TT; t++) {
    float xv = xnext;
    if (t + 1 < TT) xnext = xwrow[(long)(t + 1) * G4];
    float a0 = 0.f, a1 = 0.f, a2 = 0.f, a3 = 0.f;
#pragma unroll
    for (int k = 0; k < 16; k++) {
      uint4 hv4 = h4[k];   // uniform address -> LDS broadcast, conflict-free
      a0 = __builtin_amdgcn_fdot2(__builtin_bit_cast(h2v, hv4.x), __builtin_bit_cast(h2v, wp[4 * k]),     a0, false);
      a1 = __builtin_amdgcn_fdot2(__builtin_bit_cast(h2v, hv4.y), __builtin_bit_cast(h2v, wp[4 * k + 1]), a1, false);
      a2 = __builtin_amdgcn_fdot2(__builtin_bit_cast(h2v, hv4.z), __builtin_bit_cast(h2v, wp[4 * k + 2]), a2, false);
      a3 = __builtin_amdgcn_fdot2(__builtin_bit_cast(h2v, hv4.w), __builtin_bit_cast(h2v, wp[4 * k + 3]), a3, false);
    }
    float a = ((a0 + a1) + (a2 + a3)) + xv;
    float nl;
    if (isg) nl = tanh_fast(a);
    else     nl = 1.f / (1.f + __expf(-a));
    gl[j] = nl;
    asm volatile("s_waitcnt lgkmcnt(0)" ::: "memory");
    __builtin_amdgcn_s_barrier();
    if (j < HH) {
      float ni = gl[j], nf = gl[HH + j], ng = gl[2 * HH + j], no = gl[3 * HH + j];
      cst = nf * cst + ni * ng;
      float hv = no * tanh_fast(cst);
      ((_Float16*)hl2)[j] = (_Float16)hv;
      Hout[((long)n * TT + t) * HH + j] = hv;
    }
    asm volatile("s_waitcnt lgkmcnt(0)" ::: "memory");
    __builtin_amdgcn_s_barrier();
  }
}

// ---------------- mask GEMM (split-bf16 MFMA) + mask apply + transpose ----------------
// MS layout: [b][f][c][t] complex-interleaved (re,im)
// 1-D grid of 9*601 blocks, XCD-chunk swizzled (same mechanism as gemm4).
__launch_bounds__(256)
__global__ void k_maskms(const float* __restrict__ Hout,
                         const unsigned short* __restrict__ Wsh,
                         const unsigned short* __restrict__ Wsl,
                         const float* __restrict__ bias, const float* __restrict__ S,
                         float* __restrict__ MS) {
  __shared__ __align__(16) unsigned short sAh[64 * 40];
  __shared__ __align__(16) unsigned short sAl[64 * 40];
  __shared__ __align__(16) unsigned short sBh[64 * 40];
  __shared__ __align__(16) unsigned short sBl[64 * 40];
  __shared__ float Cs[64][68];
  __shared__ float SR[64][33];
  __shared__ float SI[64][33];
  const int tid = threadIdx.x;
  const int wg = xcd_swz(blockIdx.x, 9 * 601);
  const int f0 = (wg % 9) * 32;
  const int row0 = (wg / 9) * 64;
  const int lane = tid & 63, w = tid >> 6;
  const int wm = w * 16;
  const int l15 = lane & 15, quad = lane >> 4;
  const int sar = tid >> 2;
  const int sak = (tid & 3) * 8;
  const int np = ((sar < 32) ? 0 : 320 - 32) + f0 + sar;
  unsigned int* aH = (unsigned int*)sAh;
  unsigned int* aL = (unsigned int*)sAl;
  f32x4 acc[4] = {};
  for (int k0 = 0; k0 < HH; k0 += 32) {
    {
      const float* ap = Hout + (long)(row0 + sar) * HH + k0 + sak;
      float4 v0 = *(const float4*)ap;
      float4 v1 = *(const float4*)(ap + 4);
      float vv[8] = {v0.x, v0.y, v0.z, v0.w, v1.x, v1.y, v1.z, v1.w};
#pragma unroll
      for (int i = 0; i < 4; i++) {
        unsigned int h0 = __float_as_uint(vv[2 * i]) >> 16, h1 = __float_as_uint(vv[2 * i + 1]) >> 16;
        float r0 = vv[2 * i] - __uint_as_float(h0 << 16), r1 = vv[2 * i + 1] - __uint_as_float(h1 << 16);
        unsigned int l0 = __float_as_uint(r0) >> 16, l1 = __float_as_uint(r1) >> 16;
        aH[sar * 20 + (sak >> 1) + i] = h0 | (h1 << 16);
        aL[sar * 20 + (sak >> 1) + i] = l0 | (l1 << 16);
      }
    }
    {
      long go = (long)np * HH + k0 + sak;
      *(uint4*)(sBh + sar * 40 + sak) = *(const uint4*)(Wsh + go);
      *(uint4*)(sBl + sar * 40 + sak) = *(const uint4*)(Wsl + go);
    }
    __syncthreads();
    bf16x8 ah = *(const bf16x8*)(sAh + (wm + l15) * 40 + quad * 8);
    bf16x8 al = *(const bf16x8*)(sAl + (wm + l15) * 40 + quad * 8);
#pragma unroll
    for (int ct = 0; ct < 4; ct++) {
      bf16x8 bh = *(const bf16x8*)(sBh + (ct * 16 + l15) * 40 + quad * 8);
      bf16x8 bl = *(const bf16x8*)(sBl + (ct * 16 + l15) * 40 + quad * 8);
      acc[ct] = __builtin_amdgcn_mfma_f32_16x16x32_bf16(al, bh, acc[ct], 0, 0, 0);
      acc[ct] = __builtin_amdgcn_mfma_f32_16x16x32_bf16(ah, bl, acc[ct], 0, 0, 0);
      acc[ct] = __builtin_amdgcn_mfma_f32_16x16x32_bf16(ah, bh, acc[ct], 0, 0, 0);
    }
    __syncthreads();
  }
#pragma unroll
  for (int ct = 0; ct < 4; ct++) {
    int col = ct * 16 + l15;
    int f = f0 + (col & 31);
    int fcol = (col < 32) ? f : NF + f;
    float bv = (f < NF) ? bias[fcol] : 0.f;
#pragma unroll
    for (int rg = 0; rg < 4; rg++) Cs[wm + quad * 4 + rg][col] = acc[ct][rg] + bv;
  }
  __syncthreads();
  {
    int fl = tid & 31, r8 = tid >> 5;
    int f = f0 + fl;
#pragma unroll
    for (int i = 0; i < 8; i++) {
      int rl = r8 * 8 + i;
      int rr = row0 + rl;
      float rm = Cs[rl][fl], im = Cs[rl][32 + fl];
      float sr = 0.f, si = 0.f;
      if (f < NF) { sr = S[(long)rr * DD + f]; si = S[(long)rr * DD + NF + f]; }
      SR[rl][fl] = rm * sr - im * si;
      SI[rl][fl] = rm * si + im * sr;
    }
  }
  __syncthreads();
  {
    int tl = tid & 63, fq = tid >> 6;
    int rr = row0 + tl;
    int n = rr / TT, t = rr - n * TT;
    int b = n >> 3, c = n & 7;
#pragma unroll
    for (int i = 0; i < 8; i++) {
      int fl = fq * 8 + i;
      int f = f0 + fl;
      if (f < NF) {
        long addr = ((((long)b * NF + f) * 8 + c) * (long)TT + t) * 2;
        *(float2*)&MS[addr] = make_float2(SR[tl][fl], SI[tl][fl]);
      }
    }
  }
}

// ---------------- PSD: one block per (b,f); complex-interleaved MS ----------------
__launch_bounds__(256)
__global__ void k_psd(const float* __restrict__ MS, float* __restrict__ PSD) {
  __shared__ float buf[9616];
  __shared__ float part[64][8];
  const int tid = threadIdx.x;
  const long base = (long)blockIdx.x * 9616;
  for (int i = tid; i < 9616; i += 256) buf[i] = MS[base + i];
  __syncthreads();
  int p = tid & 63, q = tid >> 6;
  int c = p >> 3, e = p & 7;
  const float2* xc = (const float2*)&buf[c * 1202];
  const float2* xe = (const float2*)&buf[e * 1202];
  int t0 = q * 150, t1 = (q == 3) ? TT : t0 + 150;
  float ar = 0.f, ai = 0.f;
  for (int t = t0; t < t1; t++) {
    float2 m = xc[t];
    float2 v = xe[t];
    ar += m.x * v.x + m.y * v.y;
    ai += m.y * v.x - m.x * v.y;
  }
  part[p][q * 2] = ar; part[p][q * 2 + 1] = ai;
  __syncthreads();
  if (tid < 64) {
    float sr = part[tid][0] + part[tid][2] + part[tid][4] + part[tid][6];
    float si = part[tid][1] + part[tid][3] + part[tid][5] + part[tid][7];
    PSD[((long)blockIdx.x * 64 + tid) * 2]     = sr * (1.f / 601.f);
    PSD[((long)blockIdx.x * 64 + tid) * 2 + 1] = si * (1.f / 601.f);
  }
}

// ---------------- 8x8 complex solve + MVDR weight ----------------
__launch_bounds__(64)
__global__ void k_solve(const float* __restrict__ PS, const float* __restrict__ PN,
                        float* __restrict__ WV) {
  int idx = blockIdx.x * 64 + threadIdx.x;
  if (idx >= NB * NF) return;
  float Ar[8][8], Ai[8][8], Br[8][8], Bi[8][8];
  const float* pn = PN + (long)idx * 128;
  const float* ps = PS + (long)idx * 128;
  for (int i = 0; i < 8; i++)
    for (int j = 0; j < 8; j++) {
      Ar[i][j] = pn[(i * 8 + j) * 2]; Ai[i][j] = pn[(i * 8 + j) * 2 + 1];
      Br[i][j] = ps[(i * 8 + j) * 2]; Bi[i][j] = ps[(i * 8 + j) * 2 + 1];
    }
  float tr = 0.f;
  for (int i = 0; i < 8; i++) tr += Ar[i][i];
  float load = 1e-6f * tr / 8.f + 1e-8f;
  for (int i = 0; i < 8; i++) Ar[i][i] += load;
  for (int k = 0; k < 8; k++) {
    int piv = k; float mx = Ar[k][k] * Ar[k][k] + Ai[k][k] * Ai[k][k];
    for (int i = k + 1; i < 8; i++) {
      float m2 = Ar[i][k] * Ar[i][k] + Ai[i][k] * Ai[i][k];
      if (m2 > mx) { mx = m2; piv = i; }
    }
    if (piv != k) {
      for (int j = 0; j < 8; j++) {
        float t0;
        t0 = Ar[k][j]; Ar[k][j] = Ar[piv][j]; Ar[piv][j] = t0;
        t0 = Ai[k][j]; Ai[k][j] = Ai[piv][j]; Ai[piv][j] = t0;
        t0 = Br[k][j]; Br[k][j] = Br[piv][j]; Br[piv][j] = t0;
        t0 = Bi[k][j]; Bi[k][j] = Bi[piv][j]; Bi[piv][j] = t0;
      }
    }
    float dr = Ar[k][k], di = Ai[k][k];
    float inv = 1.f / (dr * dr + di * di);
    float irr = dr * inv, iii = -di * inv;
    for (int j = 0; j < 8; j++) {
      float xr = Ar[k][j], xi = Ai[k][j];
      Ar[k][j] = xr * irr - xi * iii; Ai[k][j] = xr * iii + xi * irr;
      xr = Br[k][j]; xi = Bi[k][j];
      Br[k][j] = xr * irr - xi * iii; Bi[k][j] = xr * iii + xi * irr;
    }
    for (int i = 0; i < 8; i++) {
      if (i == k) continue;
      float fr = Ar[i][k], fi = Ai[i][k];
      for (int j = 0; j < 8; j++) {
        float kr = Ar[k][j], ki = Ai[k][j];
        Ar[i][j] -= fr * kr - fi * ki;
        Ai[i][j] -= fr * ki + fi * kr;
        kr = Br[k][j]; ki = Bi[k][j];
        Br[i][j] -= fr * kr - fi * ki;
        Bi[i][j] -= fr * ki + fi * kr;
      }
    }
  }
  float trr = 1e-8f, tri = 0.f;
  for (int i = 0; i < 8; i++) { trr += Br[i][i]; tri += Bi[i][i]; }
  float inv = 1.f / (trr * trr + tri * tri);
  for (int c = 0; c < 8; c++) {
    float xr = Br[c][0], xi = Bi[c][0];
    WV[((long)idx * 8 + c) * 2]     = (xr * trr + xi * tri) * inv;
    WV[((long)idx * 8 + c) * 2 + 1] = (xi * trr - xr * tri) * inv;
  }
}

// ---------------- beamform -> pre-split ENH (KPAD rows) ----------------
__launch_bounds__(320)
__global__ void k_beam(const float* __restrict__ S, const float* __restrict__ WV,
                       unsigned short* __restrict__ ENHh, unsigned short* __restrict__ ENHl) {
  __shared__ float WL[NF * 16];
  int bb = blockIdx.x / TT, t = blockIdx.x - bb * TT;
  for (int i = threadIdx.x; i < NF * 16; i += 320) WL[i] = WV[(long)bb * NF * 16 + i];
  __syncthreads();
  int f = threadIdx.x;
  long base = ((long)bb * TT + t) * KPAD;
  if (f < NF) {
    float er = 0.f, ei = 0.f;
#pragma unroll
    for (int c = 0; c < 8; c++) {
      float wr = WL[(f * 8 + c) * 2], wi = WL[(f * 8 + c) * 2 + 1];
      const float* srow = S + (((long)(bb * 8 + c) * TT) + t) * DD;
      float sr = srow[f], si = srow[NF + f];
      er += wr * sr + wi * si;
      ei += wr * si - wi * sr;
    }
    split_bf16(er, &ENHh[base + f], &ENHl[base + f]);
    split_bf16(ei, &ENHh[base + NF + f], &ENHl[base + NF + f]);
  }
  int z = threadIdx.x - 288;   // threads 288..317 zero the 30 K-pad cols
  if (z >= 0 && z < 30) { ENHh[base + DD + z] = 0; ENHl[base + DD + z] = 0; }
}

// ---------------- overlap-add + normalize + crop ----------------
__global__ void k_ola(const float* __restrict__ IFR, const float* __restrict__ WSQ,
                      float* __restrict__ out) {
  int idx = blockIdx.x * 256 + threadIdx.x;
  if (idx >= NB * LSEQ) return;
  int b = idx / LSEQ, l = idx - b * LSEQ;
  int p = l + FPAD;
  int t0 = (p <= 511) ? 0 : (p - 352) / 160;
  int t1 = p / 160; if (t1 > 600) t1 = 600;
  float s = 0.f;
  for (int t = t0; t <= t1; t++) s += IFR[((long)b * TT + t) * NFFT + (p - t * HOP)];
  out[idx] = s / fmaxf(WSQ[p], 1e-11f);
}

// ---------------- driver ----------------
extern "C" void kernel_launch(void* const* d_in, const int* in_sizes, int n_in,
                              void* d_out, int out_size, void* d_ws, size_t ws_size,
                              hipStream_t stream) {
  (void)in_sizes; (void)n_in; (void)out_size; (void)ws_size;
  const float* x   = (const float*)d_in[0];
  const float* Wih = (const float*)d_in[1];
  const float* Whh = (const float*)d_in[2];
  const float* bih = (const float*)d_in[3];
  const float* bhh = (const float*)d_in[4];
  const float* W1  = (const float*)d_in[5];
  const float* b1  = (const float*)d_in[6];
  const float* W2  = (const float*)d_in[7];
  const float* b2  = (const float*)d_in[8];
  float* ws = (float*)d_ws;

  // XP region: pre-split XPh/XPl (exactly fills old XP fp32 footprint); IFR aliases later.
  unsigned short* XPh = (unsigned short*)(ws + 0);            // 6,176,768 ush = 3,088,384 fl
  unsigned short* XPl = (unsigned short*)(ws + 3088384);      // -> region ends 6,176,768 fl
  float* S     = ws + 6176768;    // 19,774,496
  float* XWM   = ws + 25951264;   // 19,774,496 (XW then MS; WhhP4 in tail)
  float* HOUT  = ws + 45725760;   // 4,924,288 (pre-GEMM scratch + post-beam ENH split live here too)
  float* PSD_S = ws + 50650048;   // 263,168
  float* PSD_N = ws + 50913216;   // 263,168
  float* WV    = ws + 51176384;   // 32,896
  float* BSUM  = ws + 51209280;   // 512
  float* WSQ   = ws + 51209792;   // 96,512 -> 51,306,304
  unsigned short* W1sh = (unsigned short*)(ws + 51306304);
  unsigned short* W1sl = (unsigned short*)(ws + 51347264);
  unsigned short* W2sh = (unsigned short*)(ws + 51388224);
  unsigned short* W2sl = (unsigned short*)(ws + 51429184); // -> 51,470,144
  unsigned short* WTth = (unsigned short*)(ws + 51470144); // 139,264 fl
  unsigned short* WTtl = (unsigned short*)(ws + 51609408); // -> 51,748,672
  unsigned short* BIth = (unsigned short*)(ws + 51748672); // 139,264 fl
  unsigned short* BItl = (unsigned short*)(ws + 51887936); // -> end 52,027,200 (~208 MB)
  float* MS    = XWM;
  float* IFR   = ws + 0;          // aliases XP region after gemm4
  unsigned int* WhhP4 = (unsigned int*)(XWM + 19693568);   // after true end of XW
  // Pre-GEMM scratch inside HOUT (dead until k_lstm):
  float* BFf = HOUT;                                        // 263,168 fl
  float* BWf = HOUT + 263168;                               // 262,144 fl
  unsigned short* BCh = (unsigned short*)(HOUT + 525312);   // 1152*544 ush = 313,344 fl
  unsigned short* BCl = (unsigned short*)(HOUT + 838656);   // -> 1,152,000 fl < 4,924,288
  // Post-beam ENH split in HOUT (Hout consumed by maskms before k_beam):
  unsigned short* ENHh = (unsigned short*)HOUT;             // 4808*544 ush = 1,307,776 fl
  unsigned short* ENHl = (unsigned short*)(HOUT + 1307776);

  // fused init: xp + wsq + bff + wtsplit + bisplit + bsum + wmsplit + wpack
  k_init<<<NINIT, 256, 0, stream>>>(x, Wih, Whh, bih, bhh, W1, W2,
                                    XPh, XPl, WSQ, BFf, WTth, WTtl, BIth, BItl,
                                    BSUM, W1sh, W1sl, W2sh, W2sl, WhhP4);

  // BW = BF @ Wih^T  (512x512, K=514) — small gemm3
  {
    dim3 g(4, 4);
    k_gemm3<0><<<g, 256, 0, stream>>>(BFf, WTth, WTtl, nullptr, BWf, 512, 512, DD, DD, G4);
  }
  // combined split B = [BF | BW]
  k_bcomb<<<(1152 * KPAD + 255) / 256, 256, 0, stream>>>(BWf, BCh, BCl);

  // fused STFT + xW: S[38464,514] and XW[38464,512] in one gather-GEMM (XCD-swizzled)
  k_gemm4<<<9 * 301, 256, 0, stream>>>(XPh, XPl, BCh, BCl, BSUM, S, XWM);

  k_lstm<<<64, 512, 0, stream>>>(XWM, WhhP4, HOUT);

  k_maskms<<<9 * 601, 256, 0, stream>>>(HOUT, W1sh, W1sl, b1, S, MS);
  k_psd<<<NB * NF, 256, 0, stream>>>(MS, PSD_S);
  k_maskms<<<9 * 601, 256, 0, stream>>>(HOUT, W2sh, W2sl, b2, S, MS);
  k_psd<<<NB * NF, 256, 0, stream>>>(MS, PSD_N);

  k_solve<<<(NB * NF + 63) / 64, 64, 0, stream>>>(PSD_S, PSD_N, WV);
  k_beam<<<NB * TT, 320, 0, stream>>>(S, WV, ENHh, ENHl);

  // iSTFT: IFR[4808,512] = ENH @ BI (pre-split A)
  {
    dim3 g(4, 38);
    k_gemm5<<<g, 256, 0, stream>>>(ENHh, ENHl, BIth, BItl, IFR, NB * TT, NFFT, NFFT);
  }

  k_ola<<<(NB * LSEQ + 255) / 256, 256, 0, stream>>>(IFR, WSQ, (float*)d_out);
}

// Round 11
// 1020.533 us; speedup vs baseline: 1.5130x; 1.0657x over previous
//
#include <hip/hip_runtime.h>
#include <math.h>

#define NFFT  512
#define WINL  320
#define HOP   160
#define FPAD  256
#define NF    257
#define TT    601
#define LSEQ  96000
#define XPLEN 96512
#define NCH   8
#define NB    8
#define NSEQ  64
#define NROWS 38464   // NSEQ*TT
#define DD    514
#define HH    128
#define G4    512
#define KPAD  544     // 17*32, zero-padded K for split-B arrays
#define NCOMB 1026    // 514 (S cols) + 512 (XW cols)

// fused-init block ranges (all exact multiples of 256 threads)
#define NXP   24128   // NSEQ*XPLEN/256
#define NWSQ  377     // XPLEN/256
#define NBFF  1028    // NFFT*DD/256
#define NWT   1088    // G4*KPAD/256
#define NBI   1088    // NFFT*KPAD/256
#define NBS   2       // G4/256
#define NWM   640     // 2*640*HH/256
#define NWP   128     // G4*64/256
#define NINIT (NXP + NWSQ + NBFF + NWT + NBI + NBS + NWM + NWP)   // 28479

typedef _Float16 h2v __attribute__((ext_vector_type(2)));
typedef short bf16x8 __attribute__((ext_vector_type(8)));
typedef float f32x4 __attribute__((ext_vector_type(4)));

// ---------------- init helpers ----------------
__device__ __forceinline__ float winval(int k) {
  if (k < 96 || k >= 416) return 0.f;
  return 0.5f - 0.5f * cosf((float)(2.0 * M_PI / 320.0) * (float)(k - 96));
}

__device__ __forceinline__ void split_bf16(float v, unsigned short* h, unsigned short* l) {
  unsigned int hb = __float_as_uint(v) >> 16;
  float r = v - __uint_as_float(hb << 16);
  *h = (unsigned short)hb;
  *l = (unsigned short)(__float_as_uint(r) >> 16);
}

// async global->LDS, 16B per lane; dest is wave-uniform base + lane*16
__device__ __forceinline__ void glds16(const unsigned short* g, unsigned short* l) {
  __builtin_amdgcn_global_load_lds(
      (const __attribute__((address_space(1))) void*)g,
      (__attribute__((address_space(3))) void*)l,
      16, 0, 0);
}

// bijective XCD-chunk swizzle (m204 variant; works for nwg%8 != 0)
__device__ __forceinline__ int xcd_swz(int orig, int nwg) {
  int q = nwg >> 3, r = nwg & 7;
  int xcd = orig & 7, slot = orig >> 3;
  return (xcd < r ? xcd * (q + 1) : r * (q + 1) + (xcd - r) * q) + slot;
}

// ---------------- fused init: 8 independent prep kernels in one launch ----------------
__global__ void k_init(const float* __restrict__ x, const float* __restrict__ Wih,
                       const float* __restrict__ Whh, const float* __restrict__ bih,
                       const float* __restrict__ bhh, const float* __restrict__ W1,
                       const float* __restrict__ W2,
                       unsigned short* __restrict__ XPh, unsigned short* __restrict__ XPl,
                       float* __restrict__ wsq, float* __restrict__ BFf,
                       unsigned short* __restrict__ WTh, unsigned short* __restrict__ WTl,
                       unsigned short* __restrict__ BIh, unsigned short* __restrict__ BIl,
                       float* __restrict__ BSUM,
                       unsigned short* __restrict__ W1h, unsigned short* __restrict__ W1l,
                       unsigned short* __restrict__ W2h, unsigned short* __restrict__ W2l,
                       unsigned int* __restrict__ WhhP4) {
  int b = blockIdx.x;
  const int tid = threadIdx.x;

  if (b < NXP) {                       // ---- k_xp ----
    int idx = b * 256 + tid;
    if (idx < NSEQ * XPLEN) {
      int n = idx / XPLEN, i = idx - n * XPLEN;
      int j = i - FPAD;
      if (j < 0) j = -j;
      else if (j >= LSEQ) j = 2 * LSEQ - 2 - j;
      int bb = n >> 3, c = n & 7;
      float v = x[((long)bb * LSEQ + j) * NCH + c];
      split_bf16(v, &XPh[idx], &XPl[idx]);
    }
    return;
  }
  b -= NXP;

  if (b < NWSQ) {                      // ---- k_wsq ----
    int p = b * 256 + tid;
    if (p < XPLEN) {
      int t0 = (p <= 511) ? 0 : (p - 352) / 160;
      int t1 = p / 160; if (t1 > 600) t1 = 600;
      float s = 0.f;
      for (int t = t0; t <= t1; t++) { float w = winval(p - t * HOP); s += w * w; }
      wsq[p] = s;
    }
    return;
  }
  b -= NWSQ;

  if (b < NBFF) {                      // ---- k_bff ----
    int idx = b * 256 + tid;
    if (idx < NFFT * DD) {
      int k = idx / DD, d = idx - k * DD;
      float w = winval(k);
      int f = (d < NF) ? d : d - NF;
      int m = (k * f) & 511;
      float th = (float)(M_PI / 256.0) * (float)m;
      BFf[idx] = ((d < NF) ? cosf(th) : -sinf(th)) * w;
    }
    return;
  }
  b -= NBFF;

  if (b < NWT) {                       // ---- k_wtsplit ----
    int idx = b * 256 + tid;
    if (idx < G4 * KPAD) {
      int n = idx / KPAD, k = idx - n * KPAD;
      float v = (k < DD) ? Wih[n * DD + k] : 0.f;
      split_bf16(v, &WTh[idx], &WTl[idx]);
    }
    return;
  }
  b -= NWT;

  if (b < NBI) {                       // ---- k_bisplit ----
    int idx = b * 256 + tid;
    if (idx < NFFT * KPAD) {
      int n = idx / KPAD, kk = idx - n * KPAD;
      float v = 0.f;
      if (kk < DD) {
        float w = winval(n);
        int f = (kk < NF) ? kk : kk - NF;
        int edge = (f == 0 || f == 256);
        float alpha = edge ? 1.f : 2.f;
        int m = (n * f) & 511;
        float th = (float)(M_PI / 256.0) * (float)m;
        float c;
        if (kk < NF) c = alpha * cosf(th);
        else         c = edge ? 0.f : -alpha * sinf(th);
        v = c * w * (1.f / 512.f);
      }
      split_bf16(v, &BIh[idx], &BIl[idx]);
    }
    return;
  }
  b -= NBI;

  if (b < NBS) {                       // ---- k_bsum ----
    int idx = b * 256 + tid;
    if (idx < G4) BSUM[idx] = bih[idx] + bhh[idx];
    return;
  }
  b -= NBS;

  if (b < NWM) {                       // ---- k_wmsplit ----
    int idx = b * 256 + tid;
    if (idx < 2 * 640 * HH) {
      int m = idx / (640 * HH);
      int rem = idx - m * 640 * HH;
      int np = rem / HH, k = rem - np * HH;
      int ri = np / 320, f = np - ri * 320;
      float v = 0.f;
      if (f < NF) {
        int fcol = (ri == 0) ? f : NF + f;
        v = (m == 0) ? W1[fcol * HH + k] : W2[fcol * HH + k];
      }
      unsigned short h, l;
      split_bf16(v, &h, &l);
      if (m == 0) { W1h[rem] = h; W1l[rem] = l; }
      else        { W2h[rem] = h; W2l[rem] = l; }
    }
    return;
  }
  b -= NWM;

  {                                    // ---- k_wpack ----
    int idx = b * 256 + tid;
    if (idx < G4 * 64) {
      int j = idx >> 6, k2 = idx & 63;
      _Float16 lo = (_Float16)Whh[j * HH + 2 * k2];
      _Float16 hi = (_Float16)Whh[j * HH + 2 * k2 + 1];
      unsigned int u = ((unsigned int)__builtin_bit_cast(unsigned short, hi) << 16)
                     |  (unsigned int)__builtin_bit_cast(unsigned short, lo);
      WhhP4[(k2 >> 2) * (G4 * 4) + j * 4 + (k2 & 3)] = u;
    }
  }
}

// Combined split B for the fused STFT+xW GEMM: BC[n][k], n in [0,1152).
// Rows 0-511 (pure DFT, no BWf dependence) are ALSO written to BFsh/BFsl,
// which live in the PSD regions - dead until k_psd. The fused k_lstm_s reads
// those instead of BC, because BC's home (HOUT scratch) is overwritten by the
// LSTM's Hout stores while the fused gemm runs (the v18 race).
__global__ void k_bcomb(const float* __restrict__ BWf, unsigned short* __restrict__ H,
                        unsigned short* __restrict__ L,
                        unsigned short* __restrict__ BFsh, unsigned short* __restrict__ BFsl) {
  int idx = blockIdx.x * 256 + threadIdx.x;
  if (idx >= 1152 * KPAD) return;
  int n = idx / KPAD, k = idx - n * KPAD;
  float v = 0.f;
  if (k < NFFT) {
    if (n < DD) {
      float w = winval(k);
      int f = (n < NF) ? n : n - NF;
      int m = (k * f) & 511;
      float th = (float)(M_PI / 256.0) * (float)m;
      v = ((n < NF) ? cosf(th) : -sinf(th)) * w;
    } else if (n < NCOMB) {
      v = BWf[k * G4 + (n - 514)];
    }
  }
  unsigned short h, l;
  split_bf16(v, &h, &l);
  H[idx] = h; L[idx] = l;
  if (n < 512) { BFsh[idx] = h; BFsl[idx] = l; }   // idx = n*KPAD+k, same layout
}

// ---------------- split-bf16 MFMA GEMM (fp32 A): C[M,N] = A[M,K] * Bt^T (+bias) ----------------
template <int GATHER>
__launch_bounds__(256)
__global__ void k_gemm3(const float* __restrict__ A,
                        const unsigned short* __restrict__ Bth,
                        const unsigned short* __restrict__ Btl,
                        const float* __restrict__ bias, float* __restrict__ C,
                        int M, int N, int K, int lda, int ldc) {
  __shared__ __align__(16) unsigned short sAh[128 * 40];
  __shared__ __align__(16) unsigned short sAl[128 * 40];
  __shared__ __align__(16) unsigned short sBh[128 * 40];
  __shared__ __align__(16) unsigned short sBl[128 * 40];
  const int tid = threadIdx.x;
  const int row0 = blockIdx.y * 128, col0 = blockIdx.x * 128;
  const int sar = tid >> 1, sak = (tid & 1) * 16;
  const int arow = row0 + sar;
  long abase = (long)arow * lda;
  const bool arok = (arow < M);
  const int lane = tid & 63, w = tid >> 6;
  const int wm = (w >> 1) * 64, wn = (w & 1) * 64;
  const int l15 = lane & 15, quad = lane >> 4;
  f32x4 acc[4][4] = {};
  unsigned int* aH = (unsigned int*)sAh;
  unsigned int* aL = (unsigned int*)sAl;
  uint4* bH = (uint4*)sBh;
  uint4* bL = (uint4*)sBl;
  for (int k0 = 0; k0 < K; k0 += 32) {
#pragma unroll
    for (int i = 0; i < 8; i++) {
      int kk = k0 + sak + 2 * i;
      float v0 = 0.f, v1 = 0.f;
      if (arok) {
        if (kk + 1 < K) { float2 t2 = *(const float2*)(A + abase + kk); v0 = t2.x; v1 = t2.y; }
        else if (kk < K) { v0 = A[abase + kk]; }
      }
      unsigned int h0 = __float_as_uint(v0) >> 16, h1 = __float_as_uint(v1) >> 16;
      float r0 = v0 - __uint_as_float(h0 << 16), r1 = v1 - __uint_as_float(h1 << 16);
      unsigned int l0 = __float_as_uint(r0) >> 16, l1 = __float_as_uint(r1) >> 16;
      aH[sar * 20 + (sak >> 1) + i] = h0 | (h1 << 16);
      aL[sar * 20 + (sak >> 1) + i] = l0 | (l1 << 16);
    }
#pragma unroll
    for (int h = 0; h < 2; h++) {
      int idx = tid + h * 256;
      int r = idx >> 2, c = idx & 3;
      long go = (long)(col0 + r) * KPAD + k0 + c * 8;
      bH[r * 5 + c] = *(const uint4*)(Bth + go);
      bL[r * 5 + c] = *(const uint4*)(Btl + go);
    }
    __syncthreads();
    bf16x8 ah[4], al[4], bh[4], bl[4];
#pragma unroll
    for (int i = 0; i < 4; i++) {
      int off = (wm + i * 16 + l15) * 40 + quad * 8;
      ah[i] = *(const bf16x8*)(sAh + off);
      al[i] = *(const bf16x8*)(sAl + off);
      int boff = (wn + i * 16 + l15) * 40 + quad * 8;
      bh[i] = *(const bf16x8*)(sBh + boff);
      bl[i] = *(const bf16x8*)(sBl + boff);
    }
#pragma unroll
    for (int i = 0; i < 4; i++)
#pragma unroll
      for (int j = 0; j < 4; j++) {
        acc[i][j] = __builtin_amdgcn_mfma_f32_16x16x32_bf16(al[i], bh[j], acc[i][j], 0, 0, 0);
        acc[i][j] = __builtin_amdgcn_mfma_f32_16x16x32_bf16(ah[i], bl[j], acc[i][j], 0, 0, 0);
        acc[i][j] = __builtin_amdgcn_mfma_f32_16x16x32_bf16(ah[i], bh[j], acc[i][j], 0, 0, 0);
      }
    __syncthreads();
  }
#pragma unroll
  for (int i = 0; i < 4; i++)
#pragma unroll
    for (int j = 0; j < 4; j++) {
      int cc = col0 + wn + j * 16 + l15;
      if (cc >= N) continue;
      float bv = bias ? bias[cc] : 0.f;
#pragma unroll
      for (int rg = 0; rg < 4; rg++) {
        int rr = row0 + wm + i * 16 + quad * 4 + rg;
        if (rr < M) C[(long)rr * ldc + cc] = acc[i][j][rg] + bv;
      }
    }
}

// ---------------- fused STFT+xW GEMM (partial cols): gload_lds staging + XCD swizzle ----------------
// Covers col tiles [colBase, colBase+nCT): used pre-lstm for tiles 4-8 (XW + S
// cols 512-513). Tiles 0-3 (pure S) run inside k_lstm_s under the LSTM's shadow.
__launch_bounds__(256)
__global__ void k_gemm4(const unsigned short* __restrict__ Ah, const unsigned short* __restrict__ Al,
                        const unsigned short* __restrict__ Bh, const unsigned short* __restrict__ Bl,
                        const float* __restrict__ bsum, float* __restrict__ S,
                        float* __restrict__ XW, int colBase, int nCT) {
  __shared__ __align__(16) unsigned short sAh[128 * 32];
  __shared__ __align__(16) unsigned short sAl[128 * 32];
  __shared__ __align__(16) unsigned short sBh[128 * 32];
  __shared__ __align__(16) unsigned short sBl[128 * 32];
  const int tid = threadIdx.x;
  const int wg = xcd_swz(blockIdx.x, nCT * 301);
  const int row0 = (wg / nCT) * 128, col0 = (colBase + wg % nCT) * 128;
  const int lane = tid & 63, w = tid >> 6;
  const int wm = (w >> 1) * 64, wn = (w & 1) * 64;
  const int l15 = lane & 15, quad = lane >> 4;
  const int sr0 = w * 32 + (lane >> 2);
  const int sr1 = sr0 + 16;
  const int c8 = (lane & 3) * 8;
  long ab0, ab1;
  { int rr = row0 + sr0; int n = rr / TT, t = rr - n * TT; ab0 = (long)n * XPLEN + (long)t * HOP + c8; }
  { int rr = row0 + sr1; int n = rr / TT, t = rr - n * TT; ab1 = (long)n * XPLEN + (long)t * HOP + c8; }
  const long bb0 = (long)(col0 + sr0) * KPAD + c8;
  const long bb1 = (long)(col0 + sr1) * KPAD + c8;
  const int d0 = w * 1024;
  const int d1 = d0 + 512;
  f32x4 acc[4][4] = {};
  for (int k0 = 0; k0 < NFFT; k0 += 32) {
    glds16(Ah + ab0 + k0, sAh + d0);
    glds16(Ah + ab1 + k0, sAh + d1);
    glds16(Al + ab0 + k0, sAl + d0);
    glds16(Al + ab1 + k0, sAl + d1);
    glds16(Bh + bb0 + k0, sBh + d0);
    glds16(Bh + bb1 + k0, sBh + d1);
    glds16(Bl + bb0 + k0, sBl + d0);
    glds16(Bl + bb1 + k0, sBl + d1);
    __syncthreads();
    bf16x8 ah[4], al[4], bh[4], bl[4];
#pragma unroll
    for (int i = 0; i < 4; i++) {
      int off = (wm + i * 16 + l15) * 32 + quad * 8;
      ah[i] = *(const bf16x8*)(sAh + off);
      al[i] = *(const bf16x8*)(sAl + off);
      int boff = (wn + i * 16 + l15) * 32 + quad * 8;
      bh[i] = *(const bf16x8*)(sBh + boff);
      bl[i] = *(const bf16x8*)(sBl + boff);
    }
#pragma unroll
    for (int i = 0; i < 4; i++)
#pragma unroll
      for (int j = 0; j < 4; j++) {
        acc[i][j] = __builtin_amdgcn_mfma_f32_16x16x32_bf16(al[i], bh[j], acc[i][j], 0, 0, 0);
        acc[i][j] = __builtin_amdgcn_mfma_f32_16x16x32_bf16(ah[i], bl[j], acc[i][j], 0, 0, 0);
        acc[i][j] = __builtin_amdgcn_mfma_f32_16x16x32_bf16(ah[i], bh[j], acc[i][j], 0, 0, 0);
      }
    __syncthreads();
  }
#pragma unroll
  for (int i = 0; i < 4; i++)
#pragma unroll
    for (int j = 0; j < 4; j++) {
      int cc = col0 + wn + j * 16 + l15;
      if (cc >= NCOMB) continue;
#pragma unroll
      for (int rg = 0; rg < 4; rg++) {
        int rr = row0 + wm + i * 16 + quad * 4 + rg;
        if (rr >= NROWS) continue;
        float v = acc[i][j][rg];
        if (cc < DD) S[(long)rr * DD + cc] = v;
        else         XW[(long)rr * G4 + (cc - 514)] = v + bsum[cc - 514];
      }
    }
}

// ---------------- iSTFT GEMM: pre-split A (pitch KPAD), B = BI split ----------------
__launch_bounds__(256)
__global__ void k_gemm5(const unsigned short* __restrict__ Ah, const unsigned short* __restrict__ Al,
                        const unsigned short* __restrict__ Bh, const unsigned short* __restrict__ Bl,
                        float* __restrict__ C, int M, int N, int ldc) {
  __shared__ __align__(16) unsigned short sAh[128 * 40];
  __shared__ __align__(16) unsigned short sAl[128 * 40];
  __shared__ __align__(16) unsigned short sBh[128 * 40];
  __shared__ __align__(16) unsigned short sBl[128 * 40];
  const int tid = threadIdx.x;
  const int row0 = blockIdx.y * 128, col0 = blockIdx.x * 128;
  const int sr0 = tid >> 2, c4 = (tid & 3) * 8, cq = tid & 3;
  const int lane = tid & 63, w = tid >> 6;
  const int wm = (w >> 1) * 64, wn = (w & 1) * 64;
  const int l15 = lane & 15, quad = lane >> 4;
  f32x4 acc[4][4] = {};
  uint4* aH4 = (uint4*)sAh; uint4* aL4 = (uint4*)sAl;
  uint4* bH4 = (uint4*)sBh; uint4* bL4 = (uint4*)sBl;
  for (int k0 = 0; k0 < KPAD; k0 += 32) {
    {
      long go = (long)(row0 + sr0) * KPAD + k0 + c4;
      aH4[sr0 * 5 + cq] = *(const uint4*)(Ah + go);
      aL4[sr0 * 5 + cq] = *(const uint4*)(Al + go);
      go = (long)(row0 + sr0 + 64) * KPAD + k0 + c4;
      aH4[(sr0 + 64) * 5 + cq] = *(const uint4*)(Ah + go);
      aL4[(sr0 + 64) * 5 + cq] = *(const uint4*)(Al + go);
    }
    {
      long go = (long)(col0 + sr0) * KPAD + k0 + c4;
      bH4[sr0 * 5 + cq] = *(const uint4*)(Bh + go);
      bL4[sr0 * 5 + cq] = *(const uint4*)(Bl + go);
      go = (long)(col0 + sr0 + 64) * KPAD + k0 + c4;
      bH4[(sr0 + 64) * 5 + cq] = *(const uint4*)(Bh + go);
      bL4[(sr0 + 64) * 5 + cq] = *(const uint4*)(Bl + go);
    }
    __syncthreads();
    bf16x8 ah[4], al[4], bh[4], bl[4];
#pragma unroll
    for (int i = 0; i < 4; i++) {
      int off = (wm + i * 16 + l15) * 40 + quad * 8;
      ah[i] = *(const bf16x8*)(sAh + off);
      al[i] = *(const bf16x8*)(sAl + off);
      int boff = (wn + i * 16 + l15) * 40 + quad * 8;
      bh[i] = *(const bf16x8*)(sBh + boff);
      bl[i] = *(const bf16x8*)(sBl + boff);
    }
#pragma unroll
    for (int i = 0; i < 4; i++)
#pragma unroll
      for (int j = 0; j < 4; j++) {
        acc[i][j] = __builtin_amdgcn_mfma_f32_16x16x32_bf16(al[i], bh[j], acc[i][j], 0, 0, 0);
        acc[i][j] = __builtin_amdgcn_mfma_f32_16x16x32_bf16(ah[i], bl[j], acc[i][j], 0, 0, 0);
        acc[i][j] = __builtin_amdgcn_mfma_f32_16x16x32_bf16(ah[i], bh[j], acc[i][j], 0, 0, 0);
      }
    __syncthreads();
  }
#pragma unroll
  for (int i = 0; i < 4; i++)
#pragma unroll
    for (int j = 0; j < 4; j++) {
      int cc = col0 + wn + j * 16 + l15;
      if (cc >= N) continue;
#pragma unroll
      for (int rg = 0; rg < 4; rg++) {
        int rr = row0 + wm + i * 16 + quad * 4 + rg;
        if (rr < M) C[(long)rr * ldc + cc] = acc[i][j][rg];
      }
    }
}

// ---------------- fused LSTM + S-GEMM: fill the LSTM's idle CUs ----------------
// Blocks 0-63: the v11 LSTM (382us local optimum), setprio(1)-wrapped (T5).
// Blocks 64+: gemm4 col tiles 0-3 (cols 0-511, pure S). B is read from
// BFsh/BFsl (PSD regions) - NOT from the HOUT-resident BC, which the LSTM's
// Hout stores overwrite concurrently (the v18 NaN race).
__device__ __forceinline__ float tanh_fast(float x) {
  float e = __expf(2.f * x);
  return 1.f - 2.f / (e + 1.f);
}

__launch_bounds__(512)
__global__ void k_lstm_s(const float* __restrict__ XW, const unsigned int* __restrict__ WhhP4,
                         float* __restrict__ Hout,
                         const unsigned short* __restrict__ Ah, const unsigned short* __restrict__ Al,
                         const unsigned short* __restrict__ Bh, const unsigned short* __restrict__ Bl,
                         float* __restrict__ S) {
  __shared__ __align__(16) unsigned short sAh[128 * 32];
  __shared__ __align__(16) unsigned short sAl[128 * 32];
  __shared__ __align__(16) unsigned short sBh[128 * 32];
  __shared__ __align__(16) unsigned short sBl[128 * 32];
  __shared__ __align__(16) unsigned int hl2[64];
  __shared__ float gl[G4];
  const int tid = threadIdx.x;

  if (blockIdx.x < 64) {
    // ---------------- LSTM path (verbatim v11) ----------------
    __builtin_amdgcn_s_setprio(1);
    const int j = tid;
    const int n = blockIdx.x;
    const uint4* W4 = (const uint4*)WhhP4;
    unsigned int wp[64];
#pragma unroll
    for (int i4 = 0; i4 < 16; i4++) {
      uint4 v = W4[i4 * G4 + j];
      wp[4 * i4]     = v.x;
      wp[4 * i4 + 1] = v.y;
      wp[4 * i4 + 2] = v.z;
      wp[4 * i4 + 3] = v.w;
    }
    float cst = 0.f;
    if (j < 64) hl2[j] = 0u;
    const float* xwrow = XW + (long)n * TT * G4 + j;
    float xnext = xwrow[0];
    const uint4* h4 = (const uint4*)hl2;
    const bool isg = (j >= 2 * HH) && (j < 3 * HH);
    __syncthreads();
    for (int t = 0; t < TT; t++) {
      float xv = xnext;
      if (t + 1 < TT) xnext = xwrow[(long)(t + 1) * G4];
      float a0 = 0.f, a1 = 0.f, a2 = 0.f, a3 = 0.f;
#pragma unroll
      for (int k = 0; k < 16; k++) {
        uint4 hv4 = h4[k];   // uniform address -> LDS broadcast, conflict-free
        a0 = __builtin_amdgcn_fdot2(__builtin_bit_cast(h2v, hv4.x), __builtin_bit_cast(h2v, wp[4 * k]),     a0, false);
        a1 = __builtin_amdgcn_fdot2(__builtin_bit_cast(h2v, hv4.y), __builtin_bit_cast(h2v, wp[4 * k + 1]), a1, false);
        a2 = __builtin_amdgcn_fdot2(__builtin_bit_cast(h2v, hv4.z), __builtin_bit_cast(h2v, wp[4 * k + 2]), a2, false);
        a3 = __builtin_amdgcn_fdot2(__builtin_bit_cast(h2v, hv4.w), __builtin_bit_cast(h2v, wp[4 * k + 3]), a3, false);
      }
      float a = ((a0 + a1) + (a2 + a3)) + xv;
      float nl;
      if (isg) nl = tanh_fast(a);
      else     nl = 1.f / (1.f + __expf(-a));
      gl[j] = nl;
      asm volatile("s_waitcnt lgkmcnt(0)" ::: "memory");
      __builtin_amdgcn_s_barrier();
      if (j < HH) {
        float ni = gl[j], nf = gl[HH + j], ng = gl[2 * HH + j], no = gl[3 * HH + j];
        cst = nf * cst + ni * ng;
        float hv = no * tanh_fast(cst);
        ((_Float16*)hl2)[j] = (_Float16)hv;
        Hout[((long)n * TT + t) * HH + j] = hv;
      }
      asm volatile("s_waitcnt lgkmcnt(0)" ::: "memory");
      __builtin_amdgcn_s_barrier();
    }
    __builtin_amdgcn_s_setprio(0);
    return;
  }

  // ---------------- S-GEMM path: gemm4 col tiles 0-3 ----------------
  const int wg = xcd_swz(blockIdx.x - 64, 4 * 301);
  const int row0 = (wg >> 2) * 128, col0 = (wg & 3) * 128;
  const int lane = tid & 63, w = tid >> 6;
  const int wm = (w >> 1) * 64, wn = (w & 1) * 64;
  const int l15 = lane & 15, quad = lane >> 4;
  const int sr0 = w * 32 + (lane >> 2);
  const int sr1 = sr0 + 16;
  const int c8 = (lane & 3) * 8;
  long ab0 = 0, ab1 = 0, bb0 = 0, bb1 = 0;
  int d0 = 0, d1 = 0;
  if (tid < 256) {
    { int rr = row0 + sr0; int n = rr / TT, t = rr - n * TT; ab0 = (long)n * XPLEN + (long)t * HOP + c8; }
    { int rr = row0 + sr1; int n = rr / TT, t = rr - n * TT; ab1 = (long)n * XPLEN + (long)t * HOP + c8; }
    bb0 = (long)(col0 + sr0) * KPAD + c8;
    bb1 = (long)(col0 + sr1) * KPAD + c8;
    d0 = w * 1024;
    d1 = d0 + 512;
  }
  f32x4 acc[4][4] = {};
  for (int k0 = 0; k0 < NFFT; k0 += 32) {
    if (tid < 256) {
      glds16(Ah + ab0 + k0, sAh + d0);
      glds16(Ah + ab1 + k0, sAh + d1);
      glds16(Al + ab0 + k0, sAl + d0);
      glds16(Al + ab1 + k0, sAl + d1);
      glds16(Bh + bb0 + k0, sBh + d0);
      glds16(Bh + bb1 + k0, sBh + d1);
      glds16(Bl + bb0 + k0, sBl + d0);
      glds16(Bl + bb1 + k0, sBl + d1);
    }
    __syncthreads();
    if (tid < 256) {
      bf16x8 ah[4], al[4], bh[4], bl[4];
#pragma unroll
      for (int i = 0; i < 4; i++) {
        int off = (wm + i * 16 + l15) * 32 + quad * 8;
        ah[i] = *(const bf16x8*)(sAh + off);
        al[i] = *(const bf16x8*)(sAl + off);
        int boff = (wn + i * 16 + l15) * 32 + quad * 8;
        bh[i] = *(const bf16x8*)(sBh + boff);
        bl[i] = *(const bf16x8*)(sBl + boff);
      }
#pragma unroll
      for (int i = 0; i < 4; i++)
#pragma unroll
        for (int j = 0; j < 4; j++) {
          acc[i][j] = __builtin_amdgcn_mfma_f32_16x16x32_bf16(al[i], bh[j], acc[i][j], 0, 0, 0);
          acc[i][j] = __builtin_amdgcn_mfma_f32_16x16x32_bf16(ah[i], bl[j], acc[i][j], 0, 0, 0);
          acc[i][j] = __builtin_amdgcn_mfma_f32_16x16x32_bf16(ah[i], bh[j], acc[i][j], 0, 0, 0);
        }
    }
    __syncthreads();
  }
  if (tid < 256) {
#pragma unroll
    for (int i = 0; i < 4; i++)
#pragma unroll
      for (int j = 0; j < 4; j++) {
        int cc = col0 + wn + j * 16 + l15;   // <= 511 < DD: pure S columns
#pragma unroll
        for (int rg = 0; rg < 4; rg++) {
          int rr = row0 + wm + i * 16 + quad * 4 + rg;
          if (rr < NROWS) S[(long)rr * DD + cc] = acc[i][j][rg];
        }
      }
  }
}

// ---------------- mask GEMM (split-bf16 MFMA) + mask apply + transpose ----------------
// MS layout: [b][f][c][t] complex-interleaved (re,im); XCD-chunk swizzled grid.
__launch_bounds__(256)
__global__ void k_maskms(const float* __restrict__ Hout,
                         const unsigned short* __restrict__ Wsh,
                         const unsigned short* __restrict__ Wsl,
                         const float* __restrict__ bias, const float* __restrict__ S,
                         float* __restrict__ MS) {
  __shared__ __align__(16) unsigned short sAh[64 * 40];
  __shared__ __align__(16) unsigned short sAl[64 * 40];
  __shared__ __align__(16) unsigned short sBh[64 * 40];
  __shared__ __align__(16) unsigned short sBl[64 * 40];
  __shared__ float Cs[64][68];
  __shared__ float SR[64][33];
  __shared__ float SI[64][33];
  const int tid = threadIdx.x;
  const int wg = xcd_swz(blockIdx.x, 9 * 601);
  const int f0 = (wg % 9) * 32;
  const int row0 = (wg / 9) * 64;
  const int lane = tid & 63, w = tid >> 6;
  const int wm = w * 16;
  const int l15 = lane & 15, quad = lane >> 4;
  const int sar = tid >> 2;
  const int sak = (tid & 3) * 8;
  const int np = ((sar < 32) ? 0 : 320 - 32) + f0 + sar;
  unsigned int* aH = (unsigned int*)sAh;
  unsigned int* aL = (unsigned int*)sAl;
  f32x4 acc[4] = {};
  for (int k0 = 0; k0 < HH; k0 += 32) {
    {
      const float* ap = Hout + (long)(row0 + sar) * HH + k0 + sak;
      float4 v0 = *(const float4*)ap;
      float4 v1 = *(const float4*)(ap + 4);
      float vv[8] = {v0.x, v0.y, v0.z, v0.w, v1.x, v1.y, v1.z, v1.w};
#pragma unroll
      for (int i = 0; i < 4; i++) {
        unsigned int h0 = __float_as_uint(vv[2 * i]) >> 16, h1 = __float_as_uint(vv[2 * i + 1]) >> 16;
        float r0 = vv[2 * i] - __uint_as_float(h0 << 16), r1 = vv[2 * i + 1] - __uint_as_float(h1 << 16);
        unsigned int l0 = __float_as_uint(r0) >> 16, l1 = __float_as_uint(r1) >> 16;
        aH[sar * 20 + (sak >> 1) + i] = h0 | (h1 << 16);
        aL[sar * 20 + (sak >> 1) + i] = l0 | (l1 << 16);
      }
    }
    {
      long go = (long)np * HH + k0 + sak;
      *(uint4*)(sBh + sar * 40 + sak) = *(const uint4*)(Wsh + go);
      *(uint4*)(sBl + sar * 40 + sak) = *(const uint4*)(Wsl + go);
    }
    __syncthreads();
    bf16x8 ah = *(const bf16x8*)(sAh + (wm + l15) * 40 + quad * 8);
    bf16x8 al = *(const bf16x8*)(sAl + (wm + l15) * 40 + quad * 8);
#pragma unroll
    for (int ct = 0; ct < 4; ct++) {
      bf16x8 bh = *(const bf16x8*)(sBh + (ct * 16 + l15) * 40 + quad * 8);
      bf16x8 bl = *(const bf16x8*)(sBl + (ct * 16 + l15) * 40 + quad * 8);
      acc[ct] = __builtin_amdgcn_mfma_f32_16x16x32_bf16(al, bh, acc[ct], 0, 0, 0);
      acc[ct] = __builtin_amdgcn_mfma_f32_16x16x32_bf16(ah, bl, acc[ct], 0, 0, 0);
      acc[ct] = __builtin_amdgcn_mfma_f32_16x16x32_bf16(ah, bh, acc[ct], 0, 0, 0);
    }
    __syncthreads();
  }
#pragma unroll
  for (int ct = 0; ct < 4; ct++) {
    int col = ct * 16 + l15;
    int f = f0 + (col & 31);
    int fcol = (col < 32) ? f : NF + f;
    float bv = (f < NF) ? bias[fcol] : 0.f;
#pragma unroll
    for (int rg = 0; rg < 4; rg++) Cs[wm + quad * 4 + rg][col] = acc[ct][rg] + bv;
  }
  __syncthreads();
  {
    int fl = tid & 31, r8 = tid >> 5;
    int f = f0 + fl;
#pragma unroll
    for (int i = 0; i < 8; i++) {
      int rl = r8 * 8 + i;
      int rr = row0 + rl;
      float rm = Cs[rl][fl], im = Cs[rl][32 + fl];
      float sr = 0.f, si = 0.f;
      if (f < NF) { sr = S[(long)rr * DD + f]; si = S[(long)rr * DD + NF + f]; }
      SR[rl][fl] = rm * sr - im * si;
      SI[rl][fl] = rm * si + im * sr;
    }
  }
  __syncthreads();
  {
    int tl = tid & 63, fq = tid >> 6;
    int rr = row0 + tl;
    int n = rr / TT, t = rr - n * TT;
    int b = n >> 3, c = n & 7;
#pragma unroll
    for (int i = 0; i < 8; i++) {
      int fl = fq * 8 + i;
      int f = f0 + fl;
      if (f < NF) {
        long addr = ((((long)b * NF + f) * 8 + c) * (long)TT + t) * 2;
        *(float2*)&MS[addr] = make_float2(SR[tl][fl], SI[tl][fl]);
      }
    }
  }
}

// ---------------- PSD: one block per (b,f); complex-interleaved MS ----------------
__launch_bounds__(256)
__global__ void k_psd(const float* __restrict__ MS, float* __restrict__ PSD) {
  __shared__ float buf[9616];
  __shared__ float part[64][8];
  const int tid = threadIdx.x;
  const long base = (long)blockIdx.x * 9616;
  for (int i = tid; i < 9616; i += 256) buf[i] = MS[base + i];
  __syncthreads();
  int p = tid & 63, q = tid >> 6;
  int c = p >> 3, e = p & 7;
  const float2* xc = (const float2*)&buf[c * 1202];
  const float2* xe = (const float2*)&buf[e * 1202];
  int t0 = q * 150, t1 = (q == 3) ? TT : t0 + 150;
  float ar = 0.f, ai = 0.f;
  for (int t = t0; t < t1; t++) {
    float2 m = xc[t];
    float2 v = xe[t];
    ar += m.x * v.x + m.y * v.y;
    ai += m.y * v.x - m.x * v.y;
  }
  part[p][q * 2] = ar; part[p][q * 2 + 1] = ai;
  __syncthreads();
  if (tid < 64) {
    float sr = part[tid][0] + part[tid][2] + part[tid][4] + part[tid][6];
    float si = part[tid][1] + part[tid][3] + part[tid][5] + part[tid][7];
    PSD[((long)blockIdx.x * 64 + tid) * 2]     = sr * (1.f / 601.f);
    PSD[((long)blockIdx.x * 64 + tid) * 2 + 1] = si * (1.f / 601.f);
  }
}

// ---------------- 8x8 complex solve + MVDR weight ----------------
__launch_bounds__(64)
__global__ void k_solve(const float* __restrict__ PS, const float* __restrict__ PN,
                        float* __restrict__ WV) {
  int idx = blockIdx.x * 64 + threadIdx.x;
  if (idx >= NB * NF) return;
  float Ar[8][8], Ai[8][8], Br[8][8], Bi[8][8];
  const float* pn = PN + (long)idx * 128;
  const float* ps = PS + (long)idx * 128;
  for (int i = 0; i < 8; i++)
    for (int j = 0; j < 8; j++) {
      Ar[i][j] = pn[(i * 8 + j) * 2]; Ai[i][j] = pn[(i * 8 + j) * 2 + 1];
      Br[i][j] = ps[(i * 8 + j) * 2]; Bi[i][j] = ps[(i * 8 + j) * 2 + 1];
    }
  float tr = 0.f;
  for (int i = 0; i < 8; i++) tr += Ar[i][i];
  float load = 1e-6f * tr / 8.f + 1e-8f;
  for (int i = 0; i < 8; i++) Ar[i][i] += load;
  for (int k = 0; k < 8; k++) {
    int piv = k; float mx = Ar[k][k] * Ar[k][k] + Ai[k][k] * Ai[k][k];
    for (int i = k + 1; i < 8; i++) {
      float m2 = Ar[i][k] * Ar[i][k] + Ai[i][k] * Ai[i][k];
      if (m2 > mx) { mx = m2; piv = i; }
    }
    if (piv != k) {
      for (int j = 0; j < 8; j++) {
        float t0;
        t0 = Ar[k][j]; Ar[k][j] = Ar[piv][j]; Ar[piv][j] = t0;
        t0 = Ai[k][j]; Ai[k][j] = Ai[piv][j]; Ai[piv][j] = t0;
        t0 = Br[k][j]; Br[k][j] = Br[piv][j]; Br[piv][j] = t0;
        t0 = Bi[k][j]; Bi[k][j] = Bi[piv][j]; Bi[piv][j] = t0;
      }
    }
    float dr = Ar[k][k], di = Ai[k][k];
    float inv = 1.f / (dr * dr + di * di);
    float irr = dr * inv, iii = -di * inv;
    for (int j = 0; j < 8; j++) {
      float xr = Ar[k][j], xi = Ai[k][j];
      Ar[k][j] = xr * irr - xi * iii; Ai[k][j] = xr * iii + xi * irr;
      xr = Br[k][j]; xi = Bi[k][j];
      Br[k][j] = xr * irr - xi * iii; Bi[k][j] = xr * iii + xi * irr;
    }
    for (int i = 0; i < 8; i++) {
      if (i == k) continue;
      float fr = Ar[i][k], fi = Ai[i][k];
      for (int j = 0; j < 8; j++) {
        float kr = Ar[k][j], ki = Ai[k][j];
        Ar[i][j] -= fr * kr - fi * ki;
        Ai[i][j] -= fr * ki + fi * kr;
        kr = Br[k][j]; ki = Bi[k][j];
        Br[i][j] -= fr * kr - fi * ki;
        Bi[i][j] -= fr * ki + fi * kr;
      }
    }
  }
  float trr = 1e-8f, tri = 0.f;
  for (int i = 0; i < 8; i++) { trr += Br[i][i]; tri += Bi[i][i]; }
  float inv = 1.f / (trr * trr + tri * tri);
  for (int c = 0; c < 8; c++) {
    float xr = Br[c][0], xi = Bi[c][0];
    WV[((long)idx * 8 + c) * 2]     = (xr * trr + xi * tri) * inv;
    WV[((long)idx * 8 + c) * 2 + 1] = (xi * trr - xr * tri) * inv;
  }
}

// ---------------- beamform -> pre-split ENH (KPAD rows) ----------------
__launch_bounds__(320)
__global__ void k_beam(const float* __restrict__ S, const float* __restrict__ WV,
                       unsigned short* __restrict__ ENHh, unsigned short* __restrict__ ENHl) {
  __shared__ float WL[NF * 16];
  int bb = blockIdx.x / TT, t = blockIdx.x - bb * TT;
  for (int i = threadIdx.x; i < NF * 16; i += 320) WL[i] = WV[(long)bb * NF * 16 + i];
  __syncthreads();
  int f = threadIdx.x;
  long base = ((long)bb * TT + t) * KPAD;
  if (f < NF) {
    float er = 0.f, ei = 0.f;
#pragma unroll
    for (int c = 0; c < 8; c++) {
      float wr = WL[(f * 8 + c) * 2], wi = WL[(f * 8 + c) * 2 + 1];
      const float* srow = S + (((long)(bb * 8 + c) * TT) + t) * DD;
      float sr = srow[f], si = srow[NF + f];
      er += wr * sr + wi * si;
      ei += wr * si - wi * sr;
    }
    split_bf16(er, &ENHh[base + f], &ENHl[base + f]);
    split_bf16(ei, &ENHh[base + NF + f], &ENHl[base + NF + f]);
  }
  int z = threadIdx.x - 288;   // threads 288..317 zero the 30 K-pad cols
  if (z >= 0 && z < 30) { ENHh[base + DD + z] = 0; ENHl[base + DD + z] = 0; }
}

// ---------------- overlap-add + normalize + crop ----------------
__global__ void k_ola(const float* __restrict__ IFR, const float* __restrict__ WSQ,
                      float* __restrict__ out) {
  int idx = blockIdx.x * 256 + threadIdx.x;
  if (idx >= NB * LSEQ) return;
  int b = idx / LSEQ, l = idx - b * LSEQ;
  int p = l + FPAD;
  int t0 = (p <= 511) ? 0 : (p - 352) / 160;
  int t1 = p / 160; if (t1 > 600) t1 = 600;
  float s = 0.f;
  for (int t = t0; t <= t1; t++) s += IFR[((long)b * TT + t) * NFFT + (p - t * HOP)];
  out[idx] = s / fmaxf(WSQ[p], 1e-11f);
}

// ---------------- driver ----------------
extern "C" void kernel_launch(void* const* d_in, const int* in_sizes, int n_in,
                              void* d_out, int out_size, void* d_ws, size_t ws_size,
                              hipStream_t stream) {
  (void)in_sizes; (void)n_in; (void)out_size; (void)ws_size;
  const float* x   = (const float*)d_in[0];
  const float* Wih = (const float*)d_in[1];
  const float* Whh = (const float*)d_in[2];
  const float* bih = (const float*)d_in[3];
  const float* bhh = (const float*)d_in[4];
  const float* W1  = (const float*)d_in[5];
  const float* b1  = (const float*)d_in[6];
  const float* W2  = (const float*)d_in[7];
  const float* b2  = (const float*)d_in[8];
  float* ws = (float*)d_ws;

  // XP region: pre-split XPh/XPl (exactly fills old XP fp32 footprint); IFR aliases later.
  unsigned short* XPh = (unsigned short*)(ws + 0);            // 6,176,768 ush = 3,088,384 fl
  unsigned short* XPl = (unsigned short*)(ws + 3088384);      // -> region ends 6,176,768 fl
  float* S     = ws + 6176768;    // 19,774,496
  float* XWM   = ws + 25951264;   // 19,774,496 (XW then MS; WhhP4 in tail)
  float* HOUT  = ws + 45725760;   // 4,924,288 (pre-GEMM scratch + post-beam ENH split live here too)
  float* PSD_S = ws + 50650048;   // 263,168
  float* PSD_N = ws + 50913216;   // 263,168
  float* WV    = ws + 51176384;   // 32,896
  float* BSUM  = ws + 51209280;   // 512
  float* WSQ   = ws + 51209792;   // 96,512 -> 51,306,304
  unsigned short* W1sh = (unsigned short*)(ws + 51306304);
  unsigned short* W1sl = (unsigned short*)(ws + 51347264);
  unsigned short* W2sh = (unsigned short*)(ws + 51388224);
  unsigned short* W2sl = (unsigned short*)(ws + 51429184); // -> 51,470,144
  unsigned short* WTth = (unsigned short*)(ws + 51470144); // 139,264 fl
  unsigned short* WTtl = (unsigned short*)(ws + 51609408); // -> 51,748,672
  unsigned short* BIth = (unsigned short*)(ws + 51748672); // 139,264 fl
  unsigned short* BItl = (unsigned short*)(ws + 51887936); // -> end 52,027,200 (~208 MB)
  float* MS    = XWM;
  float* IFR   = ws + 0;          // aliases XP region after gemm4
  unsigned int* WhhP4 = (unsigned int*)(XWM + 19693568);   // after true end of XW
  // Pre-GEMM scratch inside HOUT (dead until k_lstm):
  float* BFf = HOUT;                                        // 263,168 fl
  float* BWf = HOUT + 263168;                               // 262,144 fl
  unsigned short* BCh = (unsigned short*)(HOUT + 525312);   // 1152*544 ush = 313,344 fl
  unsigned short* BCl = (unsigned short*)(HOUT + 838656);   // -> 1,152,000 fl < 4,924,288
  // B rows 0-511 duplicated into PSD regions (dead until k_psd) for the fused
  // k_lstm_s, whose concurrent LSTM overwrites the HOUT-resident BC (v18 race):
  unsigned short* BFsh = (unsigned short*)PSD_S;            // 512*544 ush = 139,264 fl <= 263,168
  unsigned short* BFsl = (unsigned short*)PSD_N;            // ditto
  // Post-beam ENH split in HOUT (Hout consumed by maskms before k_beam):
  unsigned short* ENHh = (unsigned short*)HOUT;             // 4808*544 ush = 1,307,776 fl
  unsigned short* ENHl = (unsigned short*)(HOUT + 1307776);

  // fused init: xp + wsq + bff + wtsplit + bisplit + bsum + wmsplit + wpack
  k_init<<<NINIT, 256, 0, stream>>>(x, Wih, Whh, bih, bhh, W1, W2,
                                    XPh, XPl, WSQ, BFf, WTth, WTtl, BIth, BItl,
                                    BSUM, W1sh, W1sl, W2sh, W2sl, WhhP4);

  // BW = BF @ Wih^T  (512x512, K=514) — small gemm3
  {
    dim3 g(4, 4);
    k_gemm3<0><<<g, 256, 0, stream>>>(BFf, WTth, WTtl, nullptr, BWf, 512, 512, DD, DD, G4);
  }
  // combined split B = [BF | BW]; rows 0-511 also mirrored into BFsh/BFsl
  k_bcomb<<<(1152 * KPAD + 255) / 256, 256, 0, stream>>>(BWf, BCh, BCl, BFsh, BFsl);

  // pre-lstm: XW columns (+ S cols 512-513) = col tiles 4-8
  k_gemm4<<<5 * 301, 256, 0, stream>>>(XPh, XPl, BCh, BCl, BSUM, S, XWM, 4, 5);

  // fused: LSTM (blocks 0-63) + S cols 0-511 (col tiles 0-3) on idle CUs,
  // B read from the PSD-resident mirror (race-free vs Hout stores)
  k_lstm_s<<<64 + 4 * 301, 512, 0, stream>>>(XWM, WhhP4, HOUT, XPh, XPl, BFsh, BFsl, S);

  k_maskms<<<9 * 601, 256, 0, stream>>>(HOUT, W1sh, W1sl, b1, S, MS);
  k_psd<<<NB * NF, 256, 0, stream>>>(MS, PSD_S);
  k_maskms<<<9 * 601, 256, 0, stream>>>(HOUT, W2sh, W2sl, b2, S, MS);
  k_psd<<<NB * NF, 256, 0, stream>>>(MS, PSD_N);

  k_solve<<<(NB * NF + 63) / 64, 64, 0, stream>>>(PSD_S, PSD_N, WV);
  k_beam<<<NB * TT, 320, 0, stream>>>(S, WV, ENHh, ENHl);

  // iSTFT: IFR[4808,512] = ENH @ BI (pre-split A)
  {
    dim3 g(4, 38);
    k_gemm5<<<g, 256, 0, stream>>>(ENHh, ENHl, BIth, BItl, IFR, NB * TT, NFFT, NFFT);
  }

  k_ola<<<(NB * LSEQ + 255) / 256, 256, 0, stream>>>(IFR, WSQ, (float*)d_out);
}

// Round 13
// 1004.665 us; speedup vs baseline: 1.5369x; 1.0158x over previous
//
#include <hip/hip_runtime.h>
#include <math.h>

#define NFFT  512
#define WINL  320
#define HOP   160
#define FPAD  256
#define NF    257
#define TT    601
#define LSEQ  96000
#define XPLEN 96512
#define NCH   8
#define NB    8
#define NSEQ  64
#define NROWS 38464   // NSEQ*TT
#define DD    514
#define HH    128
#define G4    512
#define KPAD  544     // 17*32, zero-padded K for split-B arrays
#define NCOMB 1026    // 514 (S cols) + 512 (XW cols)

// init block ranges (v20: xp coalesced; wsq/bisplit/wmsplit moved to lstm shadow)
#define NXPC  3000    // coalesced interior xp: 8 b * 375 chunks of 256 j
#define NXPE  128     // reflect edges: 64 n * 512 i / 256
#define NBFF  1028    // NFFT*DD/256
#define NWT   1088    // G4*KPAD/256
#define NBS   2       // G4/256
#define NWP   128     // G4*64/256
#define NINIT (NXPC + NXPE + NBFF + NWT + NBS + NWP)   // 5374
// shadow aux ranges (inside k_lstm_s, after the S-GEMM blocks)
#define NWSQ  377     // XPLEN/256
#define NBI   1088    // NFFT*KPAD/256
#define NWM   640     // 2*640*HH/256
#define NGB   1204    // 4*301 S-GEMM blocks
#define NAUX  (NWSQ + NBI + NWM)   // 2105

typedef _Float16 h2v __attribute__((ext_vector_type(2)));
typedef short bf16x8 __attribute__((ext_vector_type(8)));
typedef float f32x4 __attribute__((ext_vector_type(4)));

// ---------------- init helpers ----------------
__device__ __forceinline__ float winval(int k) {
  if (k < 96 || k >= 416) return 0.f;
  return 0.5f - 0.5f * cosf((float)(2.0 * M_PI / 320.0) * (float)(k - 96));
}

__device__ __forceinline__ void split_bf16(float v, unsigned short* h, unsigned short* l) {
  unsigned int hb = __float_as_uint(v) >> 16;
  float r = v - __uint_as_float(hb << 16);
  *h = (unsigned short)hb;
  *l = (unsigned short)(__float_as_uint(r) >> 16);
}

// async global->LDS, 16B per lane; dest is wave-uniform base + lane*16
__device__ __forceinline__ void glds16(const unsigned short* g, unsigned short* l) {
  __builtin_amdgcn_global_load_lds(
      (const __attribute__((address_space(1))) void*)g,
      (__attribute__((address_space(3))) void*)l,
      16, 0, 0);
}

// bijective XCD-chunk swizzle (m204 variant; works for nwg%8 != 0)
__device__ __forceinline__ int xcd_swz(int orig, int nwg) {
  int q = nwg >> 3, r = nwg & 7;
  int xcd = orig & 7, slot = orig >> 3;
  return (xcd < r ? xcd * (q + 1) : r * (q + 1) + (xcd - r) * q) + slot;
}

// ---------------- fused init (v20): coalesced xp + bff + wtsplit + bsum + wpack ----------------
__global__ void k_init(const float* __restrict__ x, const float* __restrict__ Wih,
                       const float* __restrict__ Whh, const float* __restrict__ bih,
                       const float* __restrict__ bhh,
                       unsigned short* __restrict__ XPh, unsigned short* __restrict__ XPl,
                       float* __restrict__ BFf,
                       unsigned short* __restrict__ WTh, unsigned short* __restrict__ WTl,
                       float* __restrict__ BSUM,
                       unsigned int* __restrict__ WhhP4) {
  int b = blockIdx.x;
  const int tid = threadIdx.x;

  if (b < NXPC) {                      // ---- coalesced interior xp ----
    __shared__ float f[256 * 9];       // [j_local][c], pitch 9 (bank-conflict pad)
    int bb = b / 375, chunk = b - bb * 375;
    int j0 = chunk * 256;
    long gbase = ((long)bb * LSEQ + j0) * 8;
#pragma unroll
    for (int k = 0; k < 8; k++) {
      int e = tid + k * 256;           // linear element in [0,2048)
      float v = x[gbase + e];
      f[(e >> 3) * 9 + (e & 7)] = v;
    }
    __syncthreads();
    int c = tid >> 5, t31 = tid & 31;
    long plane = (long)(bb * 8 + c) * XPLEN;
#pragma unroll
    for (int jj = 0; jj < 8; jj++) {
      int jl = jj * 32 + t31;
      float v = f[jl * 9 + c];
      long o = plane + j0 + jl + FPAD;
      split_bf16(v, &XPh[o], &XPl[o]);
    }
    return;
  }
  b -= NXPC;

  if (b < NXPE) {                      // ---- reflect edges (old scalar path) ----
    int idx = b * 256 + tid;           // [0, 32768)
    int n = idx >> 9, e = idx & 511;
    int i = (e < 256) ? e : (96000 + e);
    int j = i - FPAD;
    if (j < 0) j = -j;
    else if (j >= LSEQ) j = 2 * LSEQ - 2 - j;
    int bb = n >> 3, c = n & 7;
    float v = x[((long)bb * LSEQ + j) * NCH + c];
    long o = (long)n * XPLEN + i;
    split_bf16(v, &XPh[o], &XPl[o]);
    return;
  }
  b -= NXPE;

  if (b < NBFF) {                      // ---- k_bff ----
    int idx = b * 256 + tid;
    if (idx < NFFT * DD) {
      int k = idx / DD, d = idx - k * DD;
      float w = winval(k);
      int f = (d < NF) ? d : d - NF;
      int m = (k * f) & 511;
      float th = (float)(M_PI / 256.0) * (float)m;
      BFf[idx] = ((d < NF) ? cosf(th) : -sinf(th)) * w;
    }
    return;
  }
  b -= NBFF;

  if (b < NWT) {                       // ---- k_wtsplit ----
    int idx = b * 256 + tid;
    if (idx < G4 * KPAD) {
      int n = idx / KPAD, k = idx - n * KPAD;
      float v = (k < DD) ? Wih[n * DD + k] : 0.f;
      split_bf16(v, &WTh[idx], &WTl[idx]);
    }
    return;
  }
  b -= NWT;

  if (b < NBS) {                       // ---- k_bsum ----
    int idx = b * 256 + tid;
    if (idx < G4) BSUM[idx] = bih[idx] + bhh[idx];
    return;
  }
  b -= NBS;

  {                                    // ---- k_wpack ----
    int idx = b * 256 + tid;
    if (idx < G4 * 64) {
      int j = idx >> 6, k2 = idx & 63;
      _Float16 lo = (_Float16)Whh[j * HH + 2 * k2];
      _Float16 hi = (_Float16)Whh[j * HH + 2 * k2 + 1];
      unsigned int u = ((unsigned int)__builtin_bit_cast(unsigned short, hi) << 16)
                     |  (unsigned int)__builtin_bit_cast(unsigned short, lo);
      WhhP4[(k2 >> 2) * (G4 * 4) + j * 4 + (k2 & 3)] = u;
    }
  }
}

// Combined split B for the fused STFT+xW GEMM: BC[n][k], n in [0,1152).
// Rows 0-511 mirrored into BFsh/BFsl (PSD regions, dead until k_psd) for the
// fused k_lstm_s (its LSTM overwrites the HOUT-resident BC - the v18 race).
__global__ void k_bcomb(const float* __restrict__ BWf, unsigned short* __restrict__ H,
                        unsigned short* __restrict__ L,
                        unsigned short* __restrict__ BFsh, unsigned short* __restrict__ BFsl) {
  int idx = blockIdx.x * 256 + threadIdx.x;
  if (idx >= 1152 * KPAD) return;
  int n = idx / KPAD, k = idx - n * KPAD;
  float v = 0.f;
  if (k < NFFT) {
    if (n < DD) {
      float w = winval(k);
      int f = (n < NF) ? n : n - NF;
      int m = (k * f) & 511;
      float th = (float)(M_PI / 256.0) * (float)m;
      v = ((n < NF) ? cosf(th) : -sinf(th)) * w;
    } else if (n < NCOMB) {
      v = BWf[k * G4 + (n - 514)];
    }
  }
  unsigned short h, l;
  split_bf16(v, &h, &l);
  H[idx] = h; L[idx] = l;
  if (n < 512) { BFsh[idx] = h; BFsl[idx] = l; }   // idx = n*KPAD+k, same layout
}

// ---------------- split-bf16 MFMA GEMM (fp32 A): C[M,N] = A[M,K] * Bt^T (+bias) ----------------
template <int GATHER>
__launch_bounds__(256)
__global__ void k_gemm3(const float* __restrict__ A,
                        const unsigned short* __restrict__ Bth,
                        const unsigned short* __restrict__ Btl,
                        const float* __restrict__ bias, float* __restrict__ C,
                        int M, int N, int K, int lda, int ldc) {
  __shared__ __align__(16) unsigned short sAh[128 * 40];
  __shared__ __align__(16) unsigned short sAl[128 * 40];
  __shared__ __align__(16) unsigned short sBh[128 * 40];
  __shared__ __align__(16) unsigned short sBl[128 * 40];
  const int tid = threadIdx.x;
  const int row0 = blockIdx.y * 128, col0 = blockIdx.x * 128;
  const int sar = tid >> 1, sak = (tid & 1) * 16;
  const int arow = row0 + sar;
  long abase = (long)arow * lda;
  const bool arok = (arow < M);
  const int lane = tid & 63, w = tid >> 6;
  const int wm = (w >> 1) * 64, wn = (w & 1) * 64;
  const int l15 = lane & 15, quad = lane >> 4;
  f32x4 acc[4][4] = {};
  unsigned int* aH = (unsigned int*)sAh;
  unsigned int* aL = (unsigned int*)sAl;
  uint4* bH = (uint4*)sBh;
  uint4* bL = (uint4*)sBl;
  for (int k0 = 0; k0 < K; k0 += 32) {
#pragma unroll
    for (int i = 0; i < 8; i++) {
      int kk = k0 + sak + 2 * i;
      float v0 = 0.f, v1 = 0.f;
      if (arok) {
        if (kk + 1 < K) { float2 t2 = *(const float2*)(A + abase + kk); v0 = t2.x; v1 = t2.y; }
        else if (kk < K) { v0 = A[abase + kk]; }
      }
      unsigned int h0 = __float_as_uint(v0) >> 16, h1 = __float_as_uint(v1) >> 16;
      float r0 = v0 - __uint_as_float(h0 << 16), r1 = v1 - __uint_as_float(h1 << 16);
      unsigned int l0 = __float_as_uint(r0) >> 16, l1 = __float_as_uint(r1) >> 16;
      aH[sar * 20 + (sak >> 1) + i] = h0 | (h1 << 16);
      aL[sar * 20 + (sak >> 1) + i] = l0 | (l1 << 16);
    }
#pragma unroll
    for (int h = 0; h < 2; h++) {
      int idx = tid + h * 256;
      int r = idx >> 2, c = idx & 3;
      long go = (long)(col0 + r) * KPAD + k0 + c * 8;
      bH[r * 5 + c] = *(const uint4*)(Bth + go);
      bL[r * 5 + c] = *(const uint4*)(Btl + go);
    }
    __syncthreads();
    bf16x8 ah[4], al[4], bh[4], bl[4];
#pragma unroll
    for (int i = 0; i < 4; i++) {
      int off = (wm + i * 16 + l15) * 40 + quad * 8;
      ah[i] = *(const bf16x8*)(sAh + off);
      al[i] = *(const bf16x8*)(sAl + off);
      int boff = (wn + i * 16 + l15) * 40 + quad * 8;
      bh[i] = *(const bf16x8*)(sBh + boff);
      bl[i] = *(const bf16x8*)(sBl + boff);
    }
#pragma unroll
    for (int i = 0; i < 4; i++)
#pragma unroll
      for (int j = 0; j < 4; j++) {
        acc[i][j] = __builtin_amdgcn_mfma_f32_16x16x32_bf16(al[i], bh[j], acc[i][j], 0, 0, 0);
        acc[i][j] = __builtin_amdgcn_mfma_f32_16x16x32_bf16(ah[i], bl[j], acc[i][j], 0, 0, 0);
        acc[i][j] = __builtin_amdgcn_mfma_f32_16x16x32_bf16(ah[i], bh[j], acc[i][j], 0, 0, 0);
      }
    __syncthreads();
  }
#pragma unroll
  for (int i = 0; i < 4; i++)
#pragma unroll
    for (int j = 0; j < 4; j++) {
      int cc = col0 + wn + j * 16 + l15;
      if (cc >= N) continue;
      float bv = bias ? bias[cc] : 0.f;
#pragma unroll
      for (int rg = 0; rg < 4; rg++) {
        int rr = row0 + wm + i * 16 + quad * 4 + rg;
        if (rr < M) C[(long)rr * ldc + cc] = acc[i][j][rg] + bv;
      }
    }
}

// ---------------- fused STFT+xW GEMM (partial cols): gload_lds staging + XCD swizzle ----------------
__launch_bounds__(256)
__global__ void k_gemm4(const unsigned short* __restrict__ Ah, const unsigned short* __restrict__ Al,
                        const unsigned short* __restrict__ Bh, const unsigned short* __restrict__ Bl,
                        const float* __restrict__ bsum, float* __restrict__ S,
                        float* __restrict__ XW, int colBase, int nCT) {
  __shared__ __align__(16) unsigned short sAh[128 * 32];
  __shared__ __align__(16) unsigned short sAl[128 * 32];
  __shared__ __align__(16) unsigned short sBh[128 * 32];
  __shared__ __align__(16) unsigned short sBl[128 * 32];
  const int tid = threadIdx.x;
  const int wg = xcd_swz(blockIdx.x, nCT * 301);
  const int row0 = (wg / nCT) * 128, col0 = (colBase + wg % nCT) * 128;
  const int lane = tid & 63, w = tid >> 6;
  const int wm = (w >> 1) * 64, wn = (w & 1) * 64;
  const int l15 = lane & 15, quad = lane >> 4;
  const int sr0 = w * 32 + (lane >> 2);
  const int sr1 = sr0 + 16;
  const int c8 = (lane & 3) * 8;
  long ab0, ab1;
  { int rr = row0 + sr0; int n = rr / TT, t = rr - n * TT; ab0 = (long)n * XPLEN + (long)t * HOP + c8; }
  { int rr = row0 + sr1; int n = rr / TT, t = rr - n * TT; ab1 = (long)n * XPLEN + (long)t * HOP + c8; }
  const long bb0 = (long)(col0 + sr0) * KPAD + c8;
  const long bb1 = (long)(col0 + sr1) * KPAD + c8;
  const int d0 = w * 1024;
  const int d1 = d0 + 512;
  f32x4 acc[4][4] = {};
  for (int k0 = 0; k0 < NFFT; k0 += 32) {
    glds16(Ah + ab0 + k0, sAh + d0);
    glds16(Ah + ab1 + k0, sAh + d1);
    glds16(Al + ab0 + k0, sAl + d0);
    glds16(Al + ab1 + k0, sAl + d1);
    glds16(Bh + bb0 + k0, sBh + d0);
    glds16(Bh + bb1 + k0, sBh + d1);
    glds16(Bl + bb0 + k0, sBl + d0);
    glds16(Bl + bb1 + k0, sBl + d1);
    __syncthreads();
    bf16x8 ah[4], al[4], bh[4], bl[4];
#pragma unroll
    for (int i = 0; i < 4; i++) {
      int off = (wm + i * 16 + l15) * 32 + quad * 8;
      ah[i] = *(const bf16x8*)(sAh + off);
      al[i] = *(const bf16x8*)(sAl + off);
      int boff = (wn + i * 16 + l15) * 32 + quad * 8;
      bh[i] = *(const bf16x8*)(sBh + boff);
      bl[i] = *(const bf16x8*)(sBl + boff);
    }
#pragma unroll
    for (int i = 0; i < 4; i++)
#pragma unroll
      for (int j = 0; j < 4; j++) {
        acc[i][j] = __builtin_amdgcn_mfma_f32_16x16x32_bf16(al[i], bh[j], acc[i][j], 0, 0, 0);
        acc[i][j] = __builtin_amdgcn_mfma_f32_16x16x32_bf16(ah[i], bl[j], acc[i][j], 0, 0, 0);
        acc[i][j] = __builtin_amdgcn_mfma_f32_16x16x32_bf16(ah[i], bh[j], acc[i][j], 0, 0, 0);
      }
    __syncthreads();
  }
#pragma unroll
  for (int i = 0; i < 4; i++)
#pragma unroll
    for (int j = 0; j < 4; j++) {
      int cc = col0 + wn + j * 16 + l15;
      if (cc >= NCOMB) continue;
#pragma unroll
      for (int rg = 0; rg < 4; rg++) {
        int rr = row0 + wm + i * 16 + quad * 4 + rg;
        if (rr >= NROWS) continue;
        float v = acc[i][j][rg];
        if (cc < DD) S[(long)rr * DD + cc] = v;
        else         XW[(long)rr * G4 + (cc - 514)] = v + bsum[cc - 514];
      }
    }
}

// ---------------- iSTFT GEMM: pre-split A (pitch KPAD), B = BI split ----------------
__launch_bounds__(256)
__global__ void k_gemm5(const unsigned short* __restrict__ Ah, const unsigned short* __restrict__ Al,
                        const unsigned short* __restrict__ Bh, const unsigned short* __restrict__ Bl,
                        float* __restrict__ C, int M, int N, int ldc) {
  __shared__ __align__(16) unsigned short sAh[128 * 40];
  __shared__ __align__(16) unsigned short sAl[128 * 40];
  __shared__ __align__(16) unsigned short sBh[128 * 40];
  __shared__ __align__(16) unsigned short sBl[128 * 40];
  const int tid = threadIdx.x;
  const int row0 = blockIdx.y * 128, col0 = blockIdx.x * 128;
  const int sr0 = tid >> 2, c4 = (tid & 3) * 8, cq = tid & 3;
  const int lane = tid & 63, w = tid >> 6;
  const int wm = (w >> 1) * 64, wn = (w & 1) * 64;
  const int l15 = lane & 15, quad = lane >> 4;
  f32x4 acc[4][4] = {};
  uint4* aH4 = (uint4*)sAh; uint4* aL4 = (uint4*)sAl;
  uint4* bH4 = (uint4*)sBh; uint4* bL4 = (uint4*)sBl;
  for (int k0 = 0; k0 < KPAD; k0 += 32) {
    {
      long go = (long)(row0 + sr0) * KPAD + k0 + c4;
      aH4[sr0 * 5 + cq] = *(const uint4*)(Ah + go);
      aL4[sr0 * 5 + cq] = *(const uint4*)(Al + go);
      go = (long)(row0 + sr0 + 64) * KPAD + k0 + c4;
      aH4[(sr0 + 64) * 5 + cq] = *(const uint4*)(Ah + go);
      aL4[(sr0 + 64) * 5 + cq] = *(const uint4*)(Al + go);
    }
    {
      long go = (long)(col0 + sr0) * KPAD + k0 + c4;
      bH4[sr0 * 5 + cq] = *(const uint4*)(Bh + go);
      bL4[sr0 * 5 + cq] = *(const uint4*)(Bl + go);
      go = (long)(col0 + sr0 + 64) * KPAD + k0 + c4;
      bH4[(sr0 + 64) * 5 + cq] = *(const uint4*)(Bh + go);
      bL4[(sr0 + 64) * 5 + cq] = *(const uint4*)(Bl + go);
    }
    __syncthreads();
    bf16x8 ah[4], al[4], bh[4], bl[4];
#pragma unroll
    for (int i = 0; i < 4; i++) {
      int off = (wm + i * 16 + l15) * 40 + quad * 8;
      ah[i] = *(const bf16x8*)(sAh + off);
      al[i] = *(const bf16x8*)(sAl + off);
      int boff = (wn + i * 16 + l15) * 40 + quad * 8;
      bh[i] = *(const bf16x8*)(sBh + boff);
      bl[i] = *(const bf16x8*)(sBl + boff);
    }
#pragma unroll
    for (int i = 0; i < 4; i++)
#pragma unroll
      for (int j = 0; j < 4; j++) {
        acc[i][j] = __builtin_amdgcn_mfma_f32_16x16x32_bf16(al[i], bh[j], acc[i][j], 0, 0, 0);
        acc[i][j] = __builtin_amdgcn_mfma_f32_16x16x32_bf16(ah[i], bl[j], acc[i][j], 0, 0, 0);
        acc[i][j] = __builtin_amdgcn_mfma_f32_16x16x32_bf16(ah[i], bh[j], acc[i][j], 0, 0, 0);
      }
    __syncthreads();
  }
#pragma unroll
  for (int i = 0; i < 4; i++)
#pragma unroll
    for (int j = 0; j < 4; j++) {
      int cc = col0 + wn + j * 16 + l15;
      if (cc >= N) continue;
#pragma unroll
      for (int rg = 0; rg < 4; rg++) {
        int rr = row0 + wm + i * 16 + quad * 4 + rg;
        if (rr < M) C[(long)rr * ldc + cc] = acc[i][j][rg];
      }
    }
}

// ---------------- fused LSTM + S-GEMM + shadow aux ----------------
// Blocks 0-63: v11 LSTM (setprio(1), T5). Blocks 64..64+NGB: gemm4 col tiles
// 0-3 (pure S, B from the PSD-resident mirror). Blocks beyond: wsq / bisplit /
// wmsplit - consumed only post-lstm (ola / gemm5 / maskms), so they run free
// in the LSTM's shadow. All writes disjoint from concurrent reads (audited).
__device__ __forceinline__ float tanh_fast(float x) {
  float e = __expf(2.f * x);
  return 1.f - 2.f / (e + 1.f);
}

__launch_bounds__(512)
__global__ void k_lstm_s(const float* __restrict__ XW, const unsigned int* __restrict__ WhhP4,
                         float* __restrict__ Hout,
                         const unsigned short* __restrict__ Ah, const unsigned short* __restrict__ Al,
                         const unsigned short* __restrict__ Bh, const unsigned short* __restrict__ Bl,
                         float* __restrict__ S,
                         const float* __restrict__ W1, const float* __restrict__ W2,
                         float* __restrict__ wsqp,
                         unsigned short* __restrict__ BIh, unsigned short* __restrict__ BIl,
                         unsigned short* __restrict__ W1h, unsigned short* __restrict__ W1l,
                         unsigned short* __restrict__ W2h, unsigned short* __restrict__ W2l) {
  __shared__ __align__(16) unsigned short sAh[128 * 32];
  __shared__ __align__(16) unsigned short sAl[128 * 32];
  __shared__ __align__(16) unsigned short sBh[128 * 32];
  __shared__ __align__(16) unsigned short sBl[128 * 32];
  __shared__ __align__(16) unsigned int hl2[64];
  __shared__ float gl[G4];
  const int tid = threadIdx.x;

  if (blockIdx.x < 64) {
    // ---------------- LSTM path (verbatim v11) ----------------
    __builtin_amdgcn_s_setprio(1);
    const int j = tid;
    const int n = blockIdx.x;
    const uint4* W4 = (const uint4*)WhhP4;
    unsigned int wp[64];
#pragma unroll
    for (int i4 = 0; i4 < 16; i4++) {
      uint4 v = W4[i4 * G4 + j];
      wp[4 * i4]     = v.x;
      wp[4 * i4 + 1] = v.y;
      wp[4 * i4 + 2] = v.z;
      wp[4 * i4 + 3] = v.w;
    }
    float cst = 0.f;
    if (j < 64) hl2[j] = 0u;
    const float* xwrow = XW + (long)n * TT * G4 + j;
    float xnext = xwrow[0];
    const uint4* h4 = (const uint4*)hl2;
    const bool isg = (j >= 2 * HH) && (j < 3 * HH);
    __syncthreads();
    for (int t = 0; t < TT; t++) {
      float xv = xnext;
      if (t + 1 < TT) xnext = xwrow[(long)(t + 1) * G4];
      float a0 = 0.f, a1 = 0.f, a2 = 0.f, a3 = 0.f;
#pragma unroll
      for (int k = 0; k < 16; k++) {
        uint4 hv4 = h4[k];   // uniform address -> LDS broadcast, conflict-free
        a0 = __builtin_amdgcn_fdot2(__builtin_bit_cast(h2v, hv4.x), __builtin_bit_cast(h2v, wp[4 * k]),     a0, false);
        a1 = __builtin_amdgcn_fdot2(__builtin_bit_cast(h2v, hv4.y), __builtin_bit_cast(h2v, wp[4 * k + 1]), a1, false);
        a2 = __builtin_amdgcn_fdot2(__builtin_bit_cast(h2v, hv4.z), __builtin_bit_cast(h2v, wp[4 * k + 2]), a2, false);
        a3 = __builtin_amdgcn_fdot2(__builtin_bit_cast(h2v, hv4.w), __builtin_bit_cast(h2v, wp[4 * k + 3]), a3, false);
      }
      float a = ((a0 + a1) + (a2 + a3)) + xv;
      float nl;
      if (isg) nl = tanh_fast(a);
      else     nl = 1.f / (1.f + __expf(-a));
      gl[j] = nl;
      asm volatile("s_waitcnt lgkmcnt(0)" ::: "memory");
      __builtin_amdgcn_s_barrier();
      if (j < HH) {
        float ni = gl[j], nf = gl[HH + j], ng = gl[2 * HH + j], no = gl[3 * HH + j];
        cst = nf * cst + ni * ng;
        float hv = no * tanh_fast(cst);
        ((_Float16*)hl2)[j] = (_Float16)hv;
        Hout[((long)n * TT + t) * HH + j] = hv;
      }
      asm volatile("s_waitcnt lgkmcnt(0)" ::: "memory");
      __builtin_amdgcn_s_barrier();
    }
    __builtin_amdgcn_s_setprio(0);
    return;
  }

  int gb = blockIdx.x - 64;
  if (gb < NGB) {
    // ---------------- S-GEMM path: gemm4 col tiles 0-3 ----------------
    const int wg = xcd_swz(gb, NGB);
    const int row0 = (wg >> 2) * 128, col0 = (wg & 3) * 128;
    const int lane = tid & 63, w = tid >> 6;
    const int wm = (w >> 1) * 64, wn = (w & 1) * 64;
    const int l15 = lane & 15, quad = lane >> 4;
    const int sr0 = w * 32 + (lane >> 2);
    const int sr1 = sr0 + 16;
    const int c8 = (lane & 3) * 8;
    long ab0 = 0, ab1 = 0, bb0 = 0, bb1 = 0;
    int d0 = 0, d1 = 0;
    if (tid < 256) {
      { int rr = row0 + sr0; int n = rr / TT, t = rr - n * TT; ab0 = (long)n * XPLEN + (long)t * HOP + c8; }
      { int rr = row0 + sr1; int n = rr / TT, t = rr - n * TT; ab1 = (long)n * XPLEN + (long)t * HOP + c8; }
      bb0 = (long)(col0 + sr0) * KPAD + c8;
      bb1 = (long)(col0 + sr1) * KPAD + c8;
      d0 = w * 1024;
      d1 = d0 + 512;
    }
    f32x4 acc[4][4] = {};
    for (int k0 = 0; k0 < NFFT; k0 += 32) {
      if (tid < 256) {
        glds16(Ah + ab0 + k0, sAh + d0);
        glds16(Ah + ab1 + k0, sAh + d1);
        glds16(Al + ab0 + k0, sAl + d0);
        glds16(Al + ab1 + k0, sAl + d1);
        glds16(Bh + bb0 + k0, sBh + d0);
        glds16(Bh + bb1 + k0, sBh + d1);
        glds16(Bl + bb0 + k0, sBl + d0);
        glds16(Bl + bb1 + k0, sBl + d1);
      }
      __syncthreads();
      if (tid < 256) {
        bf16x8 ah[4], al[4], bh[4], bl[4];
#pragma unroll
        for (int i = 0; i < 4; i++) {
          int off = (wm + i * 16 + l15) * 32 + quad * 8;
          ah[i] = *(const bf16x8*)(sAh + off);
          al[i] = *(const bf16x8*)(sAl + off);
          int boff = (wn + i * 16 + l15) * 32 + quad * 8;
          bh[i] = *(const bf16x8*)(sBh + boff);
          bl[i] = *(const bf16x8*)(sBl + boff);
        }
#pragma unroll
        for (int i = 0; i < 4; i++)
#pragma unroll
          for (int j = 0; j < 4; j++) {
            acc[i][j] = __builtin_amdgcn_mfma_f32_16x16x32_bf16(al[i], bh[j], acc[i][j], 0, 0, 0);
            acc[i][j] = __builtin_amdgcn_mfma_f32_16x16x32_bf16(ah[i], bl[j], acc[i][j], 0, 0, 0);
            acc[i][j] = __builtin_amdgcn_mfma_f32_16x16x32_bf16(ah[i], bh[j], acc[i][j], 0, 0, 0);
          }
      }
      __syncthreads();
    }
    if (tid < 256) {
#pragma unroll
      for (int i = 0; i < 4; i++)
#pragma unroll
        for (int j = 0; j < 4; j++) {
          int cc = col0 + wn + j * 16 + l15;   // <= 511 < DD: pure S columns
#pragma unroll
          for (int rg = 0; rg < 4; rg++) {
            int rr = row0 + wm + i * 16 + quad * 4 + rg;
            if (rr < NROWS) S[(long)rr * DD + cc] = acc[i][j][rg];
          }
        }
    }
    return;
  }

  // ---------------- shadow aux: wsq / bisplit / wmsplit ----------------
  int sb = gb - NGB;
  if (tid >= 256) return;
  if (sb < NWSQ) {                     // ---- wsq ----
    int p = sb * 256 + tid;
    if (p < XPLEN) {
      int t0 = (p <= 511) ? 0 : (p - 352) / 160;
      int t1 = p / 160; if (t1 > 600) t1 = 600;
      float s = 0.f;
      for (int t = t0; t <= t1; t++) { float w = winval(p - t * HOP); s += w * w; }
      wsqp[p] = s;
    }
    return;
  }
  sb -= NWSQ;
  if (sb < NBI) {                      // ---- bisplit ----
    int idx = sb * 256 + tid;
    if (idx < NFFT * KPAD) {
      int n = idx / KPAD, kk = idx - n * KPAD;
      float v = 0.f;
      if (kk < DD) {
        float w = winval(n);
        int f = (kk < NF) ? kk : kk - NF;
        int edge = (f == 0 || f == 256);
        float alpha = edge ? 1.f : 2.f;
        int m = (n * f) & 511;
        float th = (float)(M_PI / 256.0) * (float)m;
        float c;
        if (kk < NF) c = alpha * cosf(th);
        else         c = edge ? 0.f : -alpha * sinf(th);
        v = c * w * (1.f / 512.f);
      }
      split_bf16(v, &BIh[idx], &BIl[idx]);
    }
    return;
  }
  sb -= NBI;
  {                                    // ---- wmsplit ----
    int idx = sb * 256 + tid;
    if (idx < 2 * 640 * HH) {
      int m = idx / (640 * HH);
      int rem = idx - m * 640 * HH;
      int np = rem / HH, k = rem - np * HH;
      int ri = np / 320, f = np - ri * 320;
      float v = 0.f;
      if (f < NF) {
        int fcol = (ri == 0) ? f : NF + f;
        v = (m == 0) ? W1[fcol * HH + k] : W2[fcol * HH + k];
      }
      unsigned short h, l;
      split_bf16(v, &h, &l);
      if (m == 0) { W1h[rem] = h; W1l[rem] = l; }
      else        { W2h[rem] = h; W2l[rem] = l; }
    }
  }
}

// ---------------- mask GEMM (split-bf16 MFMA) + mask apply + transpose ----------------
// MS layout: [b][f][c][t] complex-interleaved (re,im); XCD-chunk swizzled grid.
__launch_bounds__(256)
__global__ void k_maskms(const float* __restrict__ Hout,
                         const unsigned short* __restrict__ Wsh,
                         const unsigned short* __restrict__ Wsl,
                         const float* __restrict__ bias, const float* __restrict__ S,
                         float* __restrict__ MS) {
  __shared__ __align__(16) unsigned short sAh[64 * 40];
  __shared__ __align__(16) unsigned short sAl[64 * 40];
  __shared__ __align__(16) unsigned short sBh[64 * 40];
  __shared__ __align__(16) unsigned short sBl[64 * 40];
  __shared__ float Cs[64][68];
  __shared__ float SR[64][33];
  __shared__ float SI[64][33];
  const int tid = threadIdx.x;
  const int wg = xcd_swz(blockIdx.x, 9 * 601);
  const int f0 = (wg % 9) * 32;
  const int row0 = (wg / 9) * 64;
  const int lane = tid & 63, w = tid >> 6;
  const int wm = w * 16;
  const int l15 = lane & 15, quad = lane >> 4;
  const int sar = tid >> 2;
  const int sak = (tid & 3) * 8;
  const int np = ((sar < 32) ? 0 : 320 - 32) + f0 + sar;
  unsigned int* aH = (unsigned int*)sAh;
  unsigned int* aL = (unsigned int*)sAl;
  f32x4 acc[4] = {};
  for (int k0 = 0; k0 < HH; k0 += 32) {
    {
      const float* ap = Hout + (long)(row0 + sar) * HH + k0 + sak;
      float4 v0 = *(const float4*)ap;
      float4 v1 = *(const float4*)(ap + 4);
      float vv[8] = {v0.x, v0.y, v0.z, v0.w, v1.x, v1.y, v1.z, v1.w};
#pragma unroll
      for (int i = 0; i < 4; i++) {
        unsigned int h0 = __float_as_uint(vv[2 * i]) >> 16, h1 = __float_as_uint(vv[2 * i + 1]) >> 16;
        float r0 = vv[2 * i] - __uint_as_float(h0 << 16), r1 = vv[2 * i + 1] - __uint_as_float(h1 << 16);
        unsigned int l0 = __float_as_uint(r0) >> 16, l1 = __float_as_uint(r1) >> 16;
        aH[sar * 20 + (sak >> 1) + i] = h0 | (h1 << 16);
        aL[sar * 20 + (sak >> 1) + i] = l0 | (l1 << 16);
      }
    }
    {
      long go = (long)np * HH + k0 + sak;
      *(uint4*)(sBh + sar * 40 + sak) = *(const uint4*)(Wsh + go);
      *(uint4*)(sBl + sar * 40 + sak) = *(const uint4*)(Wsl + go);
    }
    __syncthreads();
    bf16x8 ah = *(const bf16x8*)(sAh + (wm + l15) * 40 + quad * 8);
    bf16x8 al = *(const bf16x8*)(sAl + (wm + l15) * 40 + quad * 8);
#pragma unroll
    for (int ct = 0; ct < 4; ct++) {
      bf16x8 bh = *(const bf16x8*)(sBh + (ct * 16 + l15) * 40 + quad * 8);
      bf16x8 bl = *(const bf16x8*)(sBl + (ct * 16 + l15) * 40 + quad * 8);
      acc[ct] = __builtin_amdgcn_mfma_f32_16x16x32_bf16(al, bh, acc[ct], 0, 0, 0);
      acc[ct] = __builtin_amdgcn_mfma_f32_16x16x32_bf16(ah, bl, acc[ct], 0, 0, 0);
      acc[ct] = __builtin_amdgcn_mfma_f32_16x16x32_bf16(ah, bh, acc[ct], 0, 0, 0);
    }
    __syncthreads();
  }
#pragma unroll
  for (int ct = 0; ct < 4; ct++) {
    int col = ct * 16 + l15;
    int f = f0 + (col & 31);
    int fcol = (col < 32) ? f : NF + f;
    float bv = (f < NF) ? bias[fcol] : 0.f;
#pragma unroll
    for (int rg = 0; rg < 4; rg++) Cs[wm + quad * 4 + rg][col] = acc[ct][rg] + bv;
  }
  __syncthreads();
  {
    int fl = tid & 31, r8 = tid >> 5;
    int f = f0 + fl;
#pragma unroll
    for (int i = 0; i < 8; i++) {
      int rl = r8 * 8 + i;
      int rr = row0 + rl;
      float rm = Cs[rl][fl], im = Cs[rl][32 + fl];
      float sr = 0.f, si = 0.f;
      if (f < NF) { sr = S[(long)rr * DD + f]; si = S[(long)rr * DD + NF + f]; }
      SR[rl][fl] = rm * sr - im * si;
      SI[rl][fl] = rm * si + im * sr;
    }
  }
  __syncthreads();
  {
    int tl = tid & 63, fq = tid >> 6;
    int rr = row0 + tl;
    int n = rr / TT, t = rr - n * TT;
    int b = n >> 3, c = n & 7;
#pragma unroll
    for (int i = 0; i < 8; i++) {
      int fl = fq * 8 + i;
      int f = f0 + fl;
      if (f < NF) {
        long addr = ((((long)b * NF + f) * 8 + c) * (long)TT + t) * 2;
        *(float2*)&MS[addr] = make_float2(SR[tl][fl], SI[tl][fl]);
      }
    }
  }
}

// ---------------- PSD: one block per (b,f); complex-interleaved MS ----------------
__launch_bounds__(256)
__global__ void k_psd(const float* __restrict__ MS, float* __restrict__ PSD) {
  __shared__ float buf[9616];
  __shared__ float part[64][8];
  const int tid = threadIdx.x;
  const long base = (long)blockIdx.x * 9616;
  for (int i = tid; i < 9616; i += 256) buf[i] = MS[base + i];
  __syncthreads();
  int p = tid & 63, q = tid >> 6;
  int c = p >> 3, e = p & 7;
  const float2* xc = (const float2*)&buf[c * 1202];
  const float2* xe = (const float2*)&buf[e * 1202];
  int t0 = q * 150, t1 = (q == 3) ? TT : t0 + 150;
  float ar = 0.f, ai = 0.f;
  for (int t = t0; t < t1; t++) {
    float2 m = xc[t];
    float2 v = xe[t];
    ar += m.x * v.x + m.y * v.y;
    ai += m.y * v.x - m.x * v.y;
  }
  part[p][q * 2] = ar; part[p][q * 2 + 1] = ai;
  __syncthreads();
  if (tid < 64) {
    float sr = part[tid][0] + part[tid][2] + part[tid][4] + part[tid][6];
    float si = part[tid][1] + part[tid][3] + part[tid][5] + part[tid][7];
    PSD[((long)blockIdx.x * 64 + tid) * 2]     = sr * (1.f / 601.f);
    PSD[((long)blockIdx.x * 64 + tid) * 2 + 1] = si * (1.f / 601.f);
  }
}

// ---------------- 8x8 complex solve + MVDR weight ----------------
__launch_bounds__(64)
__global__ void k_solve(const float* __restrict__ PS, const float* __restrict__ PN,
                        float* __restrict__ WV) {
  int idx = blockIdx.x * 64 + threadIdx.x;
  if (idx >= NB * NF) return;
  float Ar[8][8], Ai[8][8], Br[8][8], Bi[8][8];
  const float* pn = PN + (long)idx * 128;
  const float* ps = PS + (long)idx * 128;
  for (int i = 0; i < 8; i++)
    for (int j = 0; j < 8; j++) {
      Ar[i][j] = pn[(i * 8 + j) * 2]; Ai[i][j] = pn[(i * 8 + j) * 2 + 1];
      Br[i][j] = ps[(i * 8 + j) * 2]; Bi[i][j] = ps[(i * 8 + j) * 2 + 1];
    }
  float tr = 0.f;
  for (int i = 0; i < 8; i++) tr += Ar[i][i];
  float load = 1e-6f * tr / 8.f + 1e-8f;
  for (int i = 0; i < 8; i++) Ar[i][i] += load;
  for (int k = 0; k < 8; k++) {
    int piv = k; float mx = Ar[k][k] * Ar[k][k] + Ai[k][k] * Ai[k][k];
    for (int i = k + 1; i < 8; i++) {
      float m2 = Ar[i][k] * Ar[i][k] + Ai[i][k] * Ai[i][k];
      if (m2 > mx) { mx = m2; piv = i; }
    }
    if (piv != k) {
      for (int j = 0; j < 8; j++) {
        float t0;
        t0 = Ar[k][j]; Ar[k][j] = Ar[piv][j]; Ar[piv][j] = t0;
        t0 = Ai[k][j]; Ai[k][j] = Ai[piv][j]; Ai[piv][j] = t0;
        t0 = Br[k][j]; Br[k][j] = Br[piv][j]; Br[piv][j] = t0;
        t0 = Bi[k][j]; Bi[k][j] = Bi[piv][j]; Bi[piv][j] = t0;
      }
    }
    float dr = Ar[k][k], di = Ai[k][k];
    float inv = 1.f / (dr * dr + di * di);
    float irr = dr * inv, iii = -di * inv;
    for (int j = 0; j < 8; j++) {
      float xr = Ar[k][j], xi = Ai[k][j];
      Ar[k][j] = xr * irr - xi * iii; Ai[k][j] = xr * iii + xi * irr;
      xr = Br[k][j]; xi = Bi[k][j];
      Br[k][j] = xr * irr - xi * iii; Bi[k][j] = xr * iii + xi * irr;
    }
    for (int i = 0; i < 8; i++) {
      if (i == k) continue;
      float fr = Ar[i][k], fi = Ai[i][k];
      for (int j = 0; j < 8; j++) {
        float kr = Ar[k][j], ki = Ai[k][j];
        Ar[i][j] -= fr * kr - fi * ki;
        Ai[i][j] -= fr * ki + fi * kr;
        kr = Br[k][j]; ki = Bi[k][j];
        Br[i][j] -= fr * kr - fi * ki;
        Bi[i][j] -= fr * ki + fi * kr;
      }
    }
  }
  float trr = 1e-8f, tri = 0.f;
  for (int i = 0; i < 8; i++) { trr += Br[i][i]; tri += Bi[i][i]; }
  float inv = 1.f / (trr * trr + tri * tri);
  for (int c = 0; c < 8; c++) {
    float xr = Br[c][0], xi = Bi[c][0];
    WV[((long)idx * 8 + c) * 2]     = (xr * trr + xi * tri) * inv;
    WV[((long)idx * 8 + c) * 2 + 1] = (xi * trr - xr * tri) * inv;
  }
}

// ---------------- beamform -> pre-split ENH (KPAD rows) ----------------
__launch_bounds__(320)
__global__ void k_beam(const float* __restrict__ S, const float* __restrict__ WV,
                       unsigned short* __restrict__ ENHh, unsigned short* __restrict__ ENHl) {
  __shared__ float WL[NF * 16];
  int bb = blockIdx.x / TT, t = blockIdx.x - bb * TT;
  for (int i = threadIdx.x; i < NF * 16; i += 320) WL[i] = WV[(long)bb * NF * 16 + i];
  __syncthreads();
  int f = threadIdx.x;
  long base = ((long)bb * TT + t) * KPAD;
  if (f < NF) {
    float er = 0.f, ei = 0.f;
#pragma unroll
    for (int c = 0; c < 8; c++) {
      float wr = WL[(f * 8 + c) * 2], wi = WL[(f * 8 + c) * 2 + 1];
      const float* srow = S + (((long)(bb * 8 + c) * TT) + t) * DD;
      float sr = srow[f], si = srow[NF + f];
      er += wr * sr + wi * si;
      ei += wr * si - wi * sr;
    }
    split_bf16(er, &ENHh[base + f], &ENHl[base + f]);
    split_bf16(ei, &ENHh[base + NF + f], &ENHl[base + NF + f]);
  }
  int z = threadIdx.x - 288;   // threads 288..317 zero the 30 K-pad cols
  if (z >= 0 && z < 30) { ENHh[base + DD + z] = 0; ENHl[base + DD + z] = 0; }
}

// ---------------- overlap-add + normalize + crop ----------------
__global__ void k_ola(const float* __restrict__ IFR, const float* __restrict__ WSQ,
                      float* __restrict__ out) {
  int idx = blockIdx.x * 256 + threadIdx.x;
  if (idx >= NB * LSEQ) return;
  int b = idx / LSEQ, l = idx - b * LSEQ;
  int p = l + FPAD;
  int t0 = (p <= 511) ? 0 : (p - 352) / 160;
  int t1 = p / 160; if (t1 > 600) t1 = 600;
  float s = 0.f;
  for (int t = t0; t <= t1; t++) s += IFR[((long)b * TT + t) * NFFT + (p - t * HOP)];
  out[idx] = s / fmaxf(WSQ[p], 1e-11f);
}

// ---------------- driver ----------------
extern "C" void kernel_launch(void* const* d_in, const int* in_sizes, int n_in,
                              void* d_out, int out_size, void* d_ws, size_t ws_size,
                              hipStream_t stream) {
  (void)in_sizes; (void)n_in; (void)out_size; (void)ws_size;
  const float* x   = (const float*)d_in[0];
  const float* Wih = (const float*)d_in[1];
  const float* Whh = (const float*)d_in[2];
  const float* bih = (const float*)d_in[3];
  const float* bhh = (const float*)d_in[4];
  const float* W1  = (const float*)d_in[5];
  const float* b1  = (const float*)d_in[6];
  const float* W2  = (const float*)d_in[7];
  const float* b2  = (const float*)d_in[8];
  float* ws = (float*)d_ws;

  // XP region: pre-split XPh/XPl (exactly fills old XP fp32 footprint); IFR aliases later.
  unsigned short* XPh = (unsigned short*)(ws + 0);            // 6,176,768 ush = 3,088,384 fl
  unsigned short* XPl = (unsigned short*)(ws + 3088384);      // -> region ends 6,176,768 fl
  float* S     = ws + 6176768;    // 19,774,496
  float* XWM   = ws + 25951264;   // 19,774,496 (XW then MS; WhhP4 in tail)
  float* HOUT  = ws + 45725760;   // 4,924,288 (pre-GEMM scratch + post-beam ENH split live here too)
  float* PSD_S = ws + 50650048;   // 263,168
  float* PSD_N = ws + 50913216;   // 263,168
  float* WV    = ws + 51176384;   // 32,896
  float* BSUM  = ws + 51209280;   // 512
  float* WSQ   = ws + 51209792;   // 96,512 -> 51,306,304
  unsigned short* W1sh = (unsigned short*)(ws + 51306304);
  unsigned short* W1sl = (unsigned short*)(ws + 51347264);
  unsigned short* W2sh = (unsigned short*)(ws + 51388224);
  unsigned short* W2sl = (unsigned short*)(ws + 51429184); // -> 51,470,144
  unsigned short* WTth = (unsigned short*)(ws + 51470144); // 139,264 fl
  unsigned short* WTtl = (unsigned short*)(ws + 51609408); // -> 51,748,672
  unsigned short* BIth = (unsigned short*)(ws + 51748672); // 139,264 fl
  unsigned short* BItl = (unsigned short*)(ws + 51887936); // -> end 52,027,200 (~208 MB)
  float* MS    = XWM;
  float* IFR   = ws + 0;          // aliases XP region after gemm4
  unsigned int* WhhP4 = (unsigned int*)(XWM + 19693568);   // after true end of XW
  // Pre-GEMM scratch inside HOUT (dead until k_lstm):
  float* BFf = HOUT;                                        // 263,168 fl
  float* BWf = HOUT + 263168;                               // 262,144 fl
  unsigned short* BCh = (unsigned short*)(HOUT + 525312);   // 1152*544 ush = 313,344 fl
  unsigned short* BCl = (unsigned short*)(HOUT + 838656);   // -> 1,152,000 fl < 4,924,288
  // B rows 0-511 duplicated into PSD regions (dead until k_psd) for the fused
  // k_lstm_s, whose concurrent LSTM overwrites the HOUT-resident BC (v18 race):
  unsigned short* BFsh = (unsigned short*)PSD_S;            // 512*544 ush = 139,264 fl <= 263,168
  unsigned short* BFsl = (unsigned short*)PSD_N;            // ditto
  // Post-beam ENH split in HOUT (Hout consumed by maskms before k_beam):
  unsigned short* ENHh = (unsigned short*)HOUT;             // 4808*544 ush = 1,307,776 fl
  unsigned short* ENHl = (unsigned short*)(HOUT + 1307776);

  // fused init: coalesced xp + edges + bff + wtsplit + bsum + wpack
  k_init<<<NINIT, 256, 0, stream>>>(x, Wih, Whh, bih, bhh,
                                    XPh, XPl, BFf, WTth, WTtl, BSUM, WhhP4);

  // BW = BF @ Wih^T  (512x512, K=514) — small gemm3
  {
    dim3 g(4, 4);
    k_gemm3<0><<<g, 256, 0, stream>>>(BFf, WTth, WTtl, nullptr, BWf, 512, 512, DD, DD, G4);
  }
  // combined split B = [BF | BW]; rows 0-511 also mirrored into BFsh/BFsl
  k_bcomb<<<(1152 * KPAD + 255) / 256, 256, 0, stream>>>(BWf, BCh, BCl, BFsh, BFsl);

  // pre-lstm: XW columns (+ S cols 512-513) = col tiles 4-8
  k_gemm4<<<5 * 301, 256, 0, stream>>>(XPh, XPl, BCh, BCl, BSUM, S, XWM, 4, 5);

  // fused: LSTM (blocks 0-63) + S cols 0-511 (tiles 0-3) + shadow aux
  // (wsq / bisplit / wmsplit - all consumed only post-lstm)
  k_lstm_s<<<64 + NGB + NAUX, 512, 0, stream>>>(XWM, WhhP4, HOUT, XPh, XPl, BFsh, BFsl, S,
                                                W1, W2, WSQ, BIth, BItl,
                                                W1sh, W1sl, W2sh, W2sl);

  k_maskms<<<9 * 601, 256, 0, stream>>>(HOUT, W1sh, W1sl, b1, S, MS);
  k_psd<<<NB * NF, 256, 0, stream>>>(MS, PSD_S);
  k_maskms<<<9 * 601, 256, 0, stream>>>(HOUT, W2sh, W2sl, b2, S, MS);
  k_psd<<<NB * NF, 256, 0, stream>>>(MS, PSD_N);

  k_solve<<<(NB * NF + 63) / 64, 64, 0, stream>>>(PSD_S, PSD_N, WV);
  k_beam<<<NB * TT, 320, 0, stream>>>(S, WV, ENHh, ENHl);

  // iSTFT: IFR[4808,512] = ENH @ BI (pre-split A)
  {
    dim3 g(4, 38);
    k_gemm5<<<g, 256, 0, stream>>>(ENHh, ENHl, BIth, BItl, IFR, NB * TT, NFFT, NFFT);
  }

  k_ola<<<(NB * LSEQ + 255) / 256, 256, 0, stream>>>(IFR, WSQ, (float*)d_out);
}